// Round 2
// baseline (1728.613 us; speedup 1.0000x reference)
//
#include <hip/hip_runtime.h>
#include <math.h>

typedef unsigned short u16;
typedef unsigned int u32;

typedef __attribute__((ext_vector_type(8))) short bf16x8;
typedef __attribute__((ext_vector_type(4))) float f32x4;

// ---------- bf16 helpers (intermediates only; I/O is f32) ----------
__device__ __forceinline__ float b2f(u16 u) {
    union { u32 ui; float f; } v; v.ui = ((u32)u) << 16; return v.f;
}
__device__ __forceinline__ float b2f_lo(u32 u) {
    union { u32 ui; float f; } v; v.ui = u << 16; return v.f;
}
__device__ __forceinline__ float b2f_hi(u32 u) {
    union { u32 ui; float f; } v; v.ui = u & 0xffff0000u; return v.f;
}
__device__ __forceinline__ u16 f2b(float f) {
    union { float f; u32 ui; } v; v.f = f;
    u32 x = v.ui;
    u32 r = (x + 0x7fffu + ((x >> 16) & 1u)) >> 16;
    return (u16)r;
}
__device__ __forceinline__ float sigf(float x) { return 1.0f / (1.0f + expf(-x)); }

// ---------- problem constants ----------
#define GNODES 128
#define EMBD   256
#define NB     64
#define TS     32
#define GOA    268
#define GLO    524

// output layout (f32 elements)
#define OUT_SPATIAL 0
#define OUT_NS      524288
#define OUT_V       524800
#define OUT_H       524864

// workspace byte offsets
#define WS_GOA   ((size_t)0)
#define WS_HBUF  ((size_t)2195456)
#define WS_CBUF  ((size_t)2260992)
#define WS_HOUT  ((size_t)2326528)
#define WS_GLO   ((size_t)2392064)
#define WS_WIHT  ((size_t)2526208)
#define WS_WHHT  ((size_t)3574784)
#define WS_BSUM  ((size_t)4623360)
#define WS_C2    ((size_t)4627456)
#define WS_C3    ((size_t)4889600)
#define WS_C4    ((size_t)5413888)
#define WS_C5    ((size_t)7511040)
#define WS_SL    ((size_t)15899648)
#define WS_WET   ((size_t)16948224)   // 256*64 bf16
#define WS_W1T   ((size_t)16980992)   // 256*256 bf16
#define WS_W2T   ((size_t)17112064)
#define WS_W3T   ((size_t)17243136)
#define WS_GX    ((size_t)17374208)   // 2048*1024 f32 = 8,388,608
#define WS_S1F   ((size_t)25762816)   // 64*4096 f32 = 1,048,576 -> end 26,811,392

// padded conv weights live in the goaAll region (dead after `heads`,
// fully rewritten by gcn_mfma next iteration). 2 x 64*64*12*4 = 393,216 B.
#define WS_WP4   WS_GOA
#define WS_WP5   (WS_GOA + (size_t)196608)

// LDS strides (elements)
#define SA_S 264
#define TT_S 136
#define XS_S 72

// ======================================================================
// weight prep: transpose + bf16-cast GCN weights
// ======================================================================
__global__ void wprep(const float* __restrict__ We, const float* __restrict__ W1,
                      const float* __restrict__ W2, const float* __restrict__ W3,
                      u16* __restrict__ WeT, u16* __restrict__ W1T,
                      u16* __restrict__ W2T, u16* __restrict__ W3T)
{
    int idx = blockIdx.x * 256 + threadIdx.x;
    if (idx < 16384) {
        int k = idx >> 8, nn = idx & 255;
        WeT[nn * 64 + k] = f2b(We[idx]);
    }
    {
        int k = idx >> 8, nn = idx & 255;
        W1T[nn * 256 + k] = f2b(W1[idx]);
        W2T[nn * 256 + k] = f2b(W2[idx]);
        W3T[nn * 256 + k] = f2b(W3[idx]);
    }
}

// ======================================================================
// GCN via MFMA — 1024 threads (16 waves) per block, 1 item per block.
// LDS 137.7KB forces 1 block/CU; 16 waves -> 4 waves/SIMD (50% occ).
// Work split:
//   W-mult : wave = (ftile-pair fp=wv&7, rt-half rh=wv>>3) -> 2x4 jobs
//   A-mult : wave = (node-tile nt=wv&7, feature-half ch=wv>>3)
//   bAgg duplicated across the two wave-halves (G re-read is L2-hit)
// ======================================================================
__global__ __launch_bounds__(1024) void gcn_mfma(
    const float* __restrict__ G, const float* __restrict__ X, const float* __restrict__ pa,
    const u16* __restrict__ WeT, const float* __restrict__ be,
    const u16* __restrict__ W1T, const float* __restrict__ b1,
    const u16* __restrict__ W2T, const float* __restrict__ b2,
    const u16* __restrict__ W3T, const float* __restrict__ b3,
    float* __restrict__ goaAll)
{
    __shared__ u16 Sa[128 * SA_S];
    __shared__ u16 Tt[256 * TT_S];
    __shared__ float dis[GNODES];
    __shared__ float dred[1024];
    __shared__ float pm[256];

    const int item = blockIdx.x;
    const int tid  = threadIdx.x;
    const int wv   = tid >> 6;        // 0..15
    const int nt   = wv & 7;          // node tile (A-mult)
    const int ch   = wv >> 3;         // half index
    const int lane = tid & 63;
    const int l16  = lane & 15;
    const int quad = lane >> 4;
    const float* Gp = G + (size_t)item * GNODES * GNODES;
    const float* Xp = X + (size_t)item * GNODES * 64;

    // stage X -> Tt (bf16), and degree partial sums (8 threads/row)
    for (int idx = tid; idx < 128 * 64; idx += 1024) {
        int m = idx >> 6, k = idx & 63;
        Tt[m * XS_S + k] = f2b(Xp[idx]);
    }
    {
        int row = tid >> 3, part = tid & 7;
        const float4* gr = (const float4*)(Gp + (size_t)row * GNODES) + part * 4;
        float s = 0.f;
#pragma unroll
        for (int k = 0; k < 4; ++k) { float4 g = gr[k]; s += g.x + g.y + g.z + g.w; }
        dred[tid] = s;
    }
    __syncthreads();
    if (tid < GNODES) {
        float s = 0.f;
#pragma unroll
        for (int p = 0; p < 8; ++p) s += dred[tid * 8 + p];
        dis[tid] = 1.0f / sqrtf(s + 1.0f);
    }
    __syncthreads();

    // bAgg: normalized adjacency fragments for node-tile nt (both halves)
    bf16x8 bAgg[4];
    {
        const int i = nt * 16 + l16;
        const float di = dis[i];
        const float* gr = Gp + (size_t)i * GNODES;
#pragma unroll
        for (int t = 0; t < 4; ++t) {
            const int k0 = t * 32 + quad * 8;
            float4 ga = *(const float4*)(gr + k0);
            float4 gb = *(const float4*)(gr + k0 + 4);
            float vv[8] = {ga.x, ga.y, ga.z, ga.w, gb.x, gb.y, gb.z, gb.w};
            bf16x8 f;
#pragma unroll
            for (int j = 0; j < 8; ++j) {
                int k = k0 + j;
                float a = (vv[j] + (k == i ? 1.0f : 0.0f)) * di * dis[k];
                f[j] = (short)f2b(a);
            }
            bAgg[t] = f;
        }
    }

    // emb = tanh(X @ We + be): wave = (node-tile nt, feature-half ch)
    {
        bf16x8 a0 = *(const bf16x8*)(Tt + (16 * nt + l16) * XS_S + quad * 8);
        bf16x8 a1 = *(const bf16x8*)(Tt + (16 * nt + l16) * XS_S + 32 + quad * 8);
#pragma unroll
        for (int cj = 0; cj < 8; ++cj) {
            const int ct = ch * 8 + cj;
            const int nf = ct * 16 + l16;
            bf16x8 wb0 = *(const bf16x8*)(WeT + nf * 64 + quad * 8);
            bf16x8 wb1 = *(const bf16x8*)(WeT + nf * 64 + 32 + quad * 8);
            float bb = be[nf];
            f32x4 acc = {bb, bb, bb, bb};
            acc = __builtin_amdgcn_mfma_f32_16x16x32_bf16(a0, wb0, acc, 0, 0, 0);
            acc = __builtin_amdgcn_mfma_f32_16x16x32_bf16(a1, wb1, acc, 0, 0, 0);
#pragma unroll
            for (int r = 0; r < 4; ++r) {
                int node = 16 * nt + quad * 4 + r;
                Sa[node * SA_S + nf] = f2b(tanhf(acc[r]));
            }
        }
    }
    __syncthreads();

    const u16* WTs[3]  = {W1T, W2T, W3T};
    const float* bss[3] = {b1, b2, b3};

    for (int l = 0; l < 3; ++l) {
        const u16* WT = WTs[l];
        const float* bias = bss[l];

        // ---- W-multiply: wave = (ftile-pair fp, rt-half rh) ----
        const int fp = wv & 7;
        const int rh = wv >> 3;
        bf16x8 bfr[2][8];
        float bb[2];
#pragma unroll
        for (int cc = 0; cc < 2; ++cc) {
            int nf = (2 * fp + cc) * 16 + l16;
            bb[cc] = bias[nf];
#pragma unroll
            for (int t = 0; t < 8; ++t)
                bfr[cc][t] = *(const bf16x8*)(WT + (size_t)nf * 256 + t * 32 + quad * 8);
        }
        for (int rj = 0; rj < 4; ++rj) {
            const int rt = rh * 4 + rj;
            bf16x8 afr[8];
#pragma unroll
            for (int t = 0; t < 8; ++t)
                afr[t] = *(const bf16x8*)(Sa + (16 * rt + l16) * SA_S + t * 32 + quad * 8);
#pragma unroll
            for (int cc = 0; cc < 2; ++cc) {
                f32x4 acc = {bb[cc], bb[cc], bb[cc], bb[cc]};
#pragma unroll
                for (int t = 0; t < 8; ++t)
                    acc = __builtin_amdgcn_mfma_f32_16x16x32_bf16(afr[t], bfr[cc][t], acc, 0, 0, 0);
                int nf = (2 * fp + cc) * 16 + l16;
                u16 p0 = f2b(acc[0]), p1 = f2b(acc[1]), p2 = f2b(acc[2]), p3 = f2b(acc[3]);
                uint2 pk; pk.x = (u32)p0 | ((u32)p1 << 16); pk.y = (u32)p2 | ((u32)p3 << 16);
                *(uint2*)(Tt + (size_t)nf * TT_S + 16 * rt + quad * 4) = pk;
            }
        }
        __syncthreads();

        // ---- A-multiply: wave = (node-tile nt, feature-half ch) ----
        for (int fj = 0; fj < 8; ++fj) {
            const int ft = ch * 8 + fj;
            bf16x8 afr[4];
#pragma unroll
            for (int t = 0; t < 4; ++t)
                afr[t] = *(const bf16x8*)(Tt + (16 * ft + l16) * TT_S + t * 32 + quad * 8);
            f32x4 acc = {0.f, 0.f, 0.f, 0.f};
#pragma unroll
            for (int t = 0; t < 4; ++t)
                acc = __builtin_amdgcn_mfma_f32_16x16x32_bf16(afr[t], bAgg[t], acc, 0, 0, 0);
            int i = nt * 16 + l16;
            u16 p0 = f2b(tanhf(acc[0])), p1 = f2b(tanhf(acc[1]));
            u16 p2 = f2b(tanhf(acc[2])), p3 = f2b(tanhf(acc[3]));
            uint2 pk; pk.x = (u32)p0 | ((u32)p1 << 16); pk.y = (u32)p2 | ((u32)p3 << 16);
            *(uint2*)(Sa + (size_t)i * SA_S + 16 * ft + quad * 4) = pk;
        }
        __syncthreads();
    }

    // ---- column max over nodes (split rows across two thread groups) ----
    const int nb = item >> 5, tt = item & 31;
    float* gdst = goaAll + ((size_t)tt * NB + nb) * GOA;
    float mymax = -2.0f;
    if (tid < 512) {
        int f = tid & 255, h = tid >> 8;
        for (int i = h * 64; i < h * 64 + 64; ++i)
            mymax = fmaxf(mymax, b2f(Sa[i * SA_S + f]));
        if (h == 1) pm[f] = mymax;
    }
    __syncthreads();
    if (tid < 256) {
        gdst[tid] = fmaxf(mymax, pm[tid]);
    } else if (tid >= 512 && tid < 524) {
        gdst[256 + (tid - 512)] = pa[(size_t)item * 12 + (tid - 512)];
    }
}

// ======================================================================
__global__ void wtrans(const float* __restrict__ Wih, const float* __restrict__ Whh,
                       const float* __restrict__ bih, const float* __restrict__ bhh,
                       float* __restrict__ wihT, float* __restrict__ whhT, float* __restrict__ bsum)
{
    int idx = blockIdx.x * 256 + threadIdx.x;
    int r = idx >> 8;
    int k = idx & 255;
    wihT[k * 1024 + r] = Wih[idx];
    whhT[k * 1024 + r] = Whh[idx];
    if (idx < 1024) bsum[idx] = bih[idx] + bhh[idx];
}

// ======================================================================
__global__ __launch_bounds__(256) void lstm_pre(
    const float* __restrict__ goaAll, const float* __restrict__ Wle, const float* __restrict__ ble,
    const float* __restrict__ wihT, const float* __restrict__ bsum,
    float* __restrict__ gatesX)
{
    __shared__ float gl[GOA];
    __shared__ float xv[256];
    const int item = blockIdx.x;          // t*NB + n
    const int u = threadIdx.x;
    const float* gsrc = goaAll + (size_t)item * GOA;
    gl[u] = gsrc[u];
    if (u < 12) gl[256 + u] = gsrc[256 + u];
    __syncthreads();

    float acc = ble[u];
    for (int k = 0; k < GOA; ++k) acc = fmaf(gl[k], Wle[k * 256 + u], acc);
    xv[u] = tanhf(acc);
    __syncthreads();

    float* gdst = gatesX + (size_t)item * 1024;
#pragma unroll
    for (int g = 0; g < 4; ++g) {
        float a = bsum[g * 256 + u];
#pragma unroll 8
        for (int k = 0; k < 256; ++k)
            a = fmaf(xv[k], wihT[k * 1024 + g * 256 + u], a);
        gdst[g * 256 + u] = a;
    }
}

// ======================================================================
__global__ __launch_bounds__(1024) void lstm_seq(
    const float* __restrict__ gatesX, const float* __restrict__ whhT,
    const int* __restrict__ relf, const float* __restrict__ lh,
    float* __restrict__ hbuf, float* __restrict__ cbuf, float* __restrict__ hout)
{
    __shared__ float hv[256];
    __shared__ float ga[1024];
    const int n = blockIdx.x, u = threadIdx.x;
    float cpriv = 0.f;
    if (u < 256) { hv[u] = lh[n * 256 + u]; cpriv = lh[16384 + n * 256 + u]; }
    __syncthreads();

    for (int t = 0; t < TS; ++t) {
        float a = gatesX[((size_t)t * NB + n) * 1024 + u];
        const float* wh = whhT + u;
#pragma unroll 8
        for (int k = 0; k < 256; ++k)
            a = fmaf(hv[k], wh[k * 1024], a);
        ga[u] = a;
        __syncthreads();
        if (u < 256) {
            float ai = ga[u], af = ga[256 + u], ag = ga[512 + u], ao = ga[768 + u];
            float cn = sigf(af) * cpriv + sigf(ai) * tanhf(ag);
            float hn = sigf(ao) * tanhf(cn);
            float kp = (relf[n * TS + t] != 0) ? 1.f : 0.f;
            if (t == TS - 1) {
                hout[n * 256 + u] = hn;
                hbuf[n * 256 + u] = hn * kp;
                cbuf[n * 256 + u] = cn * kp;
            }
            cpriv = cn * kp;
            hv[u] = hn * kp;
        }
        __syncthreads();
    }
}

// ======================================================================
__global__ __launch_bounds__(256) void heads(
    const float* __restrict__ goaAll, const float* __restrict__ hout,
    const float* __restrict__ hbuf, const float* __restrict__ cbuf,
    const float* __restrict__ Wa, const float* __restrict__ ba,
    const float* __restrict__ Wv, const float* __restrict__ bv,
    const int* __restrict__ avail, float* __restrict__ glo, float* __restrict__ out)
{
    __shared__ float gl[GLO];
    __shared__ float lg[8];
    const int n = blockIdx.x, tid = threadIdx.x;
    const float* gsrc = goaAll + ((size_t)31 * NB + n) * GOA;
    gl[tid] = hout[n * 256 + tid];
    gl[256 + tid] = gsrc[tid];
    if (tid < 12) gl[512 + tid] = gsrc[256 + tid];
    __syncthreads();

    glo[n * GLO + tid]       = gl[tid];
    glo[n * GLO + 256 + tid] = gl[256 + tid];
    if (tid < 12) glo[n * GLO + 512 + tid] = gl[512 + tid];

    out[OUT_H + n * 256 + tid]         = hbuf[n * 256 + tid];
    out[OUT_H + 16384 + n * 256 + tid] = cbuf[n * 256 + tid];

    if (tid < 8) {
        float a = ba[tid];
        for (int k = 0; k < GLO; ++k) a = fmaf(gl[k], Wa[k * 8 + tid], a);
        lg[tid] = (avail[n * 8 + tid] == 0) ? -INFINITY : a;
    } else if (tid == 8) {
        float a = bv[0];
        for (int k = 0; k < GLO; ++k) a = fmaf(gl[k], Wv[k], a);
        out[OUT_V + n] = a;
    }
    __syncthreads();
    if (tid == 0) {
        float m = -INFINITY;
        for (int a = 0; a < 8; ++a) m = fmaxf(m, lg[a]);
        float e[8], s = 0.f;
        for (int a = 0; a < 8; ++a) { e[a] = expf(lg[a] - m); s += e[a]; }
        float inv = 1.f / s;
        for (int a = 0; a < 8; ++a) out[OUT_NS + n * 8 + a] = e[a] * inv;
    }
}

// ======================================================================
// wpad_k: pad conv weights from 9 to 16B-aligned 12 floats per (co,ci)
// ======================================================================
__global__ void wpad_k(const float* __restrict__ Wc4, const float* __restrict__ Wc5,
                       float* __restrict__ wp4, float* __restrict__ wp5)
{
    int idx = blockIdx.x * 256 + threadIdx.x;   // 0 .. 73727
    int which = idx / 36864;
    int r = idx - which * 36864;
    int pair = r / 9, q = r - pair * 9;
    const float* src = which ? Wc5 : Wc4;
    float* dst = which ? wp5 : wp4;
    dst[pair * 12 + q] = src[r];
}

// ======================================================================
__global__ __launch_bounds__(256) void deconv1_k(
    const float* __restrict__ glo, const float* __restrict__ Wt1, const float* __restrict__ bt1,
    float* __restrict__ s1f)
{
    const int f = blockIdx.x;
    const int tid = threadIdx.x;
    const int n = tid >> 2, pp = tid & 3;
    float bb = bt1[f];
    float a0 = bb, a1 = bb, a2 = bb, a3 = bb;
    const float* gp = glo + n * GLO;
    for (int c = 0; c < GLO; ++c) {
        float g = gp[c];
        float4 w4 = *(const float4*)&Wt1[(((size_t)c * 256 + f) << 4) + pp * 4];
        a0 = fmaf(g, w4.x, a0);
        a1 = fmaf(g, w4.y, a1);
        a2 = fmaf(g, w4.z, a2);
        a3 = fmaf(g, w4.w, a3);
    }
    float* dst = s1f + (((size_t)n * 256 + f) << 4) + pp * 4;
    dst[0] = a0 > 0.f ? a0 : 0.1f * a0;
    dst[1] = a1 > 0.f ? a1 : 0.1f * a1;
    dst[2] = a2 > 0.f ? a2 : 0.1f * a2;
    dst[3] = a3 > 0.f ? a3 : 0.1f * a3;
}

// ======================================================================
__global__ __launch_bounds__(256) void conv2_k(
    const float* __restrict__ s1f, const float* __restrict__ Wc2, const float* __restrict__ bc2,
    u16* __restrict__ c2)
{
    __shared__ float sp[256 * 36];   // 36,864 B
    const int n = blockIdx.x >> 3, cot = blockIdx.x & 7;
    const int tid = threadIdx.x;
    for (int i = tid; i < 256 * 36; i += 256) sp[i] = 0.f;
    __syncthreads();
    for (int i = tid; i < 4096; i += 256) {
        int ci = i >> 4, p = i & 15, y = p >> 2, x = p & 3;
        sp[ci * 36 + (y + 1) * 6 + (x + 1)] = s1f[((size_t)n * 256 + ci) * 16 + p];
    }
    __syncthreads();

    const int co = cot * 16 + (tid >> 4);
    const int p = tid & 15, y = p >> 2, x = p & 3;
    float acc = bc2[co];
    const float* wp = Wc2 + (size_t)co * 256 * 9;
    for (int ci = 0; ci < 256; ++ci) {
        const float* wc = wp + ci * 9;
        const float* s = sp + ci * 36 + y * 6 + x;
#pragma unroll
        for (int ky = 0; ky < 3; ++ky) {
#pragma unroll
            for (int kx = 0; kx < 3; ++kx)
                acc = fmaf(s[ky * 6 + kx], wc[ky * 3 + kx], acc);
        }
    }
    c2[((size_t)n * 128 + co) * 16 + p] = f2b(acc);
}

// ======================================================================
// up_conv: legacy whole-image upsample+conv with dynamic LDS (c2->c3)
// ======================================================================
__global__ __launch_bounds__(256) void up_conv(
    const u16* __restrict__ in, const float* __restrict__ w, const float* __restrict__ bias,
    u16* __restrict__ out, int CIN, int CO, int H, int W, int coTiles)
{
    extern __shared__ u16 S[];
    const int tid = threadIdx.x;
    const int n  = blockIdx.x / coTiles;
    const int ct = blockIdx.x % coTiles;
    const int H2 = 2 * H, W2 = 2 * W;
    const u16* ip = in + (size_t)n * CIN * H * W;

    const int tot = CIN * H2 * W2;
    for (int i = tid; i < tot; i += 256) {
        int x2 = i % W2; int y2 = (i / W2) % H2; int ci = i / (W2 * H2);
        int y0 = (y2 - 1) >> 1; float fy = (y2 & 1) ? 0.25f : 0.75f;
        int x0 = (x2 - 1) >> 1; float fx = (x2 & 1) ? 0.25f : 0.75f;
        int y0c = y0 < 0 ? 0 : y0, y1c = y0 + 1 > H - 1 ? H - 1 : y0 + 1;
        int x0c = x0 < 0 ? 0 : x0, x1c = x0 + 1 > W - 1 ? W - 1 : x0 + 1;
        const u16* b = ip + ci * H * W;
        float v00 = b2f(b[y0c * W + x0c]), v01 = b2f(b[y0c * W + x1c]);
        float v10 = b2f(b[y1c * W + x0c]), v11 = b2f(b[y1c * W + x1c]);
        float v = (1.f - fy) * ((1.f - fx) * v00 + fx * v01)
                +        fy  * ((1.f - fx) * v10 + fx * v11);
        S[i] = f2b(fmaxf(v, 0.f));
    }
    __syncthreads();

    const int xg = W2 >> 3;
    const int units = 4 * H2 * xg;
    for (int ugl = tid; ugl < units; ugl += 256) {
        int x0p = (ugl % xg) * 8;
        int y   = (ugl / xg) % H2;
        int cp  = ugl / (xg * H2);
        int co0 = ct * 8 + cp * 2;
        float acc0[8], acc1[8];
        float bb0 = bias[co0], bb1 = bias[co0 + 1];
#pragma unroll
        for (int d = 0; d < 8; ++d) { acc0[d] = bb0; acc1[d] = bb1; }
        const float* w0 = w + (size_t)co0 * CIN * 9;
        const float* w1 = w0 + (size_t)CIN * 9;
        for (int ci = 0; ci < CIN; ++ci) {
            const u16* Sr = S + ci * H2 * W2;
            float wa[9], wb[9];
#pragma unroll
            for (int q = 0; q < 9; ++q) { wa[q] = w0[ci * 9 + q]; wb[q] = w1[ci * 9 + q]; }
#pragma unroll
            for (int ky = 0; ky < 3; ++ky) {
                int yy = y + ky - 1;
                if (yy < 0 || yy >= H2) continue;
                float seg[10];
#pragma unroll
                for (int dx = 0; dx < 10; ++dx) {
                    int xx = x0p + dx - 1;
                    seg[dx] = (xx >= 0 && xx < W2) ? b2f(Sr[yy * W2 + xx]) : 0.f;
                }
#pragma unroll
                for (int d = 0; d < 8; ++d) {
                    acc0[d] = fmaf(seg[d],     wa[ky * 3 + 0], acc0[d]);
                    acc0[d] = fmaf(seg[d + 1], wa[ky * 3 + 1], acc0[d]);
                    acc0[d] = fmaf(seg[d + 2], wa[ky * 3 + 2], acc0[d]);
                    acc1[d] = fmaf(seg[d],     wb[ky * 3 + 0], acc1[d]);
                    acc1[d] = fmaf(seg[d + 1], wb[ky * 3 + 1], acc1[d]);
                    acc1[d] = fmaf(seg[d + 2], wb[ky * 3 + 2], acc1[d]);
                }
            }
        }
        u16* op0 = out + (((size_t)(n * CO + co0) * H2) + y) * W2 + x0p;
        u16* op1 = op0 + (size_t)H2 * W2;
#pragma unroll
        for (int d = 0; d < 8; ++d) { op0[d] = f2b(acc0[d]); op1[d] = f2b(acc1[d]); }
    }
}

// ======================================================================
// up_conv_b: banded upsample+conv with halo-in-LDS layout
// ======================================================================
template<int CIN, int HI, int WI, int BH, int DW, int COT, int CO>
__global__ __launch_bounds__(256) void up_conv_b(
    const u16* __restrict__ in, const float* __restrict__ wpad, const float* __restrict__ bias,
    u16* __restrict__ out)
{
    constexpr int H2 = 2 * HI, W2 = 2 * WI;
    constexpr int XG = W2 / DW;
    constexpr int ROWS = BH + 2;
    constexpr int STR = W2 + 2;            // even, odd bank count
    constexpr int NBAND = H2 / BH;
    constexpr int CT = CO / COT;
    constexpr int PAIRS = COT / 2;
    static_assert(XG * BH * PAIRS == 256, "thread map must cover block");
    static_assert((STR & 1) == 0, "u32 LDS reads need even u16 stride");

    __shared__ u16 S[CIN * ROWS * STR];

    const int tid = threadIdx.x;
    int b = blockIdx.x;
    const int ct = b % CT; b /= CT;
    const int band = b % NBAND;
    const int n = b / NBAND;
    const int r0 = band * BH;

    const u16* ip = in + (size_t)n * CIN * HI * WI;

    // stage: bilinear x2 upsample + relu, zero halo (y and x), bf16
    for (int i = tid; i < CIN * ROWS * STR; i += 256) {
        int x  = i % STR;
        int ry = (i / STR) % ROWS;
        int ci = i / (STR * ROWS);
        int yy = r0 - 1 + ry;
        int xx = x - 1;
        float v = 0.f;
        if (yy >= 0 && yy < H2 && xx >= 0 && xx < W2) {
            int y0 = (yy - 1) >> 1; float fy = (yy & 1) ? 0.25f : 0.75f;
            int x0 = (xx - 1) >> 1; float fx = (xx & 1) ? 0.25f : 0.75f;
            int y0c = y0 < 0 ? 0 : y0, y1c = y0 + 1 > HI - 1 ? HI - 1 : y0 + 1;
            int x0c = x0 < 0 ? 0 : x0, x1c = x0 + 1 > WI - 1 ? WI - 1 : x0 + 1;
            const u16* bp = ip + ci * HI * WI;
            float v00 = b2f(bp[y0c * WI + x0c]), v01 = b2f(bp[y0c * WI + x1c]);
            float v10 = b2f(bp[y1c * WI + x0c]), v11 = b2f(bp[y1c * WI + x1c]);
            v = (1.f - fy) * ((1.f - fx) * v00 + fx * v01)
              +        fy  * ((1.f - fx) * v10 + fx * v11);
            v = fmaxf(v, 0.f);
        }
        S[i] = f2b(v);
    }
    __syncthreads();

    const int xg = tid % XG;
    const int y  = (tid / XG) % BH;
    const int pr = tid / (XG * BH);
    const int co0 = ct * COT + pr * 2;
    const int x0 = xg * DW;
    const int yo = r0 + y;

    float acc0[DW], acc1[DW];
    const float bb0 = bias[co0], bb1 = bias[co0 + 1];
#pragma unroll
    for (int d = 0; d < DW; ++d) { acc0[d] = bb0; acc1[d] = bb1; }

    const float* wp0 = wpad + (size_t)(co0 * CIN) * 12;
    const float* wp1 = wpad + (size_t)((co0 + 1) * CIN) * 12;

    for (int ci = 0; ci < CIN; ++ci) {
        float wa[9], wb[9];
        {
            const float4* av = (const float4*)(wp0 + ci * 12);
            float4 a0 = av[0], a1 = av[1], a2 = av[2];
            wa[0] = a0.x; wa[1] = a0.y; wa[2] = a0.z; wa[3] = a0.w;
            wa[4] = a1.x; wa[5] = a1.y; wa[6] = a1.z; wa[7] = a1.w; wa[8] = a2.x;
            const float4* bv = (const float4*)(wp1 + ci * 12);
            float4 b0 = bv[0], b1 = bv[1], b2v = bv[2];
            wb[0] = b0.x; wb[1] = b0.y; wb[2] = b0.z; wb[3] = b0.w;
            wb[4] = b1.x; wb[5] = b1.y; wb[6] = b1.z; wb[7] = b1.w; wb[8] = b2v.x;
        }
#pragma unroll
        for (int ky = 0; ky < 3; ++ky) {
            const u32* Sr = (const u32*)(S + ci * ROWS * STR + (y + ky) * STR + x0);
            float seg[DW + 2];
#pragma unroll
            for (int k = 0; k < (DW + 2) / 2; ++k) {
                u32 u = Sr[k];
                seg[2 * k]     = b2f_lo(u);
                seg[2 * k + 1] = b2f_hi(u);
            }
#pragma unroll
            for (int d = 0; d < DW; ++d) {
                acc0[d] = fmaf(seg[d],     wa[ky * 3 + 0], acc0[d]);
                acc0[d] = fmaf(seg[d + 1], wa[ky * 3 + 1], acc0[d]);
                acc0[d] = fmaf(seg[d + 2], wa[ky * 3 + 2], acc0[d]);
                acc1[d] = fmaf(seg[d],     wb[ky * 3 + 0], acc1[d]);
                acc1[d] = fmaf(seg[d + 1], wb[ky * 3 + 1], acc1[d]);
                acc1[d] = fmaf(seg[d + 2], wb[ky * 3 + 2], acc1[d]);
            }
        }
    }

    u16* op0 = out + (((size_t)(n * CO + co0) * H2) + yo) * W2 + x0;
    u16* op1 = op0 + (size_t)H2 * W2;
#pragma unroll
    for (int d = 0; d < DW; d += 2) {
        u32 p0 = (u32)f2b(acc0[d]) | ((u32)f2b(acc0[d + 1]) << 16);
        u32 p1 = (u32)f2b(acc1[d]) | ((u32)f2b(acc1[d + 1]) << 16);
        *(u32*)(op0 + d) = p0;
        *(u32*)(op1 + d) = p1;
    }
}

// ======================================================================
// up_conv6: 4-wide units so all 256 threads compute (CO=2 final conv)
// ======================================================================
__global__ __launch_bounds__(256) void up_conv6(
    const u16* __restrict__ c5, const float* __restrict__ w, const float* __restrict__ bias,
    u16* __restrict__ sl)
{
    __shared__ u16 S[40960];
    const int tid = threadIdx.x;
    const int n = blockIdx.x >> 3;
    const int band = blockIdx.x & 7;
    const int r0 = band * 8;
    const u16* ip = c5 + (size_t)n * 64 * 1024;

    for (int i = tid; i < 40960; i += 256) {
        int x2 = i & 63; int ry = (i >> 6) % 10; int ci = i / 640;
        int yy = r0 - 1 + ry;
        float v = 0.f;
        if (yy >= 0 && yy < 64) {
            int y0 = (yy - 1) >> 1; float fy = (yy & 1) ? 0.25f : 0.75f;
            int x0 = (x2 - 1) >> 1; float fx = (x2 & 1) ? 0.25f : 0.75f;
            int y0c = y0 < 0 ? 0 : y0, y1c = y0 + 1 > 31 ? 31 : y0 + 1;
            int x0c = x0 < 0 ? 0 : x0, x1c = x0 + 1 > 31 ? 31 : x0 + 1;
            const u16* b = ip + ci * 1024;
            float v00 = b2f(b[y0c * 32 + x0c]), v01 = b2f(b[y0c * 32 + x1c]);
            float v10 = b2f(b[y1c * 32 + x0c]), v11 = b2f(b[y1c * 32 + x1c]);
            v = fmaxf((1.f - fy) * ((1.f - fx) * v00 + fx * v01)
                      +      fy  * ((1.f - fx) * v10 + fx * v11), 0.f);
        }
        S[i] = f2b(v);
    }
    __syncthreads();

    {
        const int u = tid;                  // 256 units: 2co x 8y x 16xg(4-wide)
        const int x0p = (u & 15) * 4;
        const int yr  = (u >> 4) & 7;
        const int co  = u >> 7;
        const int y = r0 + yr;
        float acc[4];
        float bb = bias[co];
#pragma unroll
        for (int d = 0; d < 4; ++d) acc[d] = bb;
        const float* wp = w + (size_t)co * 64 * 9;
        for (int ci = 0; ci < 64; ++ci) {
            const u16* Sr = S + ci * 640;
            float wk[9];
#pragma unroll
            for (int q = 0; q < 9; ++q) wk[q] = wp[ci * 9 + q];
#pragma unroll
            for (int ky = 0; ky < 3; ++ky) {
                int ry = yr + ky;
                float seg[6];
#pragma unroll
                for (int dx = 0; dx < 6; ++dx) {
                    int xx = x0p + dx - 1;
                    seg[dx] = (xx >= 0 && xx < 64) ? b2f(Sr[ry * 64 + xx]) : 0.f;
                }
#pragma unroll
                for (int d = 0; d < 4; ++d) {
                    acc[d] = fmaf(seg[d],     wk[ky * 3 + 0], acc[d]);
                    acc[d] = fmaf(seg[d + 1], wk[ky * 3 + 1], acc[d]);
                    acc[d] = fmaf(seg[d + 2], wk[ky * 3 + 2], acc[d]);
                }
            }
        }
        u16* op = sl + (size_t)(n * 2 + co) * 4096 + y * 64 + x0p;
#pragma unroll
        for (int d = 0; d < 4; ++d) op[d] = f2b(acc[d]);
    }
}

// ======================================================================
__global__ __launch_bounds__(256) void softmax_spatial(const u16* __restrict__ sl, float* __restrict__ out)
{
    __shared__ float red[256];
    const int b = blockIdx.x;
    const u16* src = sl + (size_t)b * 4096;
    float* dst = out + (size_t)b * 4096;
    const int tid = threadIdx.x;
    float m = -INFINITY;
    for (int i = tid; i < 4096; i += 256) m = fmaxf(m, b2f(src[i]));
    red[tid] = m; __syncthreads();
    for (int s = 128; s > 0; s >>= 1) { if (tid < s) red[tid] = fmaxf(red[tid], red[tid + s]); __syncthreads(); }
    m = red[0]; __syncthreads();
    float sum = 0.f;
    for (int i = tid; i < 4096; i += 256) sum += expf(b2f(src[i]) - m);
    red[tid] = sum; __syncthreads();
    for (int s = 128; s > 0; s >>= 1) { if (tid < s) red[tid] += red[tid + s]; __syncthreads(); }
    float inv = 1.f / red[0];
    for (int i = tid; i < 4096; i += 256) dst[i] = expf(b2f(src[i]) - m) * inv;
}

// ======================================================================
extern "C" void kernel_launch(void* const* d_in, const int* in_sizes, int n_in,
                              void* d_out, int out_size, void* d_ws, size_t ws_size,
                              hipStream_t stream)
{
    const float* G     = (const float*)d_in[0];
    const float* X     = (const float*)d_in[1];
    const int*   avail = (const int*)d_in[2];
    const float* lh    = (const float*)d_in[3];
    const float* pa    = (const float*)d_in[4];
    const int*   relf  = (const int*)d_in[5];
    const float* We  = (const float*)d_in[6];   const float* be  = (const float*)d_in[7];
    const float* W1  = (const float*)d_in[8];   const float* b1  = (const float*)d_in[9];
    const float* W2  = (const float*)d_in[10];  const float* b2  = (const float*)d_in[11];
    const float* W3  = (const float*)d_in[12];  const float* b3  = (const float*)d_in[13];
    const float* Wle = (const float*)d_in[14];  const float* ble = (const float*)d_in[15];
    const float* Wih = (const float*)d_in[16];  const float* Whh = (const float*)d_in[17];
    const float* bih = (const float*)d_in[18];  const float* bhh = (const float*)d_in[19];
    const float* Wa  = (const float*)d_in[20];  const float* ba  = (const float*)d_in[21];
    const float* Wv  = (const float*)d_in[22];  const float* bv  = (const float*)d_in[23];
    const float* Wt1 = (const float*)d_in[24];  const float* bt1 = (const float*)d_in[25];
    const float* Wc2 = (const float*)d_in[26];  const float* bc2 = (const float*)d_in[27];
    const float* Wc3 = (const float*)d_in[28];  const float* bc3 = (const float*)d_in[29];
    const float* Wc4 = (const float*)d_in[30];  const float* bc4 = (const float*)d_in[31];
    const float* Wc5 = (const float*)d_in[32];  const float* bc5 = (const float*)d_in[33];
    const float* Wc6 = (const float*)d_in[34];  const float* bc6 = (const float*)d_in[35];

    char* ws = (char*)d_ws;
    float* goaAll = (float*)(ws + WS_GOA);
    float* hbuf   = (float*)(ws + WS_HBUF);
    float* cbuf   = (float*)(ws + WS_CBUF);
    float* hout   = (float*)(ws + WS_HOUT);
    float* glo    = (float*)(ws + WS_GLO);
    float* wihT   = (float*)(ws + WS_WIHT);
    float* whhT   = (float*)(ws + WS_WHHT);
    float* bsum   = (float*)(ws + WS_BSUM);
    u16*   c2     = (u16*)(ws + WS_C2);
    u16*   c3     = (u16*)(ws + WS_C3);
    u16*   c4     = (u16*)(ws + WS_C4);
    u16*   c5     = (u16*)(ws + WS_C5);
    u16*   sl     = (u16*)(ws + WS_SL);
    u16*   WeT    = (u16*)(ws + WS_WET);
    u16*   W1T    = (u16*)(ws + WS_W1T);
    u16*   W2T    = (u16*)(ws + WS_W2T);
    u16*   W3T    = (u16*)(ws + WS_W3T);
    float* gatesX = (float*)(ws + WS_GX);
    float* s1f    = (float*)(ws + WS_S1F);
    float* wp4    = (float*)(ws + WS_WP4);
    float* wp5    = (float*)(ws + WS_WP5);
    float* out    = (float*)d_out;     // OUTPUT IS FLOAT32

    wprep<<<256, 256, 0, stream>>>(We, W1, W2, W3, WeT, W1T, W2T, W3T);
    wtrans<<<1024, 256, 0, stream>>>(Wih, Whh, bih, bhh, wihT, whhT, bsum);
    gcn_mfma<<<2048, 1024, 0, stream>>>(G, X, pa, WeT, be, W1T, b1, W2T, b2, W3T, b3, goaAll);
    lstm_pre<<<2048, 256, 0, stream>>>(goaAll, Wle, ble, wihT, bsum, gatesX);
    lstm_seq<<<64, 1024, 0, stream>>>(gatesX, whhT, relf, lh, hbuf, cbuf, hout);
    heads<<<64, 256, 0, stream>>>(goaAll, hout, hbuf, cbuf, Wa, ba, Wv, bv, avail, glo, out);
    // goaAll is dead from here; reuse its region for padded conv weights
    wpad_k<<<288, 256, 0, stream>>>(Wc4, Wc5, wp4, wp5);
    deconv1_k<<<256, 256, 0, stream>>>(glo, Wt1, bt1, s1f);
    conv2_k<<<512, 256, 0, stream>>>(s1f, Wc2, bc2, c2);
    // c2->c3: legacy kernel, dynamic LDS = 128*8*8*2 = 16 KB
    up_conv<<<512, 256, 16384, stream>>>(c2, Wc3, bc3, c3, 128, 64, 4, 4, 8);
    // c3->c4: banded, 64ci, 8x8->16x16, BH=4, DW=4, COT=32 -> grid 64*4*2
    up_conv_b<64, 8, 8, 4, 4, 32, 64><<<512, 256, 0, stream>>>(c3, wp4, bc4, c4);
    // c4->c5: banded, 64ci, 16x16->32x32, BH=4, DW=8, COT=32 -> grid 64*8*2
    up_conv_b<64, 16, 16, 4, 8, 32, 64><<<1024, 256, 0, stream>>>(c4, wp5, bc5, c5);
    up_conv6<<<512, 256, 0, stream>>>(c5, Wc6, bc6, sl);
    softmax_spatial<<<128, 256, 0, stream>>>(sl, out + OUT_SPATIAL);
}

// Round 3
// 1573.664 us; speedup vs baseline: 1.0985x; 1.0985x over previous
//
#include <hip/hip_runtime.h>
#include <math.h>

typedef unsigned short u16;
typedef unsigned int u32;

typedef __attribute__((ext_vector_type(8))) short bf16x8;
typedef __attribute__((ext_vector_type(4))) float f32x4;

// ---------- bf16 helpers (intermediates only; I/O is f32) ----------
__device__ __forceinline__ float b2f(u16 u) {
    union { u32 ui; float f; } v; v.ui = ((u32)u) << 16; return v.f;
}
__device__ __forceinline__ float b2f_lo(u32 u) {
    union { u32 ui; float f; } v; v.ui = u << 16; return v.f;
}
__device__ __forceinline__ float b2f_hi(u32 u) {
    union { u32 ui; float f; } v; v.ui = u & 0xffff0000u; return v.f;
}
__device__ __forceinline__ u16 f2b(float f) {
    union { float f; u32 ui; } v; v.f = f;
    u32 x = v.ui;
    u32 r = (x + 0x7fffu + ((x >> 16) & 1u)) >> 16;
    return (u16)r;
}
__device__ __forceinline__ float sigf(float x) { return 1.0f / (1.0f + expf(-x)); }

// ---------- problem constants ----------
#define GNODES 128
#define EMBD   256
#define NB     64
#define TS     32
#define GOA    268
#define GLO    524

// output layout (f32 elements)
#define OUT_SPATIAL 0
#define OUT_NS      524288
#define OUT_V       524800
#define OUT_H       524864

// workspace byte offsets
#define WS_GOA   ((size_t)0)
#define WS_HBUF  ((size_t)2195456)
#define WS_CBUF  ((size_t)2260992)
#define WS_HOUT  ((size_t)2326528)
#define WS_GLO   ((size_t)2392064)
#define WS_WIHT  ((size_t)2526208)
#define WS_WHHT  ((size_t)3574784)
#define WS_BSUM  ((size_t)4623360)
#define WS_C2    ((size_t)4627456)
#define WS_C3    ((size_t)4889600)
#define WS_C4    ((size_t)5413888)
#define WS_C5    ((size_t)7511040)
#define WS_SL    ((size_t)15899648)
#define WS_WET   ((size_t)16948224)   // 256*64 bf16
#define WS_W1T   ((size_t)16980992)   // 256*256 bf16
#define WS_W2T   ((size_t)17112064)
#define WS_W3T   ((size_t)17243136)
#define WS_GX    ((size_t)17374208)   // 2048*1024 f32 = 8,388,608
#define WS_S1F   ((size_t)25762816)   // 64*4096 f32 = 1,048,576 -> end 26,811,392

// padded conv weights live in the goaAll region (dead after `heads`,
// fully rewritten by gcn_mfma next iteration). 2 x 64*64*12*4 = 393,216 B.
#define WS_WP4   WS_GOA
#define WS_WP5   (WS_GOA + (size_t)196608)

// LDS strides (elements)
#define SA_S 264
#define TT_S 136
#define XS_S 72

// ======================================================================
// weight prep: transpose + bf16-cast GCN weights
// ======================================================================
__global__ void wprep(const float* __restrict__ We, const float* __restrict__ W1,
                      const float* __restrict__ W2, const float* __restrict__ W3,
                      u16* __restrict__ WeT, u16* __restrict__ W1T,
                      u16* __restrict__ W2T, u16* __restrict__ W3T)
{
    int idx = blockIdx.x * 256 + threadIdx.x;
    if (idx < 16384) {
        int k = idx >> 8, nn = idx & 255;
        WeT[nn * 64 + k] = f2b(We[idx]);
    }
    {
        int k = idx >> 8, nn = idx & 255;
        W1T[nn * 256 + k] = f2b(W1[idx]);
        W2T[nn * 256 + k] = f2b(W2[idx]);
        W3T[nn * 256 + k] = f2b(W3[idx]);
    }
}

// ======================================================================
// GCN via MFMA — 1024 threads (16 waves), 1 item per block.
// LDS ~140KB forces 1 block/CU; 16 waves -> 4 waves/SIMD (50% occ).
// launch_bounds(1024,4): 4 waves/EU -> 128-VGPR cap (true occupancy
// anyway, since LDS caps at 1 block/CU). Register-light W-mult:
//   W-mult : wave = ftile (bfr[8] persistent from GLOBAL W, 32 VGPR;
//            afr[8] transient per row-tile, 32 VGPR) -> no spill
//   A-mult : wave = (node-tile nt=wv&7, feature-half ch=wv>>3)
// ======================================================================
__global__ __launch_bounds__(1024, 4) void gcn_mfma(
    const float* __restrict__ G, const float* __restrict__ X, const float* __restrict__ pa,
    const u16* __restrict__ WeT, const float* __restrict__ be,
    const u16* __restrict__ W1T, const float* __restrict__ b1,
    const u16* __restrict__ W2T, const float* __restrict__ b2,
    const u16* __restrict__ W3T, const float* __restrict__ b3,
    float* __restrict__ goaAll)
{
    __shared__ u16 Sa[128 * SA_S];
    __shared__ u16 Tt[256 * TT_S];
    __shared__ float dis[GNODES];
    __shared__ float dred[1024];
    __shared__ float pm[256];

    const int item = blockIdx.x;
    const int tid  = threadIdx.x;
    const int wv   = tid >> 6;        // 0..15
    const int nt   = wv & 7;          // node tile (A-mult / emb)
    const int ch   = wv >> 3;         // half index (A-mult / emb)
    const int lane = tid & 63;
    const int l16  = lane & 15;
    const int quad = lane >> 4;
    const float* Gp = G + (size_t)item * GNODES * GNODES;
    const float* Xp = X + (size_t)item * GNODES * 64;

    // stage X -> Tt (bf16), and degree partial sums (8 threads/row)
    for (int idx = tid; idx < 128 * 64; idx += 1024) {
        int m = idx >> 6, k = idx & 63;
        Tt[m * XS_S + k] = f2b(Xp[idx]);
    }
    {
        int row = tid >> 3, part = tid & 7;
        const float4* gr = (const float4*)(Gp + (size_t)row * GNODES) + part * 4;
        float s = 0.f;
#pragma unroll
        for (int k = 0; k < 4; ++k) { float4 g = gr[k]; s += g.x + g.y + g.z + g.w; }
        dred[tid] = s;
    }
    __syncthreads();
    if (tid < GNODES) {
        float s = 0.f;
#pragma unroll
        for (int p = 0; p < 8; ++p) s += dred[tid * 8 + p];
        dis[tid] = 1.0f / sqrtf(s + 1.0f);
    }
    __syncthreads();

    // bAgg: normalized adjacency fragments for node-tile nt (dup across ch)
    bf16x8 bAgg[4];
    {
        const int i = nt * 16 + l16;
        const float di = dis[i];
        const float* gr = Gp + (size_t)i * GNODES;
#pragma unroll
        for (int t = 0; t < 4; ++t) {
            const int k0 = t * 32 + quad * 8;
            float4 ga = *(const float4*)(gr + k0);
            float4 gb = *(const float4*)(gr + k0 + 4);
            float vv[8] = {ga.x, ga.y, ga.z, ga.w, gb.x, gb.y, gb.z, gb.w};
            bf16x8 f;
#pragma unroll
            for (int j = 0; j < 8; ++j) {
                int k = k0 + j;
                float a = (vv[j] + (k == i ? 1.0f : 0.0f)) * di * dis[k];
                f[j] = (short)f2b(a);
            }
            bAgg[t] = f;
        }
    }

    // emb = tanh(X @ We + be): wave = (node-tile nt, feature-half ch)
    {
        bf16x8 a0 = *(const bf16x8*)(Tt + (16 * nt + l16) * XS_S + quad * 8);
        bf16x8 a1 = *(const bf16x8*)(Tt + (16 * nt + l16) * XS_S + 32 + quad * 8);
        for (int cj = 0; cj < 8; ++cj) {
            const int ct = ch * 8 + cj;
            const int nf = ct * 16 + l16;
            bf16x8 wb0 = *(const bf16x8*)(WeT + nf * 64 + quad * 8);
            bf16x8 wb1 = *(const bf16x8*)(WeT + nf * 64 + 32 + quad * 8);
            float bb = be[nf];
            f32x4 acc = {bb, bb, bb, bb};
            acc = __builtin_amdgcn_mfma_f32_16x16x32_bf16(a0, wb0, acc, 0, 0, 0);
            acc = __builtin_amdgcn_mfma_f32_16x16x32_bf16(a1, wb1, acc, 0, 0, 0);
#pragma unroll
            for (int r = 0; r < 4; ++r) {
                int node = 16 * nt + quad * 4 + r;
                Sa[node * SA_S + nf] = f2b(tanhf(acc[r]));
            }
        }
    }
    __syncthreads();

    const u16* WTs[3]  = {W1T, W2T, W3T};
    const float* bss[3] = {b1, b2, b3};

    for (int l = 0; l < 3; ++l) {
        const u16* WT = WTs[l];
        const float* bias = bss[l];

        // ---- W-multiply: wave = ftile (wv). bfr persistent, afr streamed.
        const int nf = wv * 16 + l16;
        const float bb = bias[nf];
        bf16x8 bfr[8];
#pragma unroll
        for (int t = 0; t < 8; ++t)
            bfr[t] = *(const bf16x8*)(WT + (size_t)nf * 256 + t * 32 + quad * 8);

        for (int rt = 0; rt < 8; ++rt) {
            bf16x8 afr[8];
#pragma unroll
            for (int t = 0; t < 8; ++t)
                afr[t] = *(const bf16x8*)(Sa + (16 * rt + l16) * SA_S + t * 32 + quad * 8);
            f32x4 acc = {bb, bb, bb, bb};
#pragma unroll
            for (int t = 0; t < 8; ++t)
                acc = __builtin_amdgcn_mfma_f32_16x16x32_bf16(afr[t], bfr[t], acc, 0, 0, 0);
            u16 p0 = f2b(acc[0]), p1 = f2b(acc[1]), p2 = f2b(acc[2]), p3 = f2b(acc[3]);
            uint2 pk; pk.x = (u32)p0 | ((u32)p1 << 16); pk.y = (u32)p2 | ((u32)p3 << 16);
            *(uint2*)(Tt + (size_t)nf * TT_S + 16 * rt + quad * 4) = pk;
        }
        __syncthreads();

        // ---- A-multiply: wave = (node-tile nt, feature-half ch) ----
        for (int fj = 0; fj < 8; ++fj) {
            const int ft = ch * 8 + fj;
            bf16x8 afr[4];
#pragma unroll
            for (int t = 0; t < 4; ++t)
                afr[t] = *(const bf16x8*)(Tt + (16 * ft + l16) * TT_S + t * 32 + quad * 8);
            f32x4 acc = {0.f, 0.f, 0.f, 0.f};
#pragma unroll
            for (int t = 0; t < 4; ++t)
                acc = __builtin_amdgcn_mfma_f32_16x16x32_bf16(afr[t], bAgg[t], acc, 0, 0, 0);
            int i = nt * 16 + l16;
            u16 p0 = f2b(tanhf(acc[0])), p1 = f2b(tanhf(acc[1]));
            u16 p2 = f2b(tanhf(acc[2])), p3 = f2b(tanhf(acc[3]));
            uint2 pk; pk.x = (u32)p0 | ((u32)p1 << 16); pk.y = (u32)p2 | ((u32)p3 << 16);
            *(uint2*)(Sa + (size_t)i * SA_S + 16 * ft + quad * 4) = pk;
        }
        __syncthreads();
    }

    // ---- column max over nodes (split rows across two thread groups) ----
    const int nb = item >> 5, tt = item & 31;
    float* gdst = goaAll + ((size_t)tt * NB + nb) * GOA;
    float mymax = -2.0f;
    if (tid < 512) {
        int f = tid & 255, h = tid >> 8;
        for (int i = h * 64; i < h * 64 + 64; ++i)
            mymax = fmaxf(mymax, b2f(Sa[i * SA_S + f]));
        if (h == 1) pm[f] = mymax;
    }
    __syncthreads();
    if (tid < 256) {
        gdst[tid] = fmaxf(mymax, pm[tid]);
    } else if (tid >= 512 && tid < 524) {
        gdst[256 + (tid - 512)] = pa[(size_t)item * 12 + (tid - 512)];
    }
}

// ======================================================================
__global__ void wtrans(const float* __restrict__ Wih, const float* __restrict__ Whh,
                       const float* __restrict__ bih, const float* __restrict__ bhh,
                       float* __restrict__ wihT, float* __restrict__ whhT, float* __restrict__ bsum)
{
    int idx = blockIdx.x * 256 + threadIdx.x;
    int r = idx >> 8;
    int k = idx & 255;
    wihT[k * 1024 + r] = Wih[idx];
    whhT[k * 1024 + r] = Whh[idx];
    if (idx < 1024) bsum[idx] = bih[idx] + bhh[idx];
}

// ======================================================================
__global__ __launch_bounds__(256) void lstm_pre(
    const float* __restrict__ goaAll, const float* __restrict__ Wle, const float* __restrict__ ble,
    const float* __restrict__ wihT, const float* __restrict__ bsum,
    float* __restrict__ gatesX)
{
    __shared__ float gl[GOA];
    __shared__ float xv[256];
    const int item = blockIdx.x;          // t*NB + n
    const int u = threadIdx.x;
    const float* gsrc = goaAll + (size_t)item * GOA;
    gl[u] = gsrc[u];
    if (u < 12) gl[256 + u] = gsrc[256 + u];
    __syncthreads();

    float acc = ble[u];
    for (int k = 0; k < GOA; ++k) acc = fmaf(gl[k], Wle[k * 256 + u], acc);
    xv[u] = tanhf(acc);
    __syncthreads();

    float* gdst = gatesX + (size_t)item * 1024;
#pragma unroll
    for (int g = 0; g < 4; ++g) {
        float a = bsum[g * 256 + u];
#pragma unroll 8
        for (int k = 0; k < 256; ++k)
            a = fmaf(xv[k], wihT[k * 1024 + g * 256 + u], a);
        gdst[g * 256 + u] = a;
    }
}

// ======================================================================
__global__ __launch_bounds__(1024) void lstm_seq(
    const float* __restrict__ gatesX, const float* __restrict__ whhT,
    const int* __restrict__ relf, const float* __restrict__ lh,
    float* __restrict__ hbuf, float* __restrict__ cbuf, float* __restrict__ hout)
{
    __shared__ float hv[256];
    __shared__ float ga[1024];
    const int n = blockIdx.x, u = threadIdx.x;
    float cpriv = 0.f;
    if (u < 256) { hv[u] = lh[n * 256 + u]; cpriv = lh[16384 + n * 256 + u]; }
    __syncthreads();

    for (int t = 0; t < TS; ++t) {
        float a = gatesX[((size_t)t * NB + n) * 1024 + u];
        const float* wh = whhT + u;
#pragma unroll 8
        for (int k = 0; k < 256; ++k)
            a = fmaf(hv[k], wh[k * 1024], a);
        ga[u] = a;
        __syncthreads();
        if (u < 256) {
            float ai = ga[u], af = ga[256 + u], ag = ga[512 + u], ao = ga[768 + u];
            float cn = sigf(af) * cpriv + sigf(ai) * tanhf(ag);
            float hn = sigf(ao) * tanhf(cn);
            float kp = (relf[n * TS + t] != 0) ? 1.f : 0.f;
            if (t == TS - 1) {
                hout[n * 256 + u] = hn;
                hbuf[n * 256 + u] = hn * kp;
                cbuf[n * 256 + u] = cn * kp;
            }
            cpriv = cn * kp;
            hv[u] = hn * kp;
        }
        __syncthreads();
    }
}

// ======================================================================
__global__ __launch_bounds__(256) void heads(
    const float* __restrict__ goaAll, const float* __restrict__ hout,
    const float* __restrict__ hbuf, const float* __restrict__ cbuf,
    const float* __restrict__ Wa, const float* __restrict__ ba,
    const float* __restrict__ Wv, const float* __restrict__ bv,
    const int* __restrict__ avail, float* __restrict__ glo, float* __restrict__ out)
{
    __shared__ float gl[GLO];
    __shared__ float lg[8];
    const int n = blockIdx.x, tid = threadIdx.x;
    const float* gsrc = goaAll + ((size_t)31 * NB + n) * GOA;
    gl[tid] = hout[n * 256 + tid];
    gl[256 + tid] = gsrc[tid];
    if (tid < 12) gl[512 + tid] = gsrc[256 + tid];
    __syncthreads();

    glo[n * GLO + tid]       = gl[tid];
    glo[n * GLO + 256 + tid] = gl[256 + tid];
    if (tid < 12) glo[n * GLO + 512 + tid] = gl[512 + tid];

    out[OUT_H + n * 256 + tid]         = hbuf[n * 256 + tid];
    out[OUT_H + 16384 + n * 256 + tid] = cbuf[n * 256 + tid];

    if (tid < 8) {
        float a = ba[tid];
        for (int k = 0; k < GLO; ++k) a = fmaf(gl[k], Wa[k * 8 + tid], a);
        lg[tid] = (avail[n * 8 + tid] == 0) ? -INFINITY : a;
    } else if (tid == 8) {
        float a = bv[0];
        for (int k = 0; k < GLO; ++k) a = fmaf(gl[k], Wv[k], a);
        out[OUT_V + n] = a;
    }
    __syncthreads();
    if (tid == 0) {
        float m = -INFINITY;
        for (int a = 0; a < 8; ++a) m = fmaxf(m, lg[a]);
        float e[8], s = 0.f;
        for (int a = 0; a < 8; ++a) { e[a] = expf(lg[a] - m); s += e[a]; }
        float inv = 1.f / s;
        for (int a = 0; a < 8; ++a) out[OUT_NS + n * 8 + a] = e[a] * inv;
    }
}

// ======================================================================
// wpad_k: pad conv weights from 9 to 16B-aligned 12 floats per (co,ci)
// ======================================================================
__global__ void wpad_k(const float* __restrict__ Wc4, const float* __restrict__ Wc5,
                       float* __restrict__ wp4, float* __restrict__ wp5)
{
    int idx = blockIdx.x * 256 + threadIdx.x;   // 0 .. 73727
    int which = idx / 36864;
    int r = idx - which * 36864;
    int pair = r / 9, q = r - pair * 9;
    const float* src = which ? Wc5 : Wc4;
    float* dst = which ? wp5 : wp4;
    dst[pair * 12 + q] = src[r];
}

// ======================================================================
__global__ __launch_bounds__(256) void deconv1_k(
    const float* __restrict__ glo, const float* __restrict__ Wt1, const float* __restrict__ bt1,
    float* __restrict__ s1f)
{
    const int f = blockIdx.x;
    const int tid = threadIdx.x;
    const int n = tid >> 2, pp = tid & 3;
    float bb = bt1[f];
    float a0 = bb, a1 = bb, a2 = bb, a3 = bb;
    const float* gp = glo + n * GLO;
    for (int c = 0; c < GLO; ++c) {
        float g = gp[c];
        float4 w4 = *(const float4*)&Wt1[(((size_t)c * 256 + f) << 4) + pp * 4];
        a0 = fmaf(g, w4.x, a0);
        a1 = fmaf(g, w4.y, a1);
        a2 = fmaf(g, w4.z, a2);
        a3 = fmaf(g, w4.w, a3);
    }
    float* dst = s1f + (((size_t)n * 256 + f) << 4) + pp * 4;
    dst[0] = a0 > 0.f ? a0 : 0.1f * a0;
    dst[1] = a1 > 0.f ? a1 : 0.1f * a1;
    dst[2] = a2 > 0.f ? a2 : 0.1f * a2;
    dst[3] = a3 > 0.f ? a3 : 0.1f * a3;
}

// ======================================================================
__global__ __launch_bounds__(256) void conv2_k(
    const float* __restrict__ s1f, const float* __restrict__ Wc2, const float* __restrict__ bc2,
    u16* __restrict__ c2)
{
    __shared__ float sp[256 * 36];   // 36,864 B
    const int n = blockIdx.x >> 3, cot = blockIdx.x & 7;
    const int tid = threadIdx.x;
    for (int i = tid; i < 256 * 36; i += 256) sp[i] = 0.f;
    __syncthreads();
    for (int i = tid; i < 4096; i += 256) {
        int ci = i >> 4, p = i & 15, y = p >> 2, x = p & 3;
        sp[ci * 36 + (y + 1) * 6 + (x + 1)] = s1f[((size_t)n * 256 + ci) * 16 + p];
    }
    __syncthreads();

    const int co = cot * 16 + (tid >> 4);
    const int p = tid & 15, y = p >> 2, x = p & 3;
    float acc = bc2[co];
    const float* wp = Wc2 + (size_t)co * 256 * 9;
    for (int ci = 0; ci < 256; ++ci) {
        const float* wc = wp + ci * 9;
        const float* s = sp + ci * 36 + y * 6 + x;
#pragma unroll
        for (int ky = 0; ky < 3; ++ky) {
#pragma unroll
            for (int kx = 0; kx < 3; ++kx)
                acc = fmaf(s[ky * 6 + kx], wc[ky * 3 + kx], acc);
        }
    }
    c2[((size_t)n * 128 + co) * 16 + p] = f2b(acc);
}

// ======================================================================
// up_conv: legacy whole-image upsample+conv with dynamic LDS (c2->c3)
// ======================================================================
__global__ __launch_bounds__(256) void up_conv(
    const u16* __restrict__ in, const float* __restrict__ w, const float* __restrict__ bias,
    u16* __restrict__ out, int CIN, int CO, int H, int W, int coTiles)
{
    extern __shared__ u16 S[];
    const int tid = threadIdx.x;
    const int n  = blockIdx.x / coTiles;
    const int ct = blockIdx.x % coTiles;
    const int H2 = 2 * H, W2 = 2 * W;
    const u16* ip = in + (size_t)n * CIN * H * W;

    const int tot = CIN * H2 * W2;
    for (int i = tid; i < tot; i += 256) {
        int x2 = i % W2; int y2 = (i / W2) % H2; int ci = i / (W2 * H2);
        int y0 = (y2 - 1) >> 1; float fy = (y2 & 1) ? 0.25f : 0.75f;
        int x0 = (x2 - 1) >> 1; float fx = (x2 & 1) ? 0.25f : 0.75f;
        int y0c = y0 < 0 ? 0 : y0, y1c = y0 + 1 > H - 1 ? H - 1 : y0 + 1;
        int x0c = x0 < 0 ? 0 : x0, x1c = x0 + 1 > W - 1 ? W - 1 : x0 + 1;
        const u16* b = ip + ci * H * W;
        float v00 = b2f(b[y0c * W + x0c]), v01 = b2f(b[y0c * W + x1c]);
        float v10 = b2f(b[y1c * W + x0c]), v11 = b2f(b[y1c * W + x1c]);
        float v = (1.f - fy) * ((1.f - fx) * v00 + fx * v01)
                +        fy  * ((1.f - fx) * v10 + fx * v11);
        S[i] = f2b(fmaxf(v, 0.f));
    }
    __syncthreads();

    const int xg = W2 >> 3;
    const int units = 4 * H2 * xg;
    for (int ugl = tid; ugl < units; ugl += 256) {
        int x0p = (ugl % xg) * 8;
        int y   = (ugl / xg) % H2;
        int cp  = ugl / (xg * H2);
        int co0 = ct * 8 + cp * 2;
        float acc0[8], acc1[8];
        float bb0 = bias[co0], bb1 = bias[co0 + 1];
#pragma unroll
        for (int d = 0; d < 8; ++d) { acc0[d] = bb0; acc1[d] = bb1; }
        const float* w0 = w + (size_t)co0 * CIN * 9;
        const float* w1 = w0 + (size_t)CIN * 9;
        for (int ci = 0; ci < CIN; ++ci) {
            const u16* Sr = S + ci * H2 * W2;
            float wa[9], wb[9];
#pragma unroll
            for (int q = 0; q < 9; ++q) { wa[q] = w0[ci * 9 + q]; wb[q] = w1[ci * 9 + q]; }
#pragma unroll
            for (int ky = 0; ky < 3; ++ky) {
                int yy = y + ky - 1;
                if (yy < 0 || yy >= H2) continue;
                float seg[10];
#pragma unroll
                for (int dx = 0; dx < 10; ++dx) {
                    int xx = x0p + dx - 1;
                    seg[dx] = (xx >= 0 && xx < W2) ? b2f(Sr[yy * W2 + xx]) : 0.f;
                }
#pragma unroll
                for (int d = 0; d < 8; ++d) {
                    acc0[d] = fmaf(seg[d],     wa[ky * 3 + 0], acc0[d]);
                    acc0[d] = fmaf(seg[d + 1], wa[ky * 3 + 1], acc0[d]);
                    acc0[d] = fmaf(seg[d + 2], wa[ky * 3 + 2], acc0[d]);
                    acc1[d] = fmaf(seg[d],     wb[ky * 3 + 0], acc1[d]);
                    acc1[d] = fmaf(seg[d + 1], wb[ky * 3 + 1], acc1[d]);
                    acc1[d] = fmaf(seg[d + 2], wb[ky * 3 + 2], acc1[d]);
                }
            }
        }
        u16* op0 = out + (((size_t)(n * CO + co0) * H2) + y) * W2 + x0p;
        u16* op1 = op0 + (size_t)H2 * W2;
#pragma unroll
        for (int d = 0; d < 8; ++d) { op0[d] = f2b(acc0[d]); op1[d] = f2b(acc1[d]); }
    }
}

// ======================================================================
// up_conv_b: banded upsample+conv with halo-in-LDS layout
// ======================================================================
template<int CIN, int HI, int WI, int BH, int DW, int COT, int CO>
__global__ __launch_bounds__(256) void up_conv_b(
    const u16* __restrict__ in, const float* __restrict__ wpad, const float* __restrict__ bias,
    u16* __restrict__ out)
{
    constexpr int H2 = 2 * HI, W2 = 2 * WI;
    constexpr int XG = W2 / DW;
    constexpr int ROWS = BH + 2;
    constexpr int STR = W2 + 2;            // even, odd bank count
    constexpr int NBAND = H2 / BH;
    constexpr int CT = CO / COT;
    constexpr int PAIRS = COT / 2;
    static_assert(XG * BH * PAIRS == 256, "thread map must cover block");
    static_assert((STR & 1) == 0, "u32 LDS reads need even u16 stride");

    __shared__ u16 S[CIN * ROWS * STR];

    const int tid = threadIdx.x;
    int b = blockIdx.x;
    const int ct = b % CT; b /= CT;
    const int band = b % NBAND;
    const int n = b / NBAND;
    const int r0 = band * BH;

    const u16* ip = in + (size_t)n * CIN * HI * WI;

    // stage: bilinear x2 upsample + relu, zero halo (y and x), bf16
    for (int i = tid; i < CIN * ROWS * STR; i += 256) {
        int x  = i % STR;
        int ry = (i / STR) % ROWS;
        int ci = i / (STR * ROWS);
        int yy = r0 - 1 + ry;
        int xx = x - 1;
        float v = 0.f;
        if (yy >= 0 && yy < H2 && xx >= 0 && xx < W2) {
            int y0 = (yy - 1) >> 1; float fy = (yy & 1) ? 0.25f : 0.75f;
            int x0 = (xx - 1) >> 1; float fx = (xx & 1) ? 0.25f : 0.75f;
            int y0c = y0 < 0 ? 0 : y0, y1c = y0 + 1 > HI - 1 ? HI - 1 : y0 + 1;
            int x0c = x0 < 0 ? 0 : x0, x1c = x0 + 1 > WI - 1 ? WI - 1 : x0 + 1;
            const u16* bp = ip + ci * HI * WI;
            float v00 = b2f(bp[y0c * WI + x0c]), v01 = b2f(bp[y0c * WI + x1c]);
            float v10 = b2f(bp[y1c * WI + x0c]), v11 = b2f(bp[y1c * WI + x1c]);
            v = (1.f - fy) * ((1.f - fx) * v00 + fx * v01)
              +        fy  * ((1.f - fx) * v10 + fx * v11);
            v = fmaxf(v, 0.f);
        }
        S[i] = f2b(v);
    }
    __syncthreads();

    const int xg = tid % XG;
    const int y  = (tid / XG) % BH;
    const int pr = tid / (XG * BH);
    const int co0 = ct * COT + pr * 2;
    const int x0 = xg * DW;
    const int yo = r0 + y;

    float acc0[DW], acc1[DW];
    const float bb0 = bias[co0], bb1 = bias[co0 + 1];
#pragma unroll
    for (int d = 0; d < DW; ++d) { acc0[d] = bb0; acc1[d] = bb1; }

    const float* wp0 = wpad + (size_t)(co0 * CIN) * 12;
    const float* wp1 = wpad + (size_t)((co0 + 1) * CIN) * 12;

    for (int ci = 0; ci < CIN; ++ci) {
        float wa[9], wb[9];
        {
            const float4* av = (const float4*)(wp0 + ci * 12);
            float4 a0 = av[0], a1 = av[1], a2 = av[2];
            wa[0] = a0.x; wa[1] = a0.y; wa[2] = a0.z; wa[3] = a0.w;
            wa[4] = a1.x; wa[5] = a1.y; wa[6] = a1.z; wa[7] = a1.w; wa[8] = a2.x;
            const float4* bv = (const float4*)(wp1 + ci * 12);
            float4 b0 = bv[0], b1 = bv[1], b2v = bv[2];
            wb[0] = b0.x; wb[1] = b0.y; wb[2] = b0.z; wb[3] = b0.w;
            wb[4] = b1.x; wb[5] = b1.y; wb[6] = b1.z; wb[7] = b1.w; wb[8] = b2v.x;
        }
#pragma unroll
        for (int ky = 0; ky < 3; ++ky) {
            const u32* Sr = (const u32*)(S + ci * ROWS * STR + (y + ky) * STR + x0);
            float seg[DW + 2];
#pragma unroll
            for (int k = 0; k < (DW + 2) / 2; ++k) {
                u32 u = Sr[k];
                seg[2 * k]     = b2f_lo(u);
                seg[2 * k + 1] = b2f_hi(u);
            }
#pragma unroll
            for (int d = 0; d < DW; ++d) {
                acc0[d] = fmaf(seg[d],     wa[ky * 3 + 0], acc0[d]);
                acc0[d] = fmaf(seg[d + 1], wa[ky * 3 + 1], acc0[d]);
                acc0[d] = fmaf(seg[d + 2], wa[ky * 3 + 2], acc0[d]);
                acc1[d] = fmaf(seg[d],     wb[ky * 3 + 0], acc1[d]);
                acc1[d] = fmaf(seg[d + 1], wb[ky * 3 + 1], acc1[d]);
                acc1[d] = fmaf(seg[d + 2], wb[ky * 3 + 2], acc1[d]);
            }
        }
    }

    u16* op0 = out + (((size_t)(n * CO + co0) * H2) + yo) * W2 + x0;
    u16* op1 = op0 + (size_t)H2 * W2;
#pragma unroll
    for (int d = 0; d < DW; d += 2) {
        u32 p0 = (u32)f2b(acc0[d]) | ((u32)f2b(acc0[d + 1]) << 16);
        u32 p1 = (u32)f2b(acc1[d]) | ((u32)f2b(acc1[d + 1]) << 16);
        *(u32*)(op0 + d) = p0;
        *(u32*)(op1 + d) = p1;
    }
}

// ======================================================================
// up_conv6: 4-wide units so all 256 threads compute (CO=2 final conv)
// ======================================================================
__global__ __launch_bounds__(256) void up_conv6(
    const u16* __restrict__ c5, const float* __restrict__ w, const float* __restrict__ bias,
    u16* __restrict__ sl)
{
    __shared__ u16 S[40960];
    const int tid = threadIdx.x;
    const int n = blockIdx.x >> 3;
    const int band = blockIdx.x & 7;
    const int r0 = band * 8;
    const u16* ip = c5 + (size_t)n * 64 * 1024;

    for (int i = tid; i < 40960; i += 256) {
        int x2 = i & 63; int ry = (i >> 6) % 10; int ci = i / 640;
        int yy = r0 - 1 + ry;
        float v = 0.f;
        if (yy >= 0 && yy < 64) {
            int y0 = (yy - 1) >> 1; float fy = (yy & 1) ? 0.25f : 0.75f;
            int x0 = (x2 - 1) >> 1; float fx = (x2 & 1) ? 0.25f : 0.75f;
            int y0c = y0 < 0 ? 0 : y0, y1c = y0 + 1 > 31 ? 31 : y0 + 1;
            int x0c = x0 < 0 ? 0 : x0, x1c = x0 + 1 > 31 ? 31 : x0 + 1;
            const u16* b = ip + ci * 1024;
            float v00 = b2f(b[y0c * 32 + x0c]), v01 = b2f(b[y0c * 32 + x1c]);
            float v10 = b2f(b[y1c * 32 + x0c]), v11 = b2f(b[y1c * 32 + x1c]);
            v = fmaxf((1.f - fy) * ((1.f - fx) * v00 + fx * v01)
                      +      fy  * ((1.f - fx) * v10 + fx * v11), 0.f);
        }
        S[i] = f2b(v);
    }
    __syncthreads();

    {
        const int u = tid;                  // 256 units: 2co x 8y x 16xg(4-wide)
        const int x0p = (u & 15) * 4;
        const int yr  = (u >> 4) & 7;
        const int co  = u >> 7;
        const int y = r0 + yr;
        float acc[4];
        float bb = bias[co];
#pragma unroll
        for (int d = 0; d < 4; ++d) acc[d] = bb;
        const float* wp = w + (size_t)co * 64 * 9;
        for (int ci = 0; ci < 64; ++ci) {
            const u16* Sr = S + ci * 640;
            float wk[9];
#pragma unroll
            for (int q = 0; q < 9; ++q) wk[q] = wp[ci * 9 + q];
#pragma unroll
            for (int ky = 0; ky < 3; ++ky) {
                int ry = yr + ky;
                float seg[6];
#pragma unroll
                for (int dx = 0; dx < 6; ++dx) {
                    int xx = x0p + dx - 1;
                    seg[dx] = (xx >= 0 && xx < 64) ? b2f(Sr[ry * 64 + xx]) : 0.f;
                }
#pragma unroll
                for (int d = 0; d < 4; ++d) {
                    acc[d] = fmaf(seg[d],     wk[ky * 3 + 0], acc[d]);
                    acc[d] = fmaf(seg[d + 1], wk[ky * 3 + 1], acc[d]);
                    acc[d] = fmaf(seg[d + 2], wk[ky * 3 + 2], acc[d]);
                }
            }
        }
        u16* op = sl + (size_t)(n * 2 + co) * 4096 + y * 64 + x0p;
#pragma unroll
        for (int d = 0; d < 4; ++d) op[d] = f2b(acc[d]);
    }
}

// ======================================================================
__global__ __launch_bounds__(256) void softmax_spatial(const u16* __restrict__ sl, float* __restrict__ out)
{
    __shared__ float red[256];
    const int b = blockIdx.x;
    const u16* src = sl + (size_t)b * 4096;
    float* dst = out + (size_t)b * 4096;
    const int tid = threadIdx.x;
    float m = -INFINITY;
    for (int i = tid; i < 4096; i += 256) m = fmaxf(m, b2f(src[i]));
    red[tid] = m; __syncthreads();
    for (int s = 128; s > 0; s >>= 1) { if (tid < s) red[tid] = fmaxf(red[tid], red[tid + s]); __syncthreads(); }
    m = red[0]; __syncthreads();
    float sum = 0.f;
    for (int i = tid; i < 4096; i += 256) sum += expf(b2f(src[i]) - m);
    red[tid] = sum; __syncthreads();
    for (int s = 128; s > 0; s >>= 1) { if (tid < s) red[tid] += red[tid + s]; __syncthreads(); }
    float inv = 1.f / red[0];
    for (int i = tid; i < 4096; i += 256) dst[i] = expf(b2f(src[i]) - m) * inv;
}

// ======================================================================
extern "C" void kernel_launch(void* const* d_in, const int* in_sizes, int n_in,
                              void* d_out, int out_size, void* d_ws, size_t ws_size,
                              hipStream_t stream)
{
    const float* G     = (const float*)d_in[0];
    const float* X     = (const float*)d_in[1];
    const int*   avail = (const int*)d_in[2];
    const float* lh    = (const float*)d_in[3];
    const float* pa    = (const float*)d_in[4];
    const int*   relf  = (const int*)d_in[5];
    const float* We  = (const float*)d_in[6];   const float* be  = (const float*)d_in[7];
    const float* W1  = (const float*)d_in[8];   const float* b1  = (const float*)d_in[9];
    const float* W2  = (const float*)d_in[10];  const float* b2  = (const float*)d_in[11];
    const float* W3  = (const float*)d_in[12];  const float* b3  = (const float*)d_in[13];
    const float* Wle = (const float*)d_in[14];  const float* ble = (const float*)d_in[15];
    const float* Wih = (const float*)d_in[16];  const float* Whh = (const float*)d_in[17];
    const float* bih = (const float*)d_in[18];  const float* bhh = (const float*)d_in[19];
    const float* Wa  = (const float*)d_in[20];  const float* ba  = (const float*)d_in[21];
    const float* Wv  = (const float*)d_in[22];  const float* bv  = (const float*)d_in[23];
    const float* Wt1 = (const float*)d_in[24];  const float* bt1 = (const float*)d_in[25];
    const float* Wc2 = (const float*)d_in[26];  const float* bc2 = (const float*)d_in[27];
    const float* Wc3 = (const float*)d_in[28];  const float* bc3 = (const float*)d_in[29];
    const float* Wc4 = (const float*)d_in[30];  const float* bc4 = (const float*)d_in[31];
    const float* Wc5 = (const float*)d_in[32];  const float* bc5 = (const float*)d_in[33];
    const float* Wc6 = (const float*)d_in[34];  const float* bc6 = (const float*)d_in[35];

    char* ws = (char*)d_ws;
    float* goaAll = (float*)(ws + WS_GOA);
    float* hbuf   = (float*)(ws + WS_HBUF);
    float* cbuf   = (float*)(ws + WS_CBUF);
    float* hout   = (float*)(ws + WS_HOUT);
    float* glo    = (float*)(ws + WS_GLO);
    float* wihT   = (float*)(ws + WS_WIHT);
    float* whhT   = (float*)(ws + WS_WHHT);
    float* bsum   = (float*)(ws + WS_BSUM);
    u16*   c2     = (u16*)(ws + WS_C2);
    u16*   c3     = (u16*)(ws + WS_C3);
    u16*   c4     = (u16*)(ws + WS_C4);
    u16*   c5     = (u16*)(ws + WS_C5);
    u16*   sl     = (u16*)(ws + WS_SL);
    u16*   WeT    = (u16*)(ws + WS_WET);
    u16*   W1T    = (u16*)(ws + WS_W1T);
    u16*   W2T    = (u16*)(ws + WS_W2T);
    u16*   W3T    = (u16*)(ws + WS_W3T);
    float* gatesX = (float*)(ws + WS_GX);
    float* s1f    = (float*)(ws + WS_S1F);
    float* wp4    = (float*)(ws + WS_WP4);
    float* wp5    = (float*)(ws + WS_WP5);
    float* out    = (float*)d_out;     // OUTPUT IS FLOAT32

    wprep<<<256, 256, 0, stream>>>(We, W1, W2, W3, WeT, W1T, W2T, W3T);
    wtrans<<<1024, 256, 0, stream>>>(Wih, Whh, bih, bhh, wihT, whhT, bsum);
    gcn_mfma<<<2048, 1024, 0, stream>>>(G, X, pa, WeT, be, W1T, b1, W2T, b2, W3T, b3, goaAll);
    lstm_pre<<<2048, 256, 0, stream>>>(goaAll, Wle, ble, wihT, bsum, gatesX);
    lstm_seq<<<64, 1024, 0, stream>>>(gatesX, whhT, relf, lh, hbuf, cbuf, hout);
    heads<<<64, 256, 0, stream>>>(goaAll, hout, hbuf, cbuf, Wa, ba, Wv, bv, avail, glo, out);
    // goaAll is dead from here; reuse its region for padded conv weights
    wpad_k<<<288, 256, 0, stream>>>(Wc4, Wc5, wp4, wp5);
    deconv1_k<<<256, 256, 0, stream>>>(glo, Wt1, bt1, s1f);
    conv2_k<<<512, 256, 0, stream>>>(s1f, Wc2, bc2, c2);
    // c2->c3: legacy kernel, dynamic LDS = 128*8*8*2 = 16 KB
    up_conv<<<512, 256, 16384, stream>>>(c2, Wc3, bc3, c3, 128, 64, 4, 4, 8);
    // c3->c4: banded, 64ci, 8x8->16x16, BH=4, DW=4, COT=32 -> grid 64*4*2
    up_conv_b<64, 8, 8, 4, 4, 32, 64><<<512, 256, 0, stream>>>(c3, wp4, bc4, c4);
    // c4->c5: banded, 64ci, 16x16->32x32, BH=4, DW=8, COT=32 -> grid 64*8*2
    up_conv_b<64, 16, 16, 4, 8, 32, 64><<<1024, 256, 0, stream>>>(c4, wp5, bc5, c5);
    up_conv6<<<512, 256, 0, stream>>>(c5, Wc6, bc6, sl);
    softmax_spatial<<<128, 256, 0, stream>>>(sl, out + OUT_SPATIAL);
}

// Round 4
// 1529.385 us; speedup vs baseline: 1.1303x; 1.0290x over previous
//
#include <hip/hip_runtime.h>
#include <math.h>

typedef unsigned short u16;
typedef unsigned int u32;

typedef __attribute__((ext_vector_type(8))) short bf16x8;
typedef __attribute__((ext_vector_type(4))) float f32x4;

// ---------- bf16 helpers (intermediates only; I/O is f32) ----------
__device__ __forceinline__ float b2f(u16 u) {
    union { u32 ui; float f; } v; v.ui = ((u32)u) << 16; return v.f;
}
__device__ __forceinline__ float b2f_lo(u32 u) {
    union { u32 ui; float f; } v; v.ui = u << 16; return v.f;
}
__device__ __forceinline__ float b2f_hi(u32 u) {
    union { u32 ui; float f; } v; v.ui = u & 0xffff0000u; return v.f;
}
__device__ __forceinline__ u16 f2b(float f) {
    union { float f; u32 ui; } v; v.f = f;
    u32 x = v.ui;
    u32 r = (x + 0x7fffu + ((x >> 16) & 1u)) >> 16;
    return (u16)r;
}
__device__ __forceinline__ float sigf(float x) { return 1.0f / (1.0f + expf(-x)); }
// fast tanh: error ~1e-6, always followed by bf16 rounding (ulp ~4e-3 rel)
__device__ __forceinline__ float ftanh(float x) {
    float e = __expf(2.0f * x);
    return 1.0f - 2.0f / (e + 1.0f);
}

// ---------- problem constants ----------
#define GNODES 128
#define EMBD   256
#define NB     64
#define TS     32
#define GOA    268
#define GLO    524

// output layout (f32 elements)
#define OUT_SPATIAL 0
#define OUT_NS      524288
#define OUT_V       524800
#define OUT_H       524864

// workspace byte offsets
#define WS_GOA   ((size_t)0)
#define WS_HBUF  ((size_t)2195456)
#define WS_CBUF  ((size_t)2260992)
#define WS_HOUT  ((size_t)2326528)
#define WS_GLO   ((size_t)2392064)
#define WS_WIHT  ((size_t)2526208)
#define WS_WHHT  ((size_t)3574784)
#define WS_BSUM  ((size_t)4623360)
#define WS_C2    ((size_t)4627456)
#define WS_C3    ((size_t)4889600)
#define WS_C4    ((size_t)5413888)
#define WS_C5    ((size_t)7511040)
#define WS_SL    ((size_t)15899648)
#define WS_WET   ((size_t)16948224)   // 256*64 bf16
#define WS_W1T   ((size_t)16980992)   // 256*256 bf16
#define WS_W2T   ((size_t)17112064)
#define WS_W3T   ((size_t)17243136)
#define WS_GX    ((size_t)17374208)   // 2048*1024 f32 = 8,388,608
#define WS_S1F   ((size_t)25762816)   // 64*4096 f32 = 1,048,576 -> end 26,811,392

// padded conv weights live in the goaAll region (dead after `heads`,
// fully rewritten by gcn_mfma next iteration).
// wp4: 64*64*12*4 = 196,608 ; wp5: same ; wp3: 64*128*12*4 = 393,216
#define WS_WP4   WS_GOA
#define WS_WP5   (WS_GOA + (size_t)196608)
#define WS_WP3   (WS_GOA + (size_t)393216)   // end 786,432 < 2,195,456

// LDS strides (elements)
#define SA_S 264
#define TT_S 136
#define XS_S 72

// ======================================================================
// weight prep: transpose + bf16-cast GCN weights
// ======================================================================
__global__ void wprep(const float* __restrict__ We, const float* __restrict__ W1,
                      const float* __restrict__ W2, const float* __restrict__ W3,
                      u16* __restrict__ WeT, u16* __restrict__ W1T,
                      u16* __restrict__ W2T, u16* __restrict__ W3T)
{
    int idx = blockIdx.x * 256 + threadIdx.x;
    if (idx < 16384) {
        int k = idx >> 8, nn = idx & 255;
        WeT[nn * 64 + k] = f2b(We[idx]);
    }
    {
        int k = idx >> 8, nn = idx & 255;
        W1T[nn * 256 + k] = f2b(W1[idx]);
        W2T[nn * 256 + k] = f2b(W2[idx]);
        W3T[nn * 256 + k] = f2b(W3[idx]);
    }
}

// ======================================================================
// GCN via MFMA — 1024 threads (16 waves), 1 item per block.
// LDS ~140KB forces 1 block/CU; 16 waves -> 4 waves/SIMD (50% occ).
// launch_bounds(1024,4) -> 128-VGPR cap.
//   W-mult : wave = (ftile-pair fp=wv&7, rt-half rh=wv>>3).
//            bfr0/bfr1[8] persistent from GLOBAL W (64 VGPR); afr
//            streamed one k-tile at a time, feeds 2 MFMA chains.
//   A-mult : wave = (node-tile nt=wv&7, feature-half ch=wv>>3)
// ======================================================================
__global__ __launch_bounds__(1024, 4) void gcn_mfma(
    const float* __restrict__ G, const float* __restrict__ X, const float* __restrict__ pa,
    const u16* __restrict__ WeT, const float* __restrict__ be,
    const u16* __restrict__ W1T, const float* __restrict__ b1,
    const u16* __restrict__ W2T, const float* __restrict__ b2,
    const u16* __restrict__ W3T, const float* __restrict__ b3,
    float* __restrict__ goaAll)
{
    __shared__ u16 Sa[128 * SA_S];
    __shared__ u16 Tt[256 * TT_S];
    __shared__ float dis[GNODES];
    __shared__ float dred[1024];
    __shared__ float pm[256];

    const int item = blockIdx.x;
    const int tid  = threadIdx.x;
    const int wv   = tid >> 6;        // 0..15
    const int nt   = wv & 7;          // node tile (A-mult / emb)
    const int ch   = wv >> 3;         // half index (A-mult / emb)
    const int lane = tid & 63;
    const int l16  = lane & 15;
    const int quad = lane >> 4;
    const float* Gp = G + (size_t)item * GNODES * GNODES;
    const float* Xp = X + (size_t)item * GNODES * 64;

    // stage X -> Tt (bf16), and degree partial sums (8 threads/row)
    for (int idx = tid; idx < 128 * 64; idx += 1024) {
        int m = idx >> 6, k = idx & 63;
        Tt[m * XS_S + k] = f2b(Xp[idx]);
    }
    {
        int row = tid >> 3, part = tid & 7;
        const float4* gr = (const float4*)(Gp + (size_t)row * GNODES) + part * 4;
        float s = 0.f;
#pragma unroll
        for (int k = 0; k < 4; ++k) { float4 g = gr[k]; s += g.x + g.y + g.z + g.w; }
        dred[tid] = s;
    }
    __syncthreads();
    if (tid < GNODES) {
        float s = 0.f;
#pragma unroll
        for (int p = 0; p < 8; ++p) s += dred[tid * 8 + p];
        dis[tid] = 1.0f / sqrtf(s + 1.0f);
    }
    __syncthreads();

    // bAgg: normalized adjacency fragments for node-tile nt (dup across ch)
    bf16x8 bAgg[4];
    {
        const int i = nt * 16 + l16;
        const float di = dis[i];
        const float* gr = Gp + (size_t)i * GNODES;
#pragma unroll
        for (int t = 0; t < 4; ++t) {
            const int k0 = t * 32 + quad * 8;
            float4 ga = *(const float4*)(gr + k0);
            float4 gb = *(const float4*)(gr + k0 + 4);
            float vv[8] = {ga.x, ga.y, ga.z, ga.w, gb.x, gb.y, gb.z, gb.w};
            bf16x8 f;
#pragma unroll
            for (int j = 0; j < 8; ++j) {
                int k = k0 + j;
                float a = (vv[j] + (k == i ? 1.0f : 0.0f)) * di * dis[k];
                f[j] = (short)f2b(a);
            }
            bAgg[t] = f;
        }
    }

    // emb = tanh(X @ We + be): wave = (node-tile nt, feature-half ch)
    {
        bf16x8 a0 = *(const bf16x8*)(Tt + (16 * nt + l16) * XS_S + quad * 8);
        bf16x8 a1 = *(const bf16x8*)(Tt + (16 * nt + l16) * XS_S + 32 + quad * 8);
        for (int cj = 0; cj < 8; ++cj) {
            const int ct = ch * 8 + cj;
            const int nf = ct * 16 + l16;
            bf16x8 wb0 = *(const bf16x8*)(WeT + nf * 64 + quad * 8);
            bf16x8 wb1 = *(const bf16x8*)(WeT + nf * 64 + 32 + quad * 8);
            float bb = be[nf];
            f32x4 acc = {bb, bb, bb, bb};
            acc = __builtin_amdgcn_mfma_f32_16x16x32_bf16(a0, wb0, acc, 0, 0, 0);
            acc = __builtin_amdgcn_mfma_f32_16x16x32_bf16(a1, wb1, acc, 0, 0, 0);
#pragma unroll
            for (int r = 0; r < 4; ++r) {
                int node = 16 * nt + quad * 4 + r;
                Sa[node * SA_S + nf] = f2b(ftanh(acc[r]));
            }
        }
    }
    __syncthreads();

    const u16* WTs[3]  = {W1T, W2T, W3T};
    const float* bss[3] = {b1, b2, b3};

    for (int l = 0; l < 3; ++l) {
        const u16* WT = WTs[l];
        const float* bias = bss[l];

        // ---- W-multiply: wave = (ftile-pair fp, rt-half rh) ----
        const int fp = wv & 7;
        const int rh = wv >> 3;
        const int nf0 = (2 * fp) * 16 + l16;
        const int nf1 = (2 * fp + 1) * 16 + l16;
        bf16x8 bfr0[8], bfr1[8];
#pragma unroll
        for (int t = 0; t < 8; ++t) {
            bfr0[t] = *(const bf16x8*)(WT + (size_t)nf0 * 256 + t * 32 + quad * 8);
            bfr1[t] = *(const bf16x8*)(WT + (size_t)nf1 * 256 + t * 32 + quad * 8);
        }
        const float bb0 = bias[nf0], bb1 = bias[nf1];

        for (int rj = 0; rj < 4; ++rj) {
            const int rt = rh * 4 + rj;
            f32x4 acc0 = {bb0, bb0, bb0, bb0};
            f32x4 acc1 = {bb1, bb1, bb1, bb1};
#pragma unroll
            for (int t = 0; t < 8; ++t) {
                bf16x8 afr = *(const bf16x8*)(Sa + (16 * rt + l16) * SA_S + t * 32 + quad * 8);
                acc0 = __builtin_amdgcn_mfma_f32_16x16x32_bf16(afr, bfr0[t], acc0, 0, 0, 0);
                acc1 = __builtin_amdgcn_mfma_f32_16x16x32_bf16(afr, bfr1[t], acc1, 0, 0, 0);
            }
            {
                u16 p0 = f2b(acc0[0]), p1 = f2b(acc0[1]), p2 = f2b(acc0[2]), p3 = f2b(acc0[3]);
                uint2 pk; pk.x = (u32)p0 | ((u32)p1 << 16); pk.y = (u32)p2 | ((u32)p3 << 16);
                *(uint2*)(Tt + (size_t)nf0 * TT_S + 16 * rt + quad * 4) = pk;
            }
            {
                u16 p0 = f2b(acc1[0]), p1 = f2b(acc1[1]), p2 = f2b(acc1[2]), p3 = f2b(acc1[3]);
                uint2 pk; pk.x = (u32)p0 | ((u32)p1 << 16); pk.y = (u32)p2 | ((u32)p3 << 16);
                *(uint2*)(Tt + (size_t)nf1 * TT_S + 16 * rt + quad * 4) = pk;
            }
        }
        __syncthreads();

        // ---- A-multiply: wave = (node-tile nt, feature-half ch) ----
        for (int fj = 0; fj < 8; ++fj) {
            const int ft = ch * 8 + fj;
            bf16x8 afr[4];
#pragma unroll
            for (int t = 0; t < 4; ++t)
                afr[t] = *(const bf16x8*)(Tt + (16 * ft + l16) * TT_S + t * 32 + quad * 8);
            f32x4 acc = {0.f, 0.f, 0.f, 0.f};
#pragma unroll
            for (int t = 0; t < 4; ++t)
                acc = __builtin_amdgcn_mfma_f32_16x16x32_bf16(afr[t], bAgg[t], acc, 0, 0, 0);
            int i = nt * 16 + l16;
            u16 p0 = f2b(ftanh(acc[0])), p1 = f2b(ftanh(acc[1]));
            u16 p2 = f2b(ftanh(acc[2])), p3 = f2b(ftanh(acc[3]));
            uint2 pk; pk.x = (u32)p0 | ((u32)p1 << 16); pk.y = (u32)p2 | ((u32)p3 << 16);
            *(uint2*)(Sa + (size_t)i * SA_S + 16 * ft + quad * 4) = pk;
        }
        __syncthreads();
    }

    // ---- column max over nodes (split rows across two thread groups) ----
    const int nb = item >> 5, tt = item & 31;
    float* gdst = goaAll + ((size_t)tt * NB + nb) * GOA;
    float mymax = -2.0f;
    if (tid < 512) {
        int f = tid & 255, h = tid >> 8;
        for (int i = h * 64; i < h * 64 + 64; ++i)
            mymax = fmaxf(mymax, b2f(Sa[i * SA_S + f]));
        if (h == 1) pm[f] = mymax;
    }
    __syncthreads();
    if (tid < 256) {
        gdst[tid] = fmaxf(mymax, pm[tid]);
    } else if (tid >= 512 && tid < 524) {
        gdst[256 + (tid - 512)] = pa[(size_t)item * 12 + (tid - 512)];
    }
}

// ======================================================================
__global__ void wtrans(const float* __restrict__ Wih, const float* __restrict__ Whh,
                       const float* __restrict__ bih, const float* __restrict__ bhh,
                       float* __restrict__ wihT, float* __restrict__ whhT, float* __restrict__ bsum)
{
    int idx = blockIdx.x * 256 + threadIdx.x;
    int r = idx >> 8;
    int k = idx & 255;
    wihT[k * 1024 + r] = Wih[idx];
    whhT[k * 1024 + r] = Whh[idx];
    if (idx < 1024) bsum[idx] = bih[idx] + bhh[idx];
}

// ======================================================================
// lstm_pre: 8 items per block; each weight element loaded once and
// reused 8x in registers. 256 blocks x 256 threads. Bit-exact per-item
// FMA order vs the old kernel.
// ======================================================================
#define LP_IT 8
__global__ __launch_bounds__(256) void lstm_pre(
    const float* __restrict__ goaAll, const float* __restrict__ Wle, const float* __restrict__ ble,
    const float* __restrict__ wihT, const float* __restrict__ bsum,
    float* __restrict__ gatesX)
{
    __shared__ float gl[LP_IT][GOA];
    __shared__ float xv[LP_IT][256];
    const int b0 = blockIdx.x * LP_IT;
    const int u = threadIdx.x;

    for (int idx = u; idx < LP_IT * GOA; idx += 256) {
        int it = idx / GOA, k = idx - it * GOA;
        gl[it][k] = goaAll[(size_t)(b0 + it) * GOA + k];
    }
    __syncthreads();

    {
        float acc[LP_IT];
        float bl = ble[u];
#pragma unroll
        for (int i = 0; i < LP_IT; ++i) acc[i] = bl;
        for (int k = 0; k < GOA; ++k) {
            float w = Wle[k * 256 + u];
#pragma unroll
            for (int i = 0; i < LP_IT; ++i) acc[i] = fmaf(gl[i][k], w, acc[i]);
        }
#pragma unroll
        for (int i = 0; i < LP_IT; ++i) xv[i][u] = tanhf(acc[i]);
    }
    __syncthreads();

#pragma unroll
    for (int g = 0; g < 4; ++g) {
        float a[LP_IT];
        float bs = bsum[g * 256 + u];
#pragma unroll
        for (int i = 0; i < LP_IT; ++i) a[i] = bs;
#pragma unroll 4
        for (int k = 0; k < 256; ++k) {
            float w = wihT[k * 1024 + g * 256 + u];
#pragma unroll
            for (int i = 0; i < LP_IT; ++i) a[i] = fmaf(xv[i][k], w, a[i]);
        }
#pragma unroll
        for (int i = 0; i < LP_IT; ++i)
            gatesX[(size_t)(b0 + i) * 1024 + g * 256 + u] = a[i];
    }
}

// ======================================================================
// lstm_seq: h-recurrence with zero-skip. When relf==0 the hidden state
// is zeroed, so the next step's whhT matvec is exactly zero -> skip it
// (block-uniform branch, bit-exact).
// ======================================================================
__global__ __launch_bounds__(1024) void lstm_seq(
    const float* __restrict__ gatesX, const float* __restrict__ whhT,
    const int* __restrict__ relf, const float* __restrict__ lh,
    float* __restrict__ hbuf, float* __restrict__ cbuf, float* __restrict__ hout)
{
    __shared__ float hv[256];
    __shared__ float ga[1024];
    __shared__ int hzf;
    const int n = blockIdx.x, u = threadIdx.x;
    float cpriv = 0.f;
    if (u < 256) { hv[u] = lh[n * 256 + u]; cpriv = lh[16384 + n * 256 + u]; }
    if (u == 0) hzf = 0;
    __syncthreads();

    for (int t = 0; t < TS; ++t) {
        float a = gatesX[((size_t)t * NB + n) * 1024 + u];
        if (!hzf) {
            const float* wh = whhT + u;
#pragma unroll 8
            for (int k = 0; k < 256; ++k)
                a = fmaf(hv[k], wh[k * 1024], a);
        }
        ga[u] = a;
        __syncthreads();
        if (u < 256) {
            float ai = ga[u], af = ga[256 + u], ag = ga[512 + u], ao = ga[768 + u];
            float cn = sigf(af) * cpriv + sigf(ai) * tanhf(ag);
            float hn = sigf(ao) * tanhf(cn);
            float kp = (relf[n * TS + t] != 0) ? 1.f : 0.f;
            if (t == TS - 1) {
                hout[n * 256 + u] = hn;
                hbuf[n * 256 + u] = hn * kp;
                cbuf[n * 256 + u] = cn * kp;
            }
            cpriv = cn * kp;
            hv[u] = hn * kp;
        }
        if (u == 0) hzf = (relf[n * TS + t] != 0) ? 0 : 1;
        __syncthreads();
    }
}

// ======================================================================
__global__ __launch_bounds__(256) void heads(
    const float* __restrict__ goaAll, const float* __restrict__ hout,
    const float* __restrict__ hbuf, const float* __restrict__ cbuf,
    const float* __restrict__ Wa, const float* __restrict__ ba,
    const float* __restrict__ Wv, const float* __restrict__ bv,
    const int* __restrict__ avail, float* __restrict__ glo, float* __restrict__ out)
{
    __shared__ float gl[GLO];
    __shared__ float lg[8];
    const int n = blockIdx.x, tid = threadIdx.x;
    const float* gsrc = goaAll + ((size_t)31 * NB + n) * GOA;
    gl[tid] = hout[n * 256 + tid];
    gl[256 + tid] = gsrc[tid];
    if (tid < 12) gl[512 + tid] = gsrc[256 + tid];
    __syncthreads();

    glo[n * GLO + tid]       = gl[tid];
    glo[n * GLO + 256 + tid] = gl[256 + tid];
    if (tid < 12) glo[n * GLO + 512 + tid] = gl[512 + tid];

    out[OUT_H + n * 256 + tid]         = hbuf[n * 256 + tid];
    out[OUT_H + 16384 + n * 256 + tid] = cbuf[n * 256 + tid];

    if (tid < 8) {
        float a = ba[tid];
        for (int k = 0; k < GLO; ++k) a = fmaf(gl[k], Wa[k * 8 + tid], a);
        lg[tid] = (avail[n * 8 + tid] == 0) ? -INFINITY : a;
    } else if (tid == 8) {
        float a = bv[0];
        for (int k = 0; k < GLO; ++k) a = fmaf(gl[k], Wv[k], a);
        out[OUT_V + n] = a;
    }
    __syncthreads();
    if (tid == 0) {
        float m = -INFINITY;
        for (int a = 0; a < 8; ++a) m = fmaxf(m, lg[a]);
        float e[8], s = 0.f;
        for (int a = 0; a < 8; ++a) { e[a] = expf(lg[a] - m); s += e[a]; }
        float inv = 1.f / s;
        for (int a = 0; a < 8; ++a) out[OUT_NS + n * 8 + a] = e[a] * inv;
    }
}

// ======================================================================
// wpad_k: pad conv weights from 9 to 16B-aligned 12 floats per (co,ci)
// for Wc4 (36864), Wc5 (36864), Wc3 (73728). grid 576x256 = 147456.
// ======================================================================
__global__ void wpad_k(const float* __restrict__ Wc4, const float* __restrict__ Wc5,
                       const float* __restrict__ Wc3,
                       float* __restrict__ wp4, float* __restrict__ wp5,
                       float* __restrict__ wp3)
{
    int idx = blockIdx.x * 256 + threadIdx.x;
    const float* src; float* dst; int r;
    if (idx < 36864)       { src = Wc4; dst = wp4; r = idx; }
    else if (idx < 73728)  { src = Wc5; dst = wp5; r = idx - 36864; }
    else                   { src = Wc3; dst = wp3; r = idx - 73728; }
    int pair = r / 9, q = r - pair * 9;
    dst[pair * 12 + q] = src[r];
}

// ======================================================================
__global__ __launch_bounds__(256) void deconv1_k(
    const float* __restrict__ glo, const float* __restrict__ Wt1, const float* __restrict__ bt1,
    float* __restrict__ s1f)
{
    const int f = blockIdx.x;
    const int tid = threadIdx.x;
    const int n = tid >> 2, pp = tid & 3;
    float bb = bt1[f];
    float a0 = bb, a1 = bb, a2 = bb, a3 = bb;
    const float* gp = glo + n * GLO;
    for (int c = 0; c < GLO; ++c) {
        float g = gp[c];
        float4 w4 = *(const float4*)&Wt1[(((size_t)c * 256 + f) << 4) + pp * 4];
        a0 = fmaf(g, w4.x, a0);
        a1 = fmaf(g, w4.y, a1);
        a2 = fmaf(g, w4.z, a2);
        a3 = fmaf(g, w4.w, a3);
    }
    float* dst = s1f + (((size_t)n * 256 + f) << 4) + pp * 4;
    dst[0] = a0 > 0.f ? a0 : 0.1f * a0;
    dst[1] = a1 > 0.f ? a1 : 0.1f * a1;
    dst[2] = a2 > 0.f ? a2 : 0.1f * a2;
    dst[3] = a3 > 0.f ? a3 : 0.1f * a3;
}

// ======================================================================
__global__ __launch_bounds__(256) void conv2_k(
    const float* __restrict__ s1f, const float* __restrict__ Wc2, const float* __restrict__ bc2,
    u16* __restrict__ c2)
{
    __shared__ float sp[256 * 36];   // 36,864 B
    const int n = blockIdx.x >> 3, cot = blockIdx.x & 7;
    const int tid = threadIdx.x;
    for (int i = tid; i < 256 * 36; i += 256) sp[i] = 0.f;
    __syncthreads();
    for (int i = tid; i < 4096; i += 256) {
        int ci = i >> 4, p = i & 15, y = p >> 2, x = p & 3;
        sp[ci * 36 + (y + 1) * 6 + (x + 1)] = s1f[((size_t)n * 256 + ci) * 16 + p];
    }
    __syncthreads();

    const int co = cot * 16 + (tid >> 4);
    const int p = tid & 15, y = p >> 2, x = p & 3;
    float acc = bc2[co];
    const float* wp = Wc2 + (size_t)co * 256 * 9;
    for (int ci = 0; ci < 256; ++ci) {
        const float* wc = wp + ci * 9;
        const float* s = sp + ci * 36 + y * 6 + x;
#pragma unroll
        for (int ky = 0; ky < 3; ++ky) {
#pragma unroll
            for (int kx = 0; kx < 3; ++kx)
                acc = fmaf(s[ky * 6 + kx], wc[ky * 3 + kx], acc);
        }
    }
    c2[((size_t)n * 128 + co) * 16 + p] = f2b(acc);
}

// ======================================================================
// up_conv_b: banded upsample+conv with halo-in-LDS layout
// ======================================================================
template<int CIN, int HI, int WI, int BH, int DW, int COT, int CO>
__global__ __launch_bounds__(256) void up_conv_b(
    const u16* __restrict__ in, const float* __restrict__ wpad, const float* __restrict__ bias,
    u16* __restrict__ out)
{
    constexpr int H2 = 2 * HI, W2 = 2 * WI;
    constexpr int XG = W2 / DW;
    constexpr int ROWS = BH + 2;
    constexpr int STR = W2 + 2;            // even, odd bank count
    constexpr int NBAND = H2 / BH;
    constexpr int CT = CO / COT;
    constexpr int PAIRS = COT / 2;
    static_assert(XG * BH * PAIRS == 256, "thread map must cover block");
    static_assert((STR & 1) == 0, "u32 LDS reads need even u16 stride");

    __shared__ u16 S[CIN * ROWS * STR];

    const int tid = threadIdx.x;
    int b = blockIdx.x;
    const int ct = b % CT; b /= CT;
    const int band = b % NBAND;
    const int n = b / NBAND;
    const int r0 = band * BH;

    const u16* ip = in + (size_t)n * CIN * HI * WI;

    // stage: bilinear x2 upsample + relu, zero halo (y and x), bf16
    for (int i = tid; i < CIN * ROWS * STR; i += 256) {
        int x  = i % STR;
        int ry = (i / STR) % ROWS;
        int ci = i / (STR * ROWS);
        int yy = r0 - 1 + ry;
        int xx = x - 1;
        float v = 0.f;
        if (yy >= 0 && yy < H2 && xx >= 0 && xx < W2) {
            int y0 = (yy - 1) >> 1; float fy = (yy & 1) ? 0.25f : 0.75f;
            int x0 = (xx - 1) >> 1; float fx = (xx & 1) ? 0.25f : 0.75f;
            int y0c = y0 < 0 ? 0 : y0, y1c = y0 + 1 > HI - 1 ? HI - 1 : y0 + 1;
            int x0c = x0 < 0 ? 0 : x0, x1c = x0 + 1 > WI - 1 ? WI - 1 : x0 + 1;
            const u16* bp = ip + ci * HI * WI;
            float v00 = b2f(bp[y0c * WI + x0c]), v01 = b2f(bp[y0c * WI + x1c]);
            float v10 = b2f(bp[y1c * WI + x0c]), v11 = b2f(bp[y1c * WI + x1c]);
            v = (1.f - fy) * ((1.f - fx) * v00 + fx * v01)
              +        fy  * ((1.f - fx) * v10 + fx * v11);
            v = fmaxf(v, 0.f);
        }
        S[i] = f2b(v);
    }
    __syncthreads();

    const int xg = tid % XG;
    const int y  = (tid / XG) % BH;
    const int pr = tid / (XG * BH);
    const int co0 = ct * COT + pr * 2;
    const int x0 = xg * DW;
    const int yo = r0 + y;

    float acc0[DW], acc1[DW];
    const float bb0 = bias[co0], bb1 = bias[co0 + 1];
#pragma unroll
    for (int d = 0; d < DW; ++d) { acc0[d] = bb0; acc1[d] = bb1; }

    const float* wp0 = wpad + (size_t)(co0 * CIN) * 12;
    const float* wp1 = wpad + (size_t)((co0 + 1) * CIN) * 12;

    for (int ci = 0; ci < CIN; ++ci) {
        float wa[9], wb[9];
        {
            const float4* av = (const float4*)(wp0 + ci * 12);
            float4 a0 = av[0], a1 = av[1], a2 = av[2];
            wa[0] = a0.x; wa[1] = a0.y; wa[2] = a0.z; wa[3] = a0.w;
            wa[4] = a1.x; wa[5] = a1.y; wa[6] = a1.z; wa[7] = a1.w; wa[8] = a2.x;
            const float4* bv = (const float4*)(wp1 + ci * 12);
            float4 b0 = bv[0], b1 = bv[1], b2v = bv[2];
            wb[0] = b0.x; wb[1] = b0.y; wb[2] = b0.z; wb[3] = b0.w;
            wb[4] = b1.x; wb[5] = b1.y; wb[6] = b1.z; wb[7] = b1.w; wb[8] = b2v.x;
        }
#pragma unroll
        for (int ky = 0; ky < 3; ++ky) {
            const u32* Sr = (const u32*)(S + ci * ROWS * STR + (y + ky) * STR + x0);
            float seg[DW + 2];
#pragma unroll
            for (int k = 0; k < (DW + 2) / 2; ++k) {
                u32 u = Sr[k];
                seg[2 * k]     = b2f_lo(u);
                seg[2 * k + 1] = b2f_hi(u);
            }
#pragma unroll
            for (int d = 0; d < DW; ++d) {
                acc0[d] = fmaf(seg[d],     wa[ky * 3 + 0], acc0[d]);
                acc0[d] = fmaf(seg[d + 1], wa[ky * 3 + 1], acc0[d]);
                acc0[d] = fmaf(seg[d + 2], wa[ky * 3 + 2], acc0[d]);
                acc1[d] = fmaf(seg[d],     wb[ky * 3 + 0], acc1[d]);
                acc1[d] = fmaf(seg[d + 1], wb[ky * 3 + 1], acc1[d]);
                acc1[d] = fmaf(seg[d + 2], wb[ky * 3 + 2], acc1[d]);
            }
        }
    }

    u16* op0 = out + (((size_t)(n * CO + co0) * H2) + yo) * W2 + x0;
    u16* op1 = op0 + (size_t)H2 * W2;
#pragma unroll
    for (int d = 0; d < DW; d += 2) {
        u32 p0 = (u32)f2b(acc0[d]) | ((u32)f2b(acc0[d + 1]) << 16);
        u32 p1 = (u32)f2b(acc1[d]) | ((u32)f2b(acc1[d + 1]) << 16);
        *(u32*)(op0 + d) = p0;
        *(u32*)(op1 + d) = p1;
    }
}

// ======================================================================
// up_conv6: 4-wide units so all 256 threads compute (CO=2 final conv)
// ======================================================================
__global__ __launch_bounds__(256) void up_conv6(
    const u16* __restrict__ c5, const float* __restrict__ w, const float* __restrict__ bias,
    u16* __restrict__ sl)
{
    __shared__ u16 S[40960];
    const int tid = threadIdx.x;
    const int n = blockIdx.x >> 3;
    const int band = blockIdx.x & 7;
    const int r0 = band * 8;
    const u16* ip = c5 + (size_t)n * 64 * 1024;

    for (int i = tid; i < 40960; i += 256) {
        int x2 = i & 63; int ry = (i >> 6) % 10; int ci = i / 640;
        int yy = r0 - 1 + ry;
        float v = 0.f;
        if (yy >= 0 && yy < 64) {
            int y0 = (yy - 1) >> 1; float fy = (yy & 1) ? 0.25f : 0.75f;
            int x0 = (x2 - 1) >> 1; float fx = (x2 & 1) ? 0.25f : 0.75f;
            int y0c = y0 < 0 ? 0 : y0, y1c = y0 + 1 > 31 ? 31 : y0 + 1;
            int x0c = x0 < 0 ? 0 : x0, x1c = x0 + 1 > 31 ? 31 : x0 + 1;
            const u16* b = ip + ci * 1024;
            float v00 = b2f(b[y0c * 32 + x0c]), v01 = b2f(b[y0c * 32 + x1c]);
            float v10 = b2f(b[y1c * 32 + x0c]), v11 = b2f(b[y1c * 32 + x1c]);
            v = fmaxf((1.f - fy) * ((1.f - fx) * v00 + fx * v01)
                      +      fy  * ((1.f - fx) * v10 + fx * v11), 0.f);
        }
        S[i] = f2b(v);
    }
    __syncthreads();

    {
        const int u = tid;                  // 256 units: 2co x 8y x 16xg(4-wide)
        const int x0p = (u & 15) * 4;
        const int yr  = (u >> 4) & 7;
        const int co  = u >> 7;
        const int y = r0 + yr;
        float acc[4];
        float bb = bias[co];
#pragma unroll
        for (int d = 0; d < 4; ++d) acc[d] = bb;
        const float* wp = w + (size_t)co * 64 * 9;
        for (int ci = 0; ci < 64; ++ci) {
            const u16* Sr = S + ci * 640;
            float wk[9];
#pragma unroll
            for (int q = 0; q < 9; ++q) wk[q] = wp[ci * 9 + q];
#pragma unroll
            for (int ky = 0; ky < 3; ++ky) {
                int ry = yr + ky;
                float seg[6];
#pragma unroll
                for (int dx = 0; dx < 6; ++dx) {
                    int xx = x0p + dx - 1;
                    seg[dx] = (xx >= 0 && xx < 64) ? b2f(Sr[ry * 64 + xx]) : 0.f;
                }
#pragma unroll
                for (int d = 0; d < 4; ++d) {
                    acc[d] = fmaf(seg[d],     wk[ky * 3 + 0], acc[d]);
                    acc[d] = fmaf(seg[d + 1], wk[ky * 3 + 1], acc[d]);
                    acc[d] = fmaf(seg[d + 2], wk[ky * 3 + 2], acc[d]);
                }
            }
        }
        u16* op = sl + (size_t)(n * 2 + co) * 4096 + y * 64 + x0p;
#pragma unroll
        for (int d = 0; d < 4; ++d) op[d] = f2b(acc[d]);
    }
}

// ======================================================================
__global__ __launch_bounds__(256) void softmax_spatial(const u16* __restrict__ sl, float* __restrict__ out)
{
    __shared__ float red[256];
    const int b = blockIdx.x;
    const u16* src = sl + (size_t)b * 4096;
    float* dst = out + (size_t)b * 4096;
    const int tid = threadIdx.x;
    float m = -INFINITY;
    for (int i = tid; i < 4096; i += 256) m = fmaxf(m, b2f(src[i]));
    red[tid] = m; __syncthreads();
    for (int s = 128; s > 0; s >>= 1) { if (tid < s) red[tid] = fmaxf(red[tid], red[tid + s]); __syncthreads(); }
    m = red[0]; __syncthreads();
    float sum = 0.f;
    for (int i = tid; i < 4096; i += 256) sum += expf(b2f(src[i]) - m);
    red[tid] = sum; __syncthreads();
    for (int s = 128; s > 0; s >>= 1) { if (tid < s) red[tid] += red[tid + s]; __syncthreads(); }
    float inv = 1.f / red[0];
    for (int i = tid; i < 4096; i += 256) dst[i] = expf(b2f(src[i]) - m) * inv;
}

// ======================================================================
extern "C" void kernel_launch(void* const* d_in, const int* in_sizes, int n_in,
                              void* d_out, int out_size, void* d_ws, size_t ws_size,
                              hipStream_t stream)
{
    const float* G     = (const float*)d_in[0];
    const float* X     = (const float*)d_in[1];
    const int*   avail = (const int*)d_in[2];
    const float* lh    = (const float*)d_in[3];
    const float* pa    = (const float*)d_in[4];
    const int*   relf  = (const int*)d_in[5];
    const float* We  = (const float*)d_in[6];   const float* be  = (const float*)d_in[7];
    const float* W1  = (const float*)d_in[8];   const float* b1  = (const float*)d_in[9];
    const float* W2  = (const float*)d_in[10];  const float* b2  = (const float*)d_in[11];
    const float* W3  = (const float*)d_in[12];  const float* b3  = (const float*)d_in[13];
    const float* Wle = (const float*)d_in[14];  const float* ble = (const float*)d_in[15];
    const float* Wih = (const float*)d_in[16];  const float* Whh = (const float*)d_in[17];
    const float* bih = (const float*)d_in[18];  const float* bhh = (const float*)d_in[19];
    const float* Wa  = (const float*)d_in[20];  const float* ba  = (const float*)d_in[21];
    const float* Wv  = (const float*)d_in[22];  const float* bv  = (const float*)d_in[23];
    const float* Wt1 = (const float*)d_in[24];  const float* bt1 = (const float*)d_in[25];
    const float* Wc2 = (const float*)d_in[26];  const float* bc2 = (const float*)d_in[27];
    const float* Wc3 = (const float*)d_in[28];  const float* bc3 = (const float*)d_in[29];
    const float* Wc4 = (const float*)d_in[30];  const float* bc4 = (const float*)d_in[31];
    const float* Wc5 = (const float*)d_in[32];  const float* bc5 = (const float*)d_in[33];
    const float* Wc6 = (const float*)d_in[34];  const float* bc6 = (const float*)d_in[35];

    char* ws = (char*)d_ws;
    float* goaAll = (float*)(ws + WS_GOA);
    float* hbuf   = (float*)(ws + WS_HBUF);
    float* cbuf   = (float*)(ws + WS_CBUF);
    float* hout   = (float*)(ws + WS_HOUT);
    float* glo    = (float*)(ws + WS_GLO);
    float* wihT   = (float*)(ws + WS_WIHT);
    float* whhT   = (float*)(ws + WS_WHHT);
    float* bsum   = (float*)(ws + WS_BSUM);
    u16*   c2     = (u16*)(ws + WS_C2);
    u16*   c3     = (u16*)(ws + WS_C3);
    u16*   c4     = (u16*)(ws + WS_C4);
    u16*   c5     = (u16*)(ws + WS_C5);
    u16*   sl     = (u16*)(ws + WS_SL);
    u16*   WeT    = (u16*)(ws + WS_WET);
    u16*   W1T    = (u16*)(ws + WS_W1T);
    u16*   W2T    = (u16*)(ws + WS_W2T);
    u16*   W3T    = (u16*)(ws + WS_W3T);
    float* gatesX = (float*)(ws + WS_GX);
    float* s1f    = (float*)(ws + WS_S1F);
    float* wp4    = (float*)(ws + WS_WP4);
    float* wp5    = (float*)(ws + WS_WP5);
    float* wp3    = (float*)(ws + WS_WP3);
    float* out    = (float*)d_out;     // OUTPUT IS FLOAT32

    wprep<<<256, 256, 0, stream>>>(We, W1, W2, W3, WeT, W1T, W2T, W3T);
    wtrans<<<1024, 256, 0, stream>>>(Wih, Whh, bih, bhh, wihT, whhT, bsum);
    gcn_mfma<<<2048, 1024, 0, stream>>>(G, X, pa, WeT, be, W1T, b1, W2T, b2, W3T, b3, goaAll);
    lstm_pre<<<256, 256, 0, stream>>>(goaAll, Wle, ble, wihT, bsum, gatesX);
    lstm_seq<<<64, 1024, 0, stream>>>(gatesX, whhT, relf, lh, hbuf, cbuf, hout);
    heads<<<64, 256, 0, stream>>>(goaAll, hout, hbuf, cbuf, Wa, ba, Wv, bv, avail, glo, out);
    // goaAll is dead from here; reuse its region for padded conv weights
    wpad_k<<<576, 256, 0, stream>>>(Wc4, Wc5, Wc3, wp4, wp5, wp3);
    deconv1_k<<<256, 256, 0, stream>>>(glo, Wt1, bt1, s1f);
    conv2_k<<<512, 256, 0, stream>>>(s1f, Wc2, bc2, c2);
    // c2->c3: banded, 128ci, 4x4->8x8, BH=8 (whole), DW=4, COT=32 -> grid 64*1*2
    up_conv_b<128, 4, 4, 8, 4, 32, 64><<<128, 256, 0, stream>>>(c2, wp3, bc3, c3);
    // c3->c4: banded, 64ci, 8x8->16x16, BH=4, DW=4, COT=32 -> grid 64*4*2
    up_conv_b<64, 8, 8, 4, 4, 32, 64><<<512, 256, 0, stream>>>(c3, wp4, bc4, c4);
    // c4->c5: banded, 64ci, 16x16->32x32, BH=4, DW=8, COT=32 -> grid 64*8*2
    up_conv_b<64, 16, 16, 4, 8, 32, 64><<<1024, 256, 0, stream>>>(c4, wp5, bc5, c5);
    up_conv6<<<512, 256, 0, stream>>>(c5, Wc6, bc6, sl);
    softmax_spatial<<<128, 256, 0, stream>>>(sl, out + OUT_SPATIAL);
}

// Round 5
// 1416.833 us; speedup vs baseline: 1.2201x; 1.0794x over previous
//
#include <hip/hip_runtime.h>
#include <math.h>

typedef unsigned short u16;
typedef unsigned int u32;

typedef __attribute__((ext_vector_type(8))) short bf16x8;
typedef __attribute__((ext_vector_type(4))) float f32x4;

// ---------- bf16 helpers (intermediates only; I/O is f32) ----------
__device__ __forceinline__ float b2f(u16 u) {
    union { u32 ui; float f; } v; v.ui = ((u32)u) << 16; return v.f;
}
__device__ __forceinline__ float b2f_lo(u32 u) {
    union { u32 ui; float f; } v; v.ui = u << 16; return v.f;
}
__device__ __forceinline__ float b2f_hi(u32 u) {
    union { u32 ui; float f; } v; v.ui = u & 0xffff0000u; return v.f;
}
__device__ __forceinline__ u16 f2b(float f) {
    union { float f; u32 ui; } v; v.f = f;
    u32 x = v.ui;
    u32 r = (x + 0x7fffu + ((x >> 16) & 1u)) >> 16;
    return (u16)r;
}
__device__ __forceinline__ float sigf(float x) { return 1.0f / (1.0f + expf(-x)); }
// fast tanh: error ~1e-6, always followed by bf16 rounding (ulp ~4e-3 rel)
__device__ __forceinline__ float ftanh(float x) {
    float e = __expf(2.0f * x);
    return 1.0f - 2.0f / (e + 1.0f);
}

// ---------- problem constants ----------
#define GNODES 128
#define EMBD   256
#define NB     64
#define TS     32
#define GOA    268
#define GLO    524

// output layout (f32 elements)
#define OUT_SPATIAL 0
#define OUT_NS      524288
#define OUT_V       524800
#define OUT_H       524864

// workspace byte offsets
#define WS_GOA   ((size_t)0)
#define WS_HBUF  ((size_t)2195456)
#define WS_CBUF  ((size_t)2260992)
#define WS_HOUT  ((size_t)2326528)
#define WS_GLO   ((size_t)2392064)
#define WS_WIHT  ((size_t)2526208)
#define WS_WHHT  ((size_t)3574784)
#define WS_BSUM  ((size_t)4623360)
#define WS_C2    ((size_t)4627456)
#define WS_C3    ((size_t)4889600)
#define WS_C4    ((size_t)5413888)
#define WS_C5    ((size_t)7511040)
#define WS_SL    ((size_t)15899648)
#define WS_WET   ((size_t)16948224)   // 256*64 bf16
#define WS_W1T   ((size_t)16980992)   // 256*256 bf16
#define WS_W2T   ((size_t)17112064)
#define WS_W3T   ((size_t)17243136)
#define WS_GX    ((size_t)17374208)   // 2048*1024 f32 = 8,388,608
#define WS_S1F   ((size_t)25762816)   // 64*4096 f32 = 1,048,576 -> end 26,811,392

// padded conv weights live in the goaAll region (dead after `heads`,
// fully rewritten by gcn_mfma next iteration).
// wp4: 64*64*12*4 = 196,608 ; wp5: same ; wp3: 64*128*12*4 = 393,216
#define WS_WP4   WS_GOA
#define WS_WP5   (WS_GOA + (size_t)196608)
#define WS_WP3   (WS_GOA + (size_t)393216)   // end 786,432 < 2,195,456

// LDS strides (elements)
#define SA_S 264
#define TT_S 136
#define XS_S 72

// ======================================================================
// weight prep: transpose + bf16-cast GCN weights
// ======================================================================
__global__ void wprep(const float* __restrict__ We, const float* __restrict__ W1,
                      const float* __restrict__ W2, const float* __restrict__ W3,
                      u16* __restrict__ WeT, u16* __restrict__ W1T,
                      u16* __restrict__ W2T, u16* __restrict__ W3T)
{
    int idx = blockIdx.x * 256 + threadIdx.x;
    if (idx < 16384) {
        int k = idx >> 8, nn = idx & 255;
        WeT[nn * 64 + k] = f2b(We[idx]);
    }
    {
        int k = idx >> 8, nn = idx & 255;
        W1T[nn * 256 + k] = f2b(W1[idx]);
        W2T[nn * 256 + k] = f2b(W2[idx]);
        W3T[nn * 256 + k] = f2b(W3[idx]);
    }
}

// ======================================================================
// GCN via MFMA — 1024 threads (16 waves), 1 item per block.
// LDS ~140KB forces 1 block/CU; 16 waves -> 4 waves/SIMD (50% occ).
// NOTE: at 1024 threads the compiler pins VGPRs at 64 (measured R2/R3/R4)
// regardless of launch_bounds — design for <=64 VGPRs:
//   W-mult : wave = ftile (bfr[8] persistent from GLOBAL W = 32 VGPR;
//            afr[8] transient per row-tile) -> fits, no spill (R3: 425us)
//   A-mult : wave = (node-tile nt=wv&7, feature-half ch=wv>>3)
// ======================================================================
__global__ __launch_bounds__(1024, 4) void gcn_mfma(
    const float* __restrict__ G, const float* __restrict__ X, const float* __restrict__ pa,
    const u16* __restrict__ WeT, const float* __restrict__ be,
    const u16* __restrict__ W1T, const float* __restrict__ b1,
    const u16* __restrict__ W2T, const float* __restrict__ b2,
    const u16* __restrict__ W3T, const float* __restrict__ b3,
    float* __restrict__ goaAll)
{
    __shared__ u16 Sa[128 * SA_S];
    __shared__ u16 Tt[256 * TT_S];
    __shared__ float dis[GNODES];
    __shared__ float dred[1024];
    __shared__ float pm[256];

    const int item = blockIdx.x;
    const int tid  = threadIdx.x;
    const int wv   = tid >> 6;        // 0..15
    const int nt   = wv & 7;          // node tile (A-mult / emb)
    const int ch   = wv >> 3;         // half index (A-mult / emb)
    const int lane = tid & 63;
    const int l16  = lane & 15;
    const int quad = lane >> 4;
    const float* Gp = G + (size_t)item * GNODES * GNODES;
    const float* Xp = X + (size_t)item * GNODES * 64;

    // stage X -> Tt (bf16), and degree partial sums (8 threads/row)
    for (int idx = tid; idx < 128 * 64; idx += 1024) {
        int m = idx >> 6, k = idx & 63;
        Tt[m * XS_S + k] = f2b(Xp[idx]);
    }
    {
        int row = tid >> 3, part = tid & 7;
        const float4* gr = (const float4*)(Gp + (size_t)row * GNODES) + part * 4;
        float s = 0.f;
#pragma unroll
        for (int k = 0; k < 4; ++k) { float4 g = gr[k]; s += g.x + g.y + g.z + g.w; }
        dred[tid] = s;
    }
    __syncthreads();
    if (tid < GNODES) {
        float s = 0.f;
#pragma unroll
        for (int p = 0; p < 8; ++p) s += dred[tid * 8 + p];
        dis[tid] = 1.0f / sqrtf(s + 1.0f);
    }
    __syncthreads();

    // bAgg: normalized adjacency fragments for node-tile nt (dup across ch)
    bf16x8 bAgg[4];
    {
        const int i = nt * 16 + l16;
        const float di = dis[i];
        const float* gr = Gp + (size_t)i * GNODES;
#pragma unroll
        for (int t = 0; t < 4; ++t) {
            const int k0 = t * 32 + quad * 8;
            float4 ga = *(const float4*)(gr + k0);
            float4 gb = *(const float4*)(gr + k0 + 4);
            float vv[8] = {ga.x, ga.y, ga.z, ga.w, gb.x, gb.y, gb.z, gb.w};
            bf16x8 f;
#pragma unroll
            for (int j = 0; j < 8; ++j) {
                int k = k0 + j;
                float a = (vv[j] + (k == i ? 1.0f : 0.0f)) * di * dis[k];
                f[j] = (short)f2b(a);
            }
            bAgg[t] = f;
        }
    }

    // emb = tanh(X @ We + be): wave = (node-tile nt, feature-half ch)
    {
        bf16x8 a0 = *(const bf16x8*)(Tt + (16 * nt + l16) * XS_S + quad * 8);
        bf16x8 a1 = *(const bf16x8*)(Tt + (16 * nt + l16) * XS_S + 32 + quad * 8);
        for (int cj = 0; cj < 8; ++cj) {
            const int ct = ch * 8 + cj;
            const int nf = ct * 16 + l16;
            bf16x8 wb0 = *(const bf16x8*)(WeT + nf * 64 + quad * 8);
            bf16x8 wb1 = *(const bf16x8*)(WeT + nf * 64 + 32 + quad * 8);
            float bb = be[nf];
            f32x4 acc = {bb, bb, bb, bb};
            acc = __builtin_amdgcn_mfma_f32_16x16x32_bf16(a0, wb0, acc, 0, 0, 0);
            acc = __builtin_amdgcn_mfma_f32_16x16x32_bf16(a1, wb1, acc, 0, 0, 0);
#pragma unroll
            for (int r = 0; r < 4; ++r) {
                int node = 16 * nt + quad * 4 + r;
                Sa[node * SA_S + nf] = f2b(ftanh(acc[r]));
            }
        }
    }
    __syncthreads();

    const u16* WTs[3]  = {W1T, W2T, W3T};
    const float* bss[3] = {b1, b2, b3};

    for (int l = 0; l < 3; ++l) {
        const u16* WT = WTs[l];
        const float* bias = bss[l];

        // ---- W-multiply: wave = ftile (wv). bfr persistent, afr streamed.
        const int nf = wv * 16 + l16;
        const float bb = bias[nf];
        bf16x8 bfr[8];
#pragma unroll
        for (int t = 0; t < 8; ++t)
            bfr[t] = *(const bf16x8*)(WT + (size_t)nf * 256 + t * 32 + quad * 8);

        for (int rt = 0; rt < 8; ++rt) {
            bf16x8 afr[8];
#pragma unroll
            for (int t = 0; t < 8; ++t)
                afr[t] = *(const bf16x8*)(Sa + (16 * rt + l16) * SA_S + t * 32 + quad * 8);
            f32x4 acc = {bb, bb, bb, bb};
#pragma unroll
            for (int t = 0; t < 8; ++t)
                acc = __builtin_amdgcn_mfma_f32_16x16x32_bf16(afr[t], bfr[t], acc, 0, 0, 0);
            u16 p0 = f2b(acc[0]), p1 = f2b(acc[1]), p2 = f2b(acc[2]), p3 = f2b(acc[3]);
            uint2 pk; pk.x = (u32)p0 | ((u32)p1 << 16); pk.y = (u32)p2 | ((u32)p3 << 16);
            *(uint2*)(Tt + (size_t)nf * TT_S + 16 * rt + quad * 4) = pk;
        }
        __syncthreads();

        // ---- A-multiply: wave = (node-tile nt, feature-half ch) ----
        for (int fj = 0; fj < 8; ++fj) {
            const int ft = ch * 8 + fj;
            bf16x8 afr[4];
#pragma unroll
            for (int t = 0; t < 4; ++t)
                afr[t] = *(const bf16x8*)(Tt + (16 * ft + l16) * TT_S + t * 32 + quad * 8);
            f32x4 acc = {0.f, 0.f, 0.f, 0.f};
#pragma unroll
            for (int t = 0; t < 4; ++t)
                acc = __builtin_amdgcn_mfma_f32_16x16x32_bf16(afr[t], bAgg[t], acc, 0, 0, 0);
            int i = nt * 16 + l16;
            u16 p0 = f2b(ftanh(acc[0])), p1 = f2b(ftanh(acc[1]));
            u16 p2 = f2b(ftanh(acc[2])), p3 = f2b(ftanh(acc[3]));
            uint2 pk; pk.x = (u32)p0 | ((u32)p1 << 16); pk.y = (u32)p2 | ((u32)p3 << 16);
            *(uint2*)(Sa + (size_t)i * SA_S + 16 * ft + quad * 4) = pk;
        }
        __syncthreads();
    }

    // ---- column max over nodes (split rows across two thread groups) ----
    const int nb = item >> 5, tt = item & 31;
    float* gdst = goaAll + ((size_t)tt * NB + nb) * GOA;
    float mymax = -2.0f;
    if (tid < 512) {
        int f = tid & 255, h = tid >> 8;
        for (int i = h * 64; i < h * 64 + 64; ++i)
            mymax = fmaxf(mymax, b2f(Sa[i * SA_S + f]));
        if (h == 1) pm[f] = mymax;
    }
    __syncthreads();
    if (tid < 256) {
        gdst[tid] = fmaxf(mymax, pm[tid]);
    } else if (tid >= 512 && tid < 524) {
        gdst[256 + (tid - 512)] = pa[(size_t)item * 12 + (tid - 512)];
    }
}

// ======================================================================
__global__ void wtrans(const float* __restrict__ Wih, const float* __restrict__ Whh,
                       const float* __restrict__ bih, const float* __restrict__ bhh,
                       float* __restrict__ wihT, float* __restrict__ whhT, float* __restrict__ bsum)
{
    int idx = blockIdx.x * 256 + threadIdx.x;
    int r = idx >> 8;
    int k = idx & 255;
    wihT[k * 1024 + r] = Wih[idx];
    whhT[k * 1024 + r] = Whh[idx];
    if (idx < 1024) bsum[idx] = bih[idx] + bhh[idx];
}

// ======================================================================
// lstm_pre: 8 items per block; each weight element loaded once and
// reused 8x in registers. 256 blocks x 256 threads. Bit-exact per-item
// FMA order vs the old kernel.
// ======================================================================
#define LP_IT 8
__global__ __launch_bounds__(256) void lstm_pre(
    const float* __restrict__ goaAll, const float* __restrict__ Wle, const float* __restrict__ ble,
    const float* __restrict__ wihT, const float* __restrict__ bsum,
    float* __restrict__ gatesX)
{
    __shared__ float gl[LP_IT][GOA];
    __shared__ float xv[LP_IT][256];
    const int b0 = blockIdx.x * LP_IT;
    const int u = threadIdx.x;

    for (int idx = u; idx < LP_IT * GOA; idx += 256) {
        int it = idx / GOA, k = idx - it * GOA;
        gl[it][k] = goaAll[(size_t)(b0 + it) * GOA + k];
    }
    __syncthreads();

    {
        float acc[LP_IT];
        float bl = ble[u];
#pragma unroll
        for (int i = 0; i < LP_IT; ++i) acc[i] = bl;
        for (int k = 0; k < GOA; ++k) {
            float w = Wle[k * 256 + u];
#pragma unroll
            for (int i = 0; i < LP_IT; ++i) acc[i] = fmaf(gl[i][k], w, acc[i]);
        }
#pragma unroll
        for (int i = 0; i < LP_IT; ++i) xv[i][u] = tanhf(acc[i]);
    }
    __syncthreads();

#pragma unroll
    for (int g = 0; g < 4; ++g) {
        float a[LP_IT];
        float bs = bsum[g * 256 + u];
#pragma unroll
        for (int i = 0; i < LP_IT; ++i) a[i] = bs;
#pragma unroll 4
        for (int k = 0; k < 256; ++k) {
            float w = wihT[k * 1024 + g * 256 + u];
#pragma unroll
            for (int i = 0; i < LP_IT; ++i) a[i] = fmaf(xv[i][k], w, a[i]);
        }
#pragma unroll
        for (int i = 0; i < LP_IT; ++i)
            gatesX[(size_t)(b0 + i) * 1024 + g * 256 + u] = a[i];
    }
}

// ======================================================================
// lstm_seq: h-recurrence with zero-skip. When relf==0 the hidden state
// is zeroed, so the next step's whhT matvec is exactly zero -> skip it
// (block-uniform branch, bit-exact).
// ======================================================================
__global__ __launch_bounds__(1024) void lstm_seq(
    const float* __restrict__ gatesX, const float* __restrict__ whhT,
    const int* __restrict__ relf, const float* __restrict__ lh,
    float* __restrict__ hbuf, float* __restrict__ cbuf, float* __restrict__ hout)
{
    __shared__ float hv[256];
    __shared__ float ga[1024];
    __shared__ int hzf;
    const int n = blockIdx.x, u = threadIdx.x;
    float cpriv = 0.f;
    if (u < 256) { hv[u] = lh[n * 256 + u]; cpriv = lh[16384 + n * 256 + u]; }
    if (u == 0) hzf = 0;
    __syncthreads();

    for (int t = 0; t < TS; ++t) {
        float a = gatesX[((size_t)t * NB + n) * 1024 + u];
        if (!hzf) {
            const float* wh = whhT + u;
#pragma unroll 8
            for (int k = 0; k < 256; ++k)
                a = fmaf(hv[k], wh[k * 1024], a);
        }
        ga[u] = a;
        __syncthreads();
        if (u < 256) {
            float ai = ga[u], af = ga[256 + u], ag = ga[512 + u], ao = ga[768 + u];
            float cn = sigf(af) * cpriv + sigf(ai) * tanhf(ag);
            float hn = sigf(ao) * tanhf(cn);
            float kp = (relf[n * TS + t] != 0) ? 1.f : 0.f;
            if (t == TS - 1) {
                hout[n * 256 + u] = hn;
                hbuf[n * 256 + u] = hn * kp;
                cbuf[n * 256 + u] = cn * kp;
            }
            cpriv = cn * kp;
            hv[u] = hn * kp;
        }
        if (u == 0) hzf = (relf[n * TS + t] != 0) ? 0 : 1;
        __syncthreads();
    }
}

// ======================================================================
__global__ __launch_bounds__(256) void heads(
    const float* __restrict__ goaAll, const float* __restrict__ hout,
    const float* __restrict__ hbuf, const float* __restrict__ cbuf,
    const float* __restrict__ Wa, const float* __restrict__ ba,
    const float* __restrict__ Wv, const float* __restrict__ bv,
    const int* __restrict__ avail, float* __restrict__ glo, float* __restrict__ out)
{
    __shared__ float gl[GLO];
    __shared__ float lg[8];
    const int n = blockIdx.x, tid = threadIdx.x;
    const float* gsrc = goaAll + ((size_t)31 * NB + n) * GOA;
    gl[tid] = hout[n * 256 + tid];
    gl[256 + tid] = gsrc[tid];
    if (tid < 12) gl[512 + tid] = gsrc[256 + tid];
    __syncthreads();

    glo[n * GLO + tid]       = gl[tid];
    glo[n * GLO + 256 + tid] = gl[256 + tid];
    if (tid < 12) glo[n * GLO + 512 + tid] = gl[512 + tid];

    out[OUT_H + n * 256 + tid]         = hbuf[n * 256 + tid];
    out[OUT_H + 16384 + n * 256 + tid] = cbuf[n * 256 + tid];

    if (tid < 8) {
        float a = ba[tid];
        for (int k = 0; k < GLO; ++k) a = fmaf(gl[k], Wa[k * 8 + tid], a);
        lg[tid] = (avail[n * 8 + tid] == 0) ? -INFINITY : a;
    } else if (tid == 8) {
        float a = bv[0];
        for (int k = 0; k < GLO; ++k) a = fmaf(gl[k], Wv[k], a);
        out[OUT_V + n] = a;
    }
    __syncthreads();
    if (tid == 0) {
        float m = -INFINITY;
        for (int a = 0; a < 8; ++a) m = fmaxf(m, lg[a]);
        float e[8], s = 0.f;
        for (int a = 0; a < 8; ++a) { e[a] = expf(lg[a] - m); s += e[a]; }
        float inv = 1.f / s;
        for (int a = 0; a < 8; ++a) out[OUT_NS + n * 8 + a] = e[a] * inv;
    }
}

// ======================================================================
// wpad_k: pad conv weights from 9 to 16B-aligned 12 floats per (co,ci)
// for Wc4 (36864), Wc5 (36864), Wc3 (73728). grid 576x256 = 147456.
// ======================================================================
__global__ void wpad_k(const float* __restrict__ Wc4, const float* __restrict__ Wc5,
                       const float* __restrict__ Wc3,
                       float* __restrict__ wp4, float* __restrict__ wp5,
                       float* __restrict__ wp3)
{
    int idx = blockIdx.x * 256 + threadIdx.x;
    const float* src; float* dst; int r;
    if (idx < 36864)       { src = Wc4; dst = wp4; r = idx; }
    else if (idx < 73728)  { src = Wc5; dst = wp5; r = idx - 36864; }
    else                   { src = Wc3; dst = wp3; r = idx - 73728; }
    int pair = r / 9, q = r - pair * 9;
    dst[pair * 12 + q] = src[r];
}

// ======================================================================
__global__ __launch_bounds__(256) void deconv1_k(
    const float* __restrict__ glo, const float* __restrict__ Wt1, const float* __restrict__ bt1,
    float* __restrict__ s1f)
{
    const int f = blockIdx.x;
    const int tid = threadIdx.x;
    const int n = tid >> 2, pp = tid & 3;
    float bb = bt1[f];
    float a0 = bb, a1 = bb, a2 = bb, a3 = bb;
    const float* gp = glo + n * GLO;
    for (int c = 0; c < GLO; ++c) {
        float g = gp[c];
        float4 w4 = *(const float4*)&Wt1[(((size_t)c * 256 + f) << 4) + pp * 4];
        a0 = fmaf(g, w4.x, a0);
        a1 = fmaf(g, w4.y, a1);
        a2 = fmaf(g, w4.z, a2);
        a3 = fmaf(g, w4.w, a3);
    }
    float* dst = s1f + (((size_t)n * 256 + f) << 4) + pp * 4;
    dst[0] = a0 > 0.f ? a0 : 0.1f * a0;
    dst[1] = a1 > 0.f ? a1 : 0.1f * a1;
    dst[2] = a2 > 0.f ? a2 : 0.1f * a2;
    dst[3] = a3 > 0.f ? a3 : 0.1f * a3;
}

// ======================================================================
__global__ __launch_bounds__(256) void conv2_k(
    const float* __restrict__ s1f, const float* __restrict__ Wc2, const float* __restrict__ bc2,
    u16* __restrict__ c2)
{
    __shared__ float sp[256 * 36];   // 36,864 B
    const int n = blockIdx.x >> 3, cot = blockIdx.x & 7;
    const int tid = threadIdx.x;
    for (int i = tid; i < 256 * 36; i += 256) sp[i] = 0.f;
    __syncthreads();
    for (int i = tid; i < 4096; i += 256) {
        int ci = i >> 4, p = i & 15, y = p >> 2, x = p & 3;
        sp[ci * 36 + (y + 1) * 6 + (x + 1)] = s1f[((size_t)n * 256 + ci) * 16 + p];
    }
    __syncthreads();

    const int co = cot * 16 + (tid >> 4);
    const int p = tid & 15, y = p >> 2, x = p & 3;
    float acc = bc2[co];
    const float* wp = Wc2 + (size_t)co * 256 * 9;
    for (int ci = 0; ci < 256; ++ci) {
        const float* wc = wp + ci * 9;
        const float* s = sp + ci * 36 + y * 6 + x;
#pragma unroll
        for (int ky = 0; ky < 3; ++ky) {
#pragma unroll
            for (int kx = 0; kx < 3; ++kx)
                acc = fmaf(s[ky * 6 + kx], wc[ky * 3 + kx], acc);
        }
    }
    c2[((size_t)n * 128 + co) * 16 + p] = f2b(acc);
}

// ======================================================================
// up_conv_b: banded upsample+conv with halo-in-LDS layout
// ======================================================================
template<int CIN, int HI, int WI, int BH, int DW, int COT, int CO>
__global__ __launch_bounds__(256) void up_conv_b(
    const u16* __restrict__ in, const float* __restrict__ wpad, const float* __restrict__ bias,
    u16* __restrict__ out)
{
    constexpr int H2 = 2 * HI, W2 = 2 * WI;
    constexpr int XG = W2 / DW;
    constexpr int ROWS = BH + 2;
    constexpr int STR = W2 + 2;            // even, odd bank count
    constexpr int NBAND = H2 / BH;
    constexpr int CT = CO / COT;
    constexpr int PAIRS = COT / 2;
    static_assert(XG * BH * PAIRS == 256, "thread map must cover block");
    static_assert((STR & 1) == 0, "u32 LDS reads need even u16 stride");

    __shared__ u16 S[CIN * ROWS * STR];

    const int tid = threadIdx.x;
    int b = blockIdx.x;
    const int ct = b % CT; b /= CT;
    const int band = b % NBAND;
    const int n = b / NBAND;
    const int r0 = band * BH;

    const u16* ip = in + (size_t)n * CIN * HI * WI;

    // stage: bilinear x2 upsample + relu, zero halo (y and x), bf16
    for (int i = tid; i < CIN * ROWS * STR; i += 256) {
        int x  = i % STR;
        int ry = (i / STR) % ROWS;
        int ci = i / (STR * ROWS);
        int yy = r0 - 1 + ry;
        int xx = x - 1;
        float v = 0.f;
        if (yy >= 0 && yy < H2 && xx >= 0 && xx < W2) {
            int y0 = (yy - 1) >> 1; float fy = (yy & 1) ? 0.25f : 0.75f;
            int x0 = (xx - 1) >> 1; float fx = (xx & 1) ? 0.25f : 0.75f;
            int y0c = y0 < 0 ? 0 : y0, y1c = y0 + 1 > HI - 1 ? HI - 1 : y0 + 1;
            int x0c = x0 < 0 ? 0 : x0, x1c = x0 + 1 > WI - 1 ? WI - 1 : x0 + 1;
            const u16* bp = ip + ci * HI * WI;
            float v00 = b2f(bp[y0c * WI + x0c]), v01 = b2f(bp[y0c * WI + x1c]);
            float v10 = b2f(bp[y1c * WI + x0c]), v11 = b2f(bp[y1c * WI + x1c]);
            v = (1.f - fy) * ((1.f - fx) * v00 + fx * v01)
              +        fy  * ((1.f - fx) * v10 + fx * v11);
            v = fmaxf(v, 0.f);
        }
        S[i] = f2b(v);
    }
    __syncthreads();

    const int xg = tid % XG;
    const int y  = (tid / XG) % BH;
    const int pr = tid / (XG * BH);
    const int co0 = ct * COT + pr * 2;
    const int x0 = xg * DW;
    const int yo = r0 + y;

    float acc0[DW], acc1[DW];
    const float bb0 = bias[co0], bb1 = bias[co0 + 1];
#pragma unroll
    for (int d = 0; d < DW; ++d) { acc0[d] = bb0; acc1[d] = bb1; }

    const float* wp0 = wpad + (size_t)(co0 * CIN) * 12;
    const float* wp1 = wpad + (size_t)((co0 + 1) * CIN) * 12;

    for (int ci = 0; ci < CIN; ++ci) {
        float wa[9], wb[9];
        {
            const float4* av = (const float4*)(wp0 + ci * 12);
            float4 a0 = av[0], a1 = av[1], a2 = av[2];
            wa[0] = a0.x; wa[1] = a0.y; wa[2] = a0.z; wa[3] = a0.w;
            wa[4] = a1.x; wa[5] = a1.y; wa[6] = a1.z; wa[7] = a1.w; wa[8] = a2.x;
            const float4* bv = (const float4*)(wp1 + ci * 12);
            float4 b0 = bv[0], b1 = bv[1], b2v = bv[2];
            wb[0] = b0.x; wb[1] = b0.y; wb[2] = b0.z; wb[3] = b0.w;
            wb[4] = b1.x; wb[5] = b1.y; wb[6] = b1.z; wb[7] = b1.w; wb[8] = b2v.x;
        }
#pragma unroll
        for (int ky = 0; ky < 3; ++ky) {
            const u32* Sr = (const u32*)(S + ci * ROWS * STR + (y + ky) * STR + x0);
            float seg[DW + 2];
#pragma unroll
            for (int k = 0; k < (DW + 2) / 2; ++k) {
                u32 u = Sr[k];
                seg[2 * k]     = b2f_lo(u);
                seg[2 * k + 1] = b2f_hi(u);
            }
#pragma unroll
            for (int d = 0; d < DW; ++d) {
                acc0[d] = fmaf(seg[d],     wa[ky * 3 + 0], acc0[d]);
                acc0[d] = fmaf(seg[d + 1], wa[ky * 3 + 1], acc0[d]);
                acc0[d] = fmaf(seg[d + 2], wa[ky * 3 + 2], acc0[d]);
                acc1[d] = fmaf(seg[d],     wb[ky * 3 + 0], acc1[d]);
                acc1[d] = fmaf(seg[d + 1], wb[ky * 3 + 1], acc1[d]);
                acc1[d] = fmaf(seg[d + 2], wb[ky * 3 + 2], acc1[d]);
            }
        }
    }

    u16* op0 = out + (((size_t)(n * CO + co0) * H2) + yo) * W2 + x0;
    u16* op1 = op0 + (size_t)H2 * W2;
#pragma unroll
    for (int d = 0; d < DW; d += 2) {
        u32 p0 = (u32)f2b(acc0[d]) | ((u32)f2b(acc0[d + 1]) << 16);
        u32 p1 = (u32)f2b(acc1[d]) | ((u32)f2b(acc1[d + 1]) << 16);
        *(u32*)(op0 + d) = p0;
        *(u32*)(op1 + d) = p1;
    }
}

// ======================================================================
// up_conv6: 4-wide units so all 256 threads compute (CO=2 final conv)
// ======================================================================
__global__ __launch_bounds__(256) void up_conv6(
    const u16* __restrict__ c5, const float* __restrict__ w, const float* __restrict__ bias,
    u16* __restrict__ sl)
{
    __shared__ u16 S[40960];
    const int tid = threadIdx.x;
    const int n = blockIdx.x >> 3;
    const int band = blockIdx.x & 7;
    const int r0 = band * 8;
    const u16* ip = c5 + (size_t)n * 64 * 1024;

    for (int i = tid; i < 40960; i += 256) {
        int x2 = i & 63; int ry = (i >> 6) % 10; int ci = i / 640;
        int yy = r0 - 1 + ry;
        float v = 0.f;
        if (yy >= 0 && yy < 64) {
            int y0 = (yy - 1) >> 1; float fy = (yy & 1) ? 0.25f : 0.75f;
            int x0 = (x2 - 1) >> 1; float fx = (x2 & 1) ? 0.25f : 0.75f;
            int y0c = y0 < 0 ? 0 : y0, y1c = y0 + 1 > 31 ? 31 : y0 + 1;
            int x0c = x0 < 0 ? 0 : x0, x1c = x0 + 1 > 31 ? 31 : x0 + 1;
            const u16* b = ip + ci * 1024;
            float v00 = b2f(b[y0c * 32 + x0c]), v01 = b2f(b[y0c * 32 + x1c]);
            float v10 = b2f(b[y1c * 32 + x0c]), v11 = b2f(b[y1c * 32 + x1c]);
            v = fmaxf((1.f - fy) * ((1.f - fx) * v00 + fx * v01)
                      +      fy  * ((1.f - fx) * v10 + fx * v11), 0.f);
        }
        S[i] = f2b(v);
    }
    __syncthreads();

    {
        const int u = tid;                  // 256 units: 2co x 8y x 16xg(4-wide)
        const int x0p = (u & 15) * 4;
        const int yr  = (u >> 4) & 7;
        const int co  = u >> 7;
        const int y = r0 + yr;
        float acc[4];
        float bb = bias[co];
#pragma unroll
        for (int d = 0; d < 4; ++d) acc[d] = bb;
        const float* wp = w + (size_t)co * 64 * 9;
        for (int ci = 0; ci < 64; ++ci) {
            const u16* Sr = S + ci * 640;
            float wk[9];
#pragma unroll
            for (int q = 0; q < 9; ++q) wk[q] = wp[ci * 9 + q];
#pragma unroll
            for (int ky = 0; ky < 3; ++ky) {
                int ry = yr + ky;
                float seg[6];
#pragma unroll
                for (int dx = 0; dx < 6; ++dx) {
                    int xx = x0p + dx - 1;
                    seg[dx] = (xx >= 0 && xx < 64) ? b2f(Sr[ry * 64 + xx]) : 0.f;
                }
#pragma unroll
                for (int d = 0; d < 4; ++d) {
                    acc[d] = fmaf(seg[d],     wk[ky * 3 + 0], acc[d]);
                    acc[d] = fmaf(seg[d + 1], wk[ky * 3 + 1], acc[d]);
                    acc[d] = fmaf(seg[d + 2], wk[ky * 3 + 2], acc[d]);
                }
            }
        }
        u16* op = sl + (size_t)(n * 2 + co) * 4096 + y * 64 + x0p;
#pragma unroll
        for (int d = 0; d < 4; ++d) op[d] = f2b(acc[d]);
    }
}

// ======================================================================
__global__ __launch_bounds__(256) void softmax_spatial(const u16* __restrict__ sl, float* __restrict__ out)
{
    __shared__ float red[256];
    const int b = blockIdx.x;
    const u16* src = sl + (size_t)b * 4096;
    float* dst = out + (size_t)b * 4096;
    const int tid = threadIdx.x;
    float m = -INFINITY;
    for (int i = tid; i < 4096; i += 256) m = fmaxf(m, b2f(src[i]));
    red[tid] = m; __syncthreads();
    for (int s = 128; s > 0; s >>= 1) { if (tid < s) red[tid] = fmaxf(red[tid], red[tid + s]); __syncthreads(); }
    m = red[0]; __syncthreads();
    float sum = 0.f;
    for (int i = tid; i < 4096; i += 256) sum += expf(b2f(src[i]) - m);
    red[tid] = sum; __syncthreads();
    for (int s = 128; s > 0; s >>= 1) { if (tid < s) red[tid] += red[tid + s]; __syncthreads(); }
    float inv = 1.f / red[0];
    for (int i = tid; i < 4096; i += 256) dst[i] = expf(b2f(src[i]) - m) * inv;
}

// ======================================================================
extern "C" void kernel_launch(void* const* d_in, const int* in_sizes, int n_in,
                              void* d_out, int out_size, void* d_ws, size_t ws_size,
                              hipStream_t stream)
{
    const float* G     = (const float*)d_in[0];
    const float* X     = (const float*)d_in[1];
    const int*   avail = (const int*)d_in[2];
    const float* lh    = (const float*)d_in[3];
    const float* pa    = (const float*)d_in[4];
    const int*   relf  = (const int*)d_in[5];
    const float* We  = (const float*)d_in[6];   const float* be  = (const float*)d_in[7];
    const float* W1  = (const float*)d_in[8];   const float* b1  = (const float*)d_in[9];
    const float* W2  = (const float*)d_in[10];  const float* b2  = (const float*)d_in[11];
    const float* W3  = (const float*)d_in[12];  const float* b3  = (const float*)d_in[13];
    const float* Wle = (const float*)d_in[14];  const float* ble = (const float*)d_in[15];
    const float* Wih = (const float*)d_in[16];  const float* Whh = (const float*)d_in[17];
    const float* bih = (const float*)d_in[18];  const float* bhh = (const float*)d_in[19];
    const float* Wa  = (const float*)d_in[20];  const float* ba  = (const float*)d_in[21];
    const float* Wv  = (const float*)d_in[22];  const float* bv  = (const float*)d_in[23];
    const float* Wt1 = (const float*)d_in[24];  const float* bt1 = (const float*)d_in[25];
    const float* Wc2 = (const float*)d_in[26];  const float* bc2 = (const float*)d_in[27];
    const float* Wc3 = (const float*)d_in[28];  const float* bc3 = (const float*)d_in[29];
    const float* Wc4 = (const float*)d_in[30];  const float* bc4 = (const float*)d_in[31];
    const float* Wc5 = (const float*)d_in[32];  const float* bc5 = (const float*)d_in[33];
    const float* Wc6 = (const float*)d_in[34];  const float* bc6 = (const float*)d_in[35];

    char* ws = (char*)d_ws;
    float* goaAll = (float*)(ws + WS_GOA);
    float* hbuf   = (float*)(ws + WS_HBUF);
    float* cbuf   = (float*)(ws + WS_CBUF);
    float* hout   = (float*)(ws + WS_HOUT);
    float* glo    = (float*)(ws + WS_GLO);
    float* wihT   = (float*)(ws + WS_WIHT);
    float* whhT   = (float*)(ws + WS_WHHT);
    float* bsum   = (float*)(ws + WS_BSUM);
    u16*   c2     = (u16*)(ws + WS_C2);
    u16*   c3     = (u16*)(ws + WS_C3);
    u16*   c4     = (u16*)(ws + WS_C4);
    u16*   c5     = (u16*)(ws + WS_C5);
    u16*   sl     = (u16*)(ws + WS_SL);
    u16*   WeT    = (u16*)(ws + WS_WET);
    u16*   W1T    = (u16*)(ws + WS_W1T);
    u16*   W2T    = (u16*)(ws + WS_W2T);
    u16*   W3T    = (u16*)(ws + WS_W3T);
    float* gatesX = (float*)(ws + WS_GX);
    float* s1f    = (float*)(ws + WS_S1F);
    float* wp4    = (float*)(ws + WS_WP4);
    float* wp5    = (float*)(ws + WS_WP5);
    float* wp3    = (float*)(ws + WS_WP3);
    float* out    = (float*)d_out;     // OUTPUT IS FLOAT32

    wprep<<<256, 256, 0, stream>>>(We, W1, W2, W3, WeT, W1T, W2T, W3T);
    wtrans<<<1024, 256, 0, stream>>>(Wih, Whh, bih, bhh, wihT, whhT, bsum);
    gcn_mfma<<<2048, 1024, 0, stream>>>(G, X, pa, WeT, be, W1T, b1, W2T, b2, W3T, b3, goaAll);
    lstm_pre<<<256, 256, 0, stream>>>(goaAll, Wle, ble, wihT, bsum, gatesX);
    lstm_seq<<<64, 1024, 0, stream>>>(gatesX, whhT, relf, lh, hbuf, cbuf, hout);
    heads<<<64, 256, 0, stream>>>(goaAll, hout, hbuf, cbuf, Wa, ba, Wv, bv, avail, glo, out);
    // goaAll is dead from here; reuse its region for padded conv weights
    wpad_k<<<576, 256, 0, stream>>>(Wc4, Wc5, Wc3, wp4, wp5, wp3);
    deconv1_k<<<256, 256, 0, stream>>>(glo, Wt1, bt1, s1f);
    conv2_k<<<512, 256, 0, stream>>>(s1f, Wc2, bc2, c2);
    // c2->c3: banded, 128ci, 4x4->8x8, BH=8 (whole), DW=4, COT=32 -> grid 64*1*2
    up_conv_b<128, 4, 4, 8, 4, 32, 64><<<128, 256, 0, stream>>>(c2, wp3, bc3, c3);
    // c3->c4: banded, 64ci, 8x8->16x16, BH=4, DW=4, COT=32 -> grid 64*4*2
    up_conv_b<64, 8, 8, 4, 4, 32, 64><<<512, 256, 0, stream>>>(c3, wp4, bc4, c4);
    // c4->c5: banded, 64ci, 16x16->32x32, BH=4, DW=8, COT=32 -> grid 64*8*2
    up_conv_b<64, 16, 16, 4, 8, 32, 64><<<1024, 256, 0, stream>>>(c4, wp5, bc5, c5);
    up_conv6<<<512, 256, 0, stream>>>(c5, Wc6, bc6, sl);
    softmax_spatial<<<128, 256, 0, stream>>>(sl, out + OUT_SPATIAL);
}

// Round 7
// 1401.296 us; speedup vs baseline: 1.2336x; 1.0111x over previous
//
#include <hip/hip_runtime.h>
#include <math.h>

typedef unsigned short u16;
typedef unsigned int u32;

typedef __attribute__((ext_vector_type(8))) short bf16x8;
typedef __attribute__((ext_vector_type(4))) float f32x4;

// ---------- bf16 helpers (intermediates only; I/O is f32) ----------
__device__ __forceinline__ float b2f(u16 u) {
    union { u32 ui; float f; } v; v.ui = ((u32)u) << 16; return v.f;
}
__device__ __forceinline__ float b2f_lo(u32 u) {
    union { u32 ui; float f; } v; v.ui = u << 16; return v.f;
}
__device__ __forceinline__ float b2f_hi(u32 u) {
    union { u32 ui; float f; } v; v.ui = u & 0xffff0000u; return v.f;
}
__device__ __forceinline__ u16 f2b(float f) {
    union { float f; u32 ui; } v; v.f = f;
    u32 x = v.ui;
    u32 r = (x + 0x7fffu + ((x >> 16) & 1u)) >> 16;
    return (u16)r;
}
__device__ __forceinline__ float sigf(float x) { return 1.0f / (1.0f + expf(-x)); }
// fast tanh: error ~1e-6, always followed by bf16 rounding (ulp ~4e-3 rel)
__device__ __forceinline__ float ftanh(float x) {
    float e = __expf(2.0f * x);
    return 1.0f - 2.0f / (e + 1.0f);
}

// ---------- problem constants ----------
#define GNODES 128
#define EMBD   256
#define NB     64
#define TS     32
#define GOA    268
#define GLO    524

// output layout (f32 elements)
#define OUT_SPATIAL 0
#define OUT_NS      524288
#define OUT_V       524800
#define OUT_H       524864

// workspace byte offsets
#define WS_GOA   ((size_t)0)
#define WS_HBUF  ((size_t)2195456)
#define WS_CBUF  ((size_t)2260992)
#define WS_HOUT  ((size_t)2326528)
#define WS_GLO   ((size_t)2392064)
#define WS_WIHT  ((size_t)2526208)
#define WS_WHHT  ((size_t)3574784)
#define WS_BSUM  ((size_t)4623360)
#define WS_C2    ((size_t)4627456)
#define WS_C3    ((size_t)4889600)
#define WS_C4    ((size_t)5413888)
#define WS_C5    ((size_t)7511040)
#define WS_SL    ((size_t)15899648)
#define WS_WET   ((size_t)16948224)   // 256*64 bf16
#define WS_W1T   ((size_t)16980992)   // 256*256 bf16
#define WS_W2T   ((size_t)17112064)
#define WS_W3T   ((size_t)17243136)
#define WS_GX    ((size_t)17374208)   // 2048*1024 f32 = 8,388,608
#define WS_S1F   ((size_t)25762816)   // 64*4096 f32 = 1,048,576 -> end 26,811,392

// padded conv weights: wp4/wp5/wp3 in the goaAll region (dead after
// `heads`); wp2 (128co x 256ci x 12 = 1.5MB) in the gatesX region
// (dead after lstm_seq). wpad_k runs after heads.
#define WS_WP4   WS_GOA
#define WS_WP5   (WS_GOA + (size_t)196608)
#define WS_WP3   (WS_GOA + (size_t)393216)   // end 786,432 < 2,195,456
#define WS_WP2   WS_GX                        // 1,572,864 < 8,388,608

// LDS strides (elements)
#define SA_S 264
#define TT_S 136
#define XS_S 72

// ======================================================================
// weight prep: transpose + bf16-cast GCN weights
// ======================================================================
__global__ void wprep(const float* __restrict__ We, const float* __restrict__ W1,
                      const float* __restrict__ W2, const float* __restrict__ W3,
                      u16* __restrict__ WeT, u16* __restrict__ W1T,
                      u16* __restrict__ W2T, u16* __restrict__ W3T)
{
    int idx = blockIdx.x * 256 + threadIdx.x;
    if (idx < 16384) {
        int k = idx >> 8, nn = idx & 255;
        WeT[nn * 64 + k] = f2b(We[idx]);
    }
    {
        int k = idx >> 8, nn = idx & 255;
        W1T[nn * 256 + k] = f2b(W1[idx]);
        W2T[nn * 256 + k] = f2b(W2[idx]);
        W3T[nn * 256 + k] = f2b(W3[idx]);
    }
}

// ======================================================================
// GCN via MFMA — 1024 threads (16 waves), 1 item per block.
// EXACT R5 code (known good: 437us, absmax 9.77e-4). R6's
// v_cvt_pk_bf16_f32 broke correctness (suspected lo/hi or rounding
// semantics mismatch) — do NOT reintroduce without a single-site test.
// Design rule: <=64 VGPRs (compiler pins 1024-thr blocks at 64).
// ======================================================================
__global__ __launch_bounds__(1024, 4) void gcn_mfma(
    const float* __restrict__ G, const float* __restrict__ X, const float* __restrict__ pa,
    const u16* __restrict__ WeT, const float* __restrict__ be,
    const u16* __restrict__ W1T, const float* __restrict__ b1,
    const u16* __restrict__ W2T, const float* __restrict__ b2,
    const u16* __restrict__ W3T, const float* __restrict__ b3,
    float* __restrict__ goaAll)
{
    __shared__ u16 Sa[128 * SA_S];
    __shared__ u16 Tt[256 * TT_S];
    __shared__ float dis[GNODES];
    __shared__ float dred[1024];
    __shared__ float pm[256];

    const int item = blockIdx.x;
    const int tid  = threadIdx.x;
    const int wv   = tid >> 6;        // 0..15
    const int nt   = wv & 7;          // node tile (A-mult / emb)
    const int ch   = wv >> 3;         // half index (A-mult / emb)
    const int lane = tid & 63;
    const int l16  = lane & 15;
    const int quad = lane >> 4;
    const float* Gp = G + (size_t)item * GNODES * GNODES;
    const float* Xp = X + (size_t)item * GNODES * 64;

    // stage X -> Tt (bf16), and degree partial sums (8 threads/row)
    for (int idx = tid; idx < 128 * 64; idx += 1024) {
        int m = idx >> 6, k = idx & 63;
        Tt[m * XS_S + k] = f2b(Xp[idx]);
    }
    {
        int row = tid >> 3, part = tid & 7;
        const float4* gr = (const float4*)(Gp + (size_t)row * GNODES) + part * 4;
        float s = 0.f;
#pragma unroll
        for (int k = 0; k < 4; ++k) { float4 g = gr[k]; s += g.x + g.y + g.z + g.w; }
        dred[tid] = s;
    }
    __syncthreads();
    if (tid < GNODES) {
        float s = 0.f;
#pragma unroll
        for (int p = 0; p < 8; ++p) s += dred[tid * 8 + p];
        dis[tid] = 1.0f / sqrtf(s + 1.0f);
    }
    __syncthreads();

    // bAgg: normalized adjacency fragments for node-tile nt (dup across ch)
    bf16x8 bAgg[4];
    {
        const int i = nt * 16 + l16;
        const float di = dis[i];
        const float* gr = Gp + (size_t)i * GNODES;
#pragma unroll
        for (int t = 0; t < 4; ++t) {
            const int k0 = t * 32 + quad * 8;
            float4 ga = *(const float4*)(gr + k0);
            float4 gb = *(const float4*)(gr + k0 + 4);
            float vv[8] = {ga.x, ga.y, ga.z, ga.w, gb.x, gb.y, gb.z, gb.w};
            bf16x8 f;
#pragma unroll
            for (int j = 0; j < 8; ++j) {
                int k = k0 + j;
                float a = (vv[j] + (k == i ? 1.0f : 0.0f)) * di * dis[k];
                f[j] = (short)f2b(a);
            }
            bAgg[t] = f;
        }
    }

    // emb = tanh(X @ We + be): wave = (node-tile nt, feature-half ch)
    {
        bf16x8 a0 = *(const bf16x8*)(Tt + (16 * nt + l16) * XS_S + quad * 8);
        bf16x8 a1 = *(const bf16x8*)(Tt + (16 * nt + l16) * XS_S + 32 + quad * 8);
        for (int cj = 0; cj < 8; ++cj) {
            const int ct = ch * 8 + cj;
            const int nf = ct * 16 + l16;
            bf16x8 wb0 = *(const bf16x8*)(WeT + nf * 64 + quad * 8);
            bf16x8 wb1 = *(const bf16x8*)(WeT + nf * 64 + 32 + quad * 8);
            float bb = be[nf];
            f32x4 acc = {bb, bb, bb, bb};
            acc = __builtin_amdgcn_mfma_f32_16x16x32_bf16(a0, wb0, acc, 0, 0, 0);
            acc = __builtin_amdgcn_mfma_f32_16x16x32_bf16(a1, wb1, acc, 0, 0, 0);
#pragma unroll
            for (int r = 0; r < 4; ++r) {
                int node = 16 * nt + quad * 4 + r;
                Sa[node * SA_S + nf] = f2b(ftanh(acc[r]));
            }
        }
    }
    __syncthreads();

    const u16* WTs[3]  = {W1T, W2T, W3T};
    const float* bss[3] = {b1, b2, b3};

    for (int l = 0; l < 3; ++l) {
        const u16* WT = WTs[l];
        const float* bias = bss[l];

        // ---- W-multiply: wave = ftile (wv). bfr persistent, afr streamed.
        const int nf = wv * 16 + l16;
        const float bb = bias[nf];
        bf16x8 bfr[8];
#pragma unroll
        for (int t = 0; t < 8; ++t)
            bfr[t] = *(const bf16x8*)(WT + (size_t)nf * 256 + t * 32 + quad * 8);

        for (int rt = 0; rt < 8; ++rt) {
            bf16x8 afr[8];
#pragma unroll
            for (int t = 0; t < 8; ++t)
                afr[t] = *(const bf16x8*)(Sa + (16 * rt + l16) * SA_S + t * 32 + quad * 8);
            f32x4 acc = {bb, bb, bb, bb};
#pragma unroll
            for (int t = 0; t < 8; ++t)
                acc = __builtin_amdgcn_mfma_f32_16x16x32_bf16(afr[t], bfr[t], acc, 0, 0, 0);
            u16 p0 = f2b(acc[0]), p1 = f2b(acc[1]), p2 = f2b(acc[2]), p3 = f2b(acc[3]);
            uint2 pk; pk.x = (u32)p0 | ((u32)p1 << 16); pk.y = (u32)p2 | ((u32)p3 << 16);
            *(uint2*)(Tt + (size_t)nf * TT_S + 16 * rt + quad * 4) = pk;
        }
        __syncthreads();

        // ---- A-multiply: wave = (node-tile nt, feature-half ch) ----
        for (int fj = 0; fj < 8; ++fj) {
            const int ft = ch * 8 + fj;
            bf16x8 afr[4];
#pragma unroll
            for (int t = 0; t < 4; ++t)
                afr[t] = *(const bf16x8*)(Tt + (16 * ft + l16) * TT_S + t * 32 + quad * 8);
            f32x4 acc = {0.f, 0.f, 0.f, 0.f};
#pragma unroll
            for (int t = 0; t < 4; ++t)
                acc = __builtin_amdgcn_mfma_f32_16x16x32_bf16(afr[t], bAgg[t], acc, 0, 0, 0);
            int i = nt * 16 + l16;
            u16 p0 = f2b(ftanh(acc[0])), p1 = f2b(ftanh(acc[1]));
            u16 p2 = f2b(ftanh(acc[2])), p3 = f2b(ftanh(acc[3]));
            uint2 pk; pk.x = (u32)p0 | ((u32)p1 << 16); pk.y = (u32)p2 | ((u32)p3 << 16);
            *(uint2*)(Sa + (size_t)i * SA_S + 16 * ft + quad * 4) = pk;
        }
        __syncthreads();
    }

    // ---- column max over nodes (split rows across two thread groups) ----
    const int nb = item >> 5, tt = item & 31;
    float* gdst = goaAll + ((size_t)tt * NB + nb) * GOA;
    float mymax = -2.0f;
    if (tid < 512) {
        int f = tid & 255, h = tid >> 8;
        for (int i = h * 64; i < h * 64 + 64; ++i)
            mymax = fmaxf(mymax, b2f(Sa[i * SA_S + f]));
        if (h == 1) pm[f] = mymax;
    }
    __syncthreads();
    if (tid < 256) {
        gdst[tid] = fmaxf(mymax, pm[tid]);
    } else if (tid >= 512 && tid < 524) {
        gdst[256 + (tid - 512)] = pa[(size_t)item * 12 + (tid - 512)];
    }
}

// ======================================================================
__global__ void wtrans(const float* __restrict__ Wih, const float* __restrict__ Whh,
                       const float* __restrict__ bih, const float* __restrict__ bhh,
                       float* __restrict__ wihT, float* __restrict__ whhT, float* __restrict__ bsum)
{
    int idx = blockIdx.x * 256 + threadIdx.x;
    int r = idx >> 8;
    int k = idx & 255;
    wihT[k * 1024 + r] = Wih[idx];
    whhT[k * 1024 + r] = Whh[idx];
    if (idx < 1024) bsum[idx] = bih[idx] + bhh[idx];
}

// ======================================================================
// lstm_pre: 8 items per block; weight reuse 8x in registers.
// ======================================================================
#define LP_IT 8
__global__ __launch_bounds__(256) void lstm_pre(
    const float* __restrict__ goaAll, const float* __restrict__ Wle, const float* __restrict__ ble,
    const float* __restrict__ wihT, const float* __restrict__ bsum,
    float* __restrict__ gatesX)
{
    __shared__ float gl[LP_IT][GOA];
    __shared__ float xv[LP_IT][256];
    const int b0 = blockIdx.x * LP_IT;
    const int u = threadIdx.x;

    for (int idx = u; idx < LP_IT * GOA; idx += 256) {
        int it = idx / GOA, k = idx - it * GOA;
        gl[it][k] = goaAll[(size_t)(b0 + it) * GOA + k];
    }
    __syncthreads();

    {
        float acc[LP_IT];
        float bl = ble[u];
#pragma unroll
        for (int i = 0; i < LP_IT; ++i) acc[i] = bl;
        for (int k = 0; k < GOA; ++k) {
            float w = Wle[k * 256 + u];
#pragma unroll
            for (int i = 0; i < LP_IT; ++i) acc[i] = fmaf(gl[i][k], w, acc[i]);
        }
#pragma unroll
        for (int i = 0; i < LP_IT; ++i) xv[i][u] = tanhf(acc[i]);
    }
    __syncthreads();

#pragma unroll
    for (int g = 0; g < 4; ++g) {
        float a[LP_IT];
        float bs = bsum[g * 256 + u];
#pragma unroll
        for (int i = 0; i < LP_IT; ++i) a[i] = bs;
#pragma unroll 4
        for (int k = 0; k < 256; ++k) {
            float w = wihT[k * 1024 + g * 256 + u];
#pragma unroll
            for (int i = 0; i < LP_IT; ++i) a[i] = fmaf(xv[i][k], w, a[i]);
        }
#pragma unroll
        for (int i = 0; i < LP_IT; ++i)
            gatesX[(size_t)(b0 + i) * 1024 + g * 256 + u] = a[i];
    }
}

// ======================================================================
// lstm_seq: h-recurrence with zero-skip + 4-way accumulator ILP
// (breaks the 256-long serial FMA chain; fp32 reorder ~1e-7).
// ======================================================================
__global__ __launch_bounds__(1024) void lstm_seq(
    const float* __restrict__ gatesX, const float* __restrict__ whhT,
    const int* __restrict__ relf, const float* __restrict__ lh,
    float* __restrict__ hbuf, float* __restrict__ cbuf, float* __restrict__ hout)
{
    __shared__ float hv[256];
    __shared__ float ga[1024];
    __shared__ int hzf;
    const int n = blockIdx.x, u = threadIdx.x;
    float cpriv = 0.f;
    if (u < 256) { hv[u] = lh[n * 256 + u]; cpriv = lh[16384 + n * 256 + u]; }
    if (u == 0) hzf = 0;
    __syncthreads();

    for (int t = 0; t < TS; ++t) {
        float a = gatesX[((size_t)t * NB + n) * 1024 + u];
        if (!hzf) {
            const float* wh = whhT + u;
            float a0 = 0.f, a1 = 0.f, a2 = 0.f, a3 = 0.f;
#pragma unroll 4
            for (int k = 0; k < 256; k += 4) {
                a0 = fmaf(hv[k],     wh[(k)     * 1024], a0);
                a1 = fmaf(hv[k + 1], wh[(k + 1) * 1024], a1);
                a2 = fmaf(hv[k + 2], wh[(k + 2) * 1024], a2);
                a3 = fmaf(hv[k + 3], wh[(k + 3) * 1024], a3);
            }
            a += (a0 + a1) + (a2 + a3);
        }
        ga[u] = a;
        __syncthreads();
        if (u < 256) {
            float ai = ga[u], af = ga[256 + u], ag = ga[512 + u], ao = ga[768 + u];
            float cn = sigf(af) * cpriv + sigf(ai) * tanhf(ag);
            float hn = sigf(ao) * tanhf(cn);
            float kp = (relf[n * TS + t] != 0) ? 1.f : 0.f;
            if (t == TS - 1) {
                hout[n * 256 + u] = hn;
                hbuf[n * 256 + u] = hn * kp;
                cbuf[n * 256 + u] = cn * kp;
            }
            cpriv = cn * kp;
            hv[u] = hn * kp;
        }
        if (u == 0) hzf = (relf[n * TS + t] != 0) ? 0 : 1;
        __syncthreads();
    }
}

// ======================================================================
__global__ __launch_bounds__(256) void heads(
    const float* __restrict__ goaAll, const float* __restrict__ hout,
    const float* __restrict__ hbuf, const float* __restrict__ cbuf,
    const float* __restrict__ Wa, const float* __restrict__ ba,
    const float* __restrict__ Wv, const float* __restrict__ bv,
    const int* __restrict__ avail, float* __restrict__ glo, float* __restrict__ out)
{
    __shared__ float gl[GLO];
    __shared__ float lg[8];
    const int n = blockIdx.x, tid = threadIdx.x;
    const float* gsrc = goaAll + ((size_t)31 * NB + n) * GOA;
    gl[tid] = hout[n * 256 + tid];
    gl[256 + tid] = gsrc[tid];
    if (tid < 12) gl[512 + tid] = gsrc[256 + tid];
    __syncthreads();

    glo[n * GLO + tid]       = gl[tid];
    glo[n * GLO + 256 + tid] = gl[256 + tid];
    if (tid < 12) glo[n * GLO + 512 + tid] = gl[512 + tid];

    out[OUT_H + n * 256 + tid]         = hbuf[n * 256 + tid];
    out[OUT_H + 16384 + n * 256 + tid] = cbuf[n * 256 + tid];

    if (tid < 8) {
        float a = ba[tid];
        for (int k = 0; k < GLO; ++k) a = fmaf(gl[k], Wa[k * 8 + tid], a);
        lg[tid] = (avail[n * 8 + tid] == 0) ? -INFINITY : a;
    } else if (tid == 8) {
        float a = bv[0];
        for (int k = 0; k < GLO; ++k) a = fmaf(gl[k], Wv[k], a);
        out[OUT_V + n] = a;
    }
    __syncthreads();
    if (tid == 0) {
        float m = -INFINITY;
        for (int a = 0; a < 8; ++a) m = fmaxf(m, lg[a]);
        float e[8], s = 0.f;
        for (int a = 0; a < 8; ++a) { e[a] = expf(lg[a] - m); s += e[a]; }
        float inv = 1.f / s;
        for (int a = 0; a < 8; ++a) out[OUT_NS + n * 8 + a] = e[a] * inv;
    }
}

// ======================================================================
// wpad_k: pad conv weights 9 -> 12 floats per (co,ci) for float4 loads.
// Wc4 (36864), Wc5 (36864), Wc3 (73728), Wc2 (294912). grid 1728x256.
// ======================================================================
__global__ void wpad_k(const float* __restrict__ Wc4, const float* __restrict__ Wc5,
                       const float* __restrict__ Wc3, const float* __restrict__ Wc2,
                       float* __restrict__ wp4, float* __restrict__ wp5,
                       float* __restrict__ wp3, float* __restrict__ wp2)
{
    int idx = blockIdx.x * 256 + threadIdx.x;
    const float* src; float* dst; int r;
    if (idx < 36864)        { src = Wc4; dst = wp4; r = idx; }
    else if (idx < 73728)   { src = Wc5; dst = wp5; r = idx - 36864; }
    else if (idx < 147456)  { src = Wc3; dst = wp3; r = idx - 73728; }
    else                    { src = Wc2; dst = wp2; r = idx - 147456; }
    int pair = r / 9, q = r - pair * 9;
    dst[pair * 12 + q] = src[r];
}

// ======================================================================
__global__ __launch_bounds__(256) void deconv1_k(
    const float* __restrict__ glo, const float* __restrict__ Wt1, const float* __restrict__ bt1,
    float* __restrict__ s1f)
{
    const int f = blockIdx.x;
    const int tid = threadIdx.x;
    const int n = tid >> 2, pp = tid & 3;
    float bb = bt1[f];
    float a0 = bb, a1 = bb, a2 = bb, a3 = bb;
    const float* gp = glo + n * GLO;
    for (int c = 0; c < GLO; ++c) {
        float g = gp[c];
        float4 w4 = *(const float4*)&Wt1[(((size_t)c * 256 + f) << 4) + pp * 4];
        a0 = fmaf(g, w4.x, a0);
        a1 = fmaf(g, w4.y, a1);
        a2 = fmaf(g, w4.z, a2);
        a3 = fmaf(g, w4.w, a3);
    }
    float* dst = s1f + (((size_t)n * 256 + f) << 4) + pp * 4;
    dst[0] = a0 > 0.f ? a0 : 0.1f * a0;
    dst[1] = a1 > 0.f ? a1 : 0.1f * a1;
    dst[2] = a2 > 0.f ? a2 : 0.1f * a2;
    dst[3] = a3 > 0.f ? a3 : 0.1f * a3;
}

// ======================================================================
// conv2_k: padded weights -> 3x float4 loads per ci (was 9 scalar).
// Bit-exact vs old kernel (same values, same FMA order).
// ======================================================================
__global__ __launch_bounds__(256) void conv2_k(
    const float* __restrict__ s1f, const float* __restrict__ wp2, const float* __restrict__ bc2,
    u16* __restrict__ c2)
{
    __shared__ float sp[256 * 36];   // 36,864 B
    const int n = blockIdx.x >> 3, cot = blockIdx.x & 7;
    const int tid = threadIdx.x;
    for (int i = tid; i < 256 * 36; i += 256) sp[i] = 0.f;
    __syncthreads();
    for (int i = tid; i < 4096; i += 256) {
        int ci = i >> 4, p = i & 15, y = p >> 2, x = p & 3;
        sp[ci * 36 + (y + 1) * 6 + (x + 1)] = s1f[((size_t)n * 256 + ci) * 16 + p];
    }
    __syncthreads();

    const int co = cot * 16 + (tid >> 4);
    const int p = tid & 15, y = p >> 2, x = p & 3;
    float acc = bc2[co];
    const float* wpb = wp2 + (size_t)co * 256 * 12;
    for (int ci = 0; ci < 256; ++ci) {
        const float4* wv4 = (const float4*)(wpb + ci * 12);
        float4 w0 = wv4[0], w1 = wv4[1], w2 = wv4[2];
        float wc[9] = {w0.x, w0.y, w0.z, w0.w, w1.x, w1.y, w1.z, w1.w, w2.x};
        const float* s = sp + ci * 36 + y * 6 + x;
#pragma unroll
        for (int ky = 0; ky < 3; ++ky) {
#pragma unroll
            for (int kx = 0; kx < 3; ++kx)
                acc = fmaf(s[ky * 6 + kx], wc[ky * 3 + kx], acc);
        }
    }
    c2[((size_t)n * 128 + co) * 16 + p] = f2b(acc);
}

// ======================================================================
// up_conv_b: banded upsample+conv with halo-in-LDS layout
// ======================================================================
template<int CIN, int HI, int WI, int BH, int DW, int COT, int CO>
__global__ __launch_bounds__(256) void up_conv_b(
    const u16* __restrict__ in, const float* __restrict__ wpad, const float* __restrict__ bias,
    u16* __restrict__ out)
{
    constexpr int H2 = 2 * HI, W2 = 2 * WI;
    constexpr int XG = W2 / DW;
    constexpr int ROWS = BH + 2;
    constexpr int STR = W2 + 2;            // even, odd bank count
    constexpr int NBAND = H2 / BH;
    constexpr int CT = CO / COT;
    constexpr int PAIRS = COT / 2;
    static_assert(XG * BH * PAIRS == 256, "thread map must cover block");
    static_assert((STR & 1) == 0, "u32 LDS reads need even u16 stride");

    __shared__ u16 S[CIN * ROWS * STR];

    const int tid = threadIdx.x;
    int b = blockIdx.x;
    const int ct = b % CT; b /= CT;
    const int band = b % NBAND;
    const int n = b / NBAND;
    const int r0 = band * BH;

    const u16* ip = in + (size_t)n * CIN * HI * WI;

    // stage: bilinear x2 upsample + relu, zero halo (y and x), bf16
    for (int i = tid; i < CIN * ROWS * STR; i += 256) {
        int x  = i % STR;
        int ry = (i / STR) % ROWS;
        int ci = i / (STR * ROWS);
        int yy = r0 - 1 + ry;
        int xx = x - 1;
        float v = 0.f;
        if (yy >= 0 && yy < H2 && xx >= 0 && xx < W2) {
            int y0 = (yy - 1) >> 1; float fy = (yy & 1) ? 0.25f : 0.75f;
            int x0 = (xx - 1) >> 1; float fx = (xx & 1) ? 0.25f : 0.75f;
            int y0c = y0 < 0 ? 0 : y0, y1c = y0 + 1 > HI - 1 ? HI - 1 : y0 + 1;
            int x0c = x0 < 0 ? 0 : x0, x1c = x0 + 1 > WI - 1 ? WI - 1 : x0 + 1;
            const u16* bp = ip + ci * HI * WI;
            float v00 = b2f(bp[y0c * WI + x0c]), v01 = b2f(bp[y0c * WI + x1c]);
            float v10 = b2f(bp[y1c * WI + x0c]), v11 = b2f(bp[y1c * WI + x1c]);
            v = (1.f - fy) * ((1.f - fx) * v00 + fx * v01)
              +        fy  * ((1.f - fx) * v10 + fx * v11);
            v = fmaxf(v, 0.f);
        }
        S[i] = f2b(v);
    }
    __syncthreads();

    const int xg = tid % XG;
    const int y  = (tid / XG) % BH;
    const int pr = tid / (XG * BH);
    const int co0 = ct * COT + pr * 2;
    const int x0 = xg * DW;
    const int yo = r0 + y;

    float acc0[DW], acc1[DW];
    const float bb0 = bias[co0], bb1 = bias[co0 + 1];
#pragma unroll
    for (int d = 0; d < DW; ++d) { acc0[d] = bb0; acc1[d] = bb1; }

    const float* wp0 = wpad + (size_t)(co0 * CIN) * 12;
    const float* wp1 = wpad + (size_t)((co0 + 1) * CIN) * 12;

    for (int ci = 0; ci < CIN; ++ci) {
        float wa[9], wb[9];
        {
            const float4* av = (const float4*)(wp0 + ci * 12);
            float4 a0 = av[0], a1 = av[1], a2 = av[2];
            wa[0] = a0.x; wa[1] = a0.y; wa[2] = a0.z; wa[3] = a0.w;
            wa[4] = a1.x; wa[5] = a1.y; wa[6] = a1.z; wa[7] = a1.w; wa[8] = a2.x;
            const float4* bv = (const float4*)(wp1 + ci * 12);
            float4 b0 = bv[0], b1 = bv[1], b2v = bv[2];
            wb[0] = b0.x; wb[1] = b0.y; wb[2] = b0.z; wb[3] = b0.w;
            wb[4] = b1.x; wb[5] = b1.y; wb[6] = b1.z; wb[7] = b1.w; wb[8] = b2v.x;
        }
#pragma unroll
        for (int ky = 0; ky < 3; ++ky) {
            const u32* Sr = (const u32*)(S + ci * ROWS * STR + (y + ky) * STR + x0);
            float seg[DW + 2];
#pragma unroll
            for (int k = 0; k < (DW + 2) / 2; ++k) {
                u32 u = Sr[k];
                seg[2 * k]     = b2f_lo(u);
                seg[2 * k + 1] = b2f_hi(u);
            }
#pragma unroll
            for (int d = 0; d < DW; ++d) {
                acc0[d] = fmaf(seg[d],     wa[ky * 3 + 0], acc0[d]);
                acc0[d] = fmaf(seg[d + 1], wa[ky * 3 + 1], acc0[d]);
                acc0[d] = fmaf(seg[d + 2], wa[ky * 3 + 2], acc0[d]);
                acc1[d] = fmaf(seg[d],     wb[ky * 3 + 0], acc1[d]);
                acc1[d] = fmaf(seg[d + 1], wb[ky * 3 + 1], acc1[d]);
                acc1[d] = fmaf(seg[d + 2], wb[ky * 3 + 2], acc1[d]);
            }
        }
    }

    u16* op0 = out + (((size_t)(n * CO + co0) * H2) + yo) * W2 + x0;
    u16* op1 = op0 + (size_t)H2 * W2;
#pragma unroll
    for (int d = 0; d < DW; d += 2) {
        u32 p0 = (u32)f2b(acc0[d]) | ((u32)f2b(acc0[d + 1]) << 16);
        u32 p1 = (u32)f2b(acc1[d]) | ((u32)f2b(acc1[d + 1]) << 16);
        *(u32*)(op0 + d) = p0;
        *(u32*)(op1 + d) = p1;
    }
}

// ======================================================================
// up_conv6: 4-wide units so all 256 threads compute (CO=2 final conv)
// ======================================================================
__global__ __launch_bounds__(256) void up_conv6(
    const u16* __restrict__ c5, const float* __restrict__ w, const float* __restrict__ bias,
    u16* __restrict__ sl)
{
    __shared__ u16 S[40960];
    const int tid = threadIdx.x;
    const int n = blockIdx.x >> 3;
    const int band = blockIdx.x & 7;
    const int r0 = band * 8;
    const u16* ip = c5 + (size_t)n * 64 * 1024;

    for (int i = tid; i < 40960; i += 256) {
        int x2 = i & 63; int ry = (i >> 6) % 10; int ci = i / 640;
        int yy = r0 - 1 + ry;
        float v = 0.f;
        if (yy >= 0 && yy < 64) {
            int y0 = (yy - 1) >> 1; float fy = (yy & 1) ? 0.25f : 0.75f;
            int x0 = (x2 - 1) >> 1; float fx = (x2 & 1) ? 0.25f : 0.75f;
            int y0c = y0 < 0 ? 0 : y0, y1c = y0 + 1 > 31 ? 31 : y0 + 1;
            int x0c = x0 < 0 ? 0 : x0, x1c = x0 + 1 > 31 ? 31 : x0 + 1;
            const u16* b = ip + ci * 1024;
            float v00 = b2f(b[y0c * 32 + x0c]), v01 = b2f(b[y0c * 32 + x1c]);
            float v10 = b2f(b[y1c * 32 + x0c]), v11 = b2f(b[y1c * 32 + x1c]);
            v = fmaxf((1.f - fy) * ((1.f - fx) * v00 + fx * v01)
                      +      fy  * ((1.f - fx) * v10 + fx * v11), 0.f);
        }
        S[i] = f2b(v);
    }
    __syncthreads();

    {
        const int u = tid;                  // 256 units: 2co x 8y x 16xg(4-wide)
        const int x0p = (u & 15) * 4;
        const int yr  = (u >> 4) & 7;
        const int co  = u >> 7;
        const int y = r0 + yr;
        float acc[4];
        float bb = bias[co];
#pragma unroll
        for (int d = 0; d < 4; ++d) acc[d] = bb;
        const float* wp = w + (size_t)co * 64 * 9;
        for (int ci = 0; ci < 64; ++ci) {
            const u16* Sr = S + ci * 640;
            float wk[9];
#pragma unroll
            for (int q = 0; q < 9; ++q) wk[q] = wp[ci * 9 + q];
#pragma unroll
            for (int ky = 0; ky < 3; ++ky) {
                int ry = yr + ky;
                float seg[6];
#pragma unroll
                for (int dx = 0; dx < 6; ++dx) {
                    int xx = x0p + dx - 1;
                    seg[dx] = (xx >= 0 && xx < 64) ? b2f(Sr[ry * 64 + xx]) : 0.f;
                }
#pragma unroll
                for (int d = 0; d < 4; ++d) {
                    acc[d] = fmaf(seg[d],     wk[ky * 3 + 0], acc[d]);
                    acc[d] = fmaf(seg[d + 1], wk[ky * 3 + 1], acc[d]);
                    acc[d] = fmaf(seg[d + 2], wk[ky * 3 + 2], acc[d]);
                }
            }
        }
        u16* op = sl + (size_t)(n * 2 + co) * 4096 + y * 64 + x0p;
        u32 p0 = (u32)f2b(acc[0]) | ((u32)f2b(acc[1]) << 16);
        u32 p1 = (u32)f2b(acc[2]) | ((u32)f2b(acc[3]) << 16);
        *(u32*)(op)     = p0;
        *(u32*)(op + 2) = p1;
    }
}

// ======================================================================
__global__ __launch_bounds__(256) void softmax_spatial(const u16* __restrict__ sl, float* __restrict__ out)
{
    __shared__ float red[256];
    const int b = blockIdx.x;
    const u16* src = sl + (size_t)b * 4096;
    float* dst = out + (size_t)b * 4096;
    const int tid = threadIdx.x;
    float m = -INFINITY;
    for (int i = tid; i < 4096; i += 256) m = fmaxf(m, b2f(src[i]));
    red[tid] = m; __syncthreads();
    for (int s = 128; s > 0; s >>= 1) { if (tid < s) red[tid] = fmaxf(red[tid], red[tid + s]); __syncthreads(); }
    m = red[0]; __syncthreads();
    float sum = 0.f;
    for (int i = tid; i < 4096; i += 256) sum += expf(b2f(src[i]) - m);
    red[tid] = sum; __syncthreads();
    for (int s = 128; s > 0; s >>= 1) { if (tid < s) red[tid] += red[tid + s]; __syncthreads(); }
    float inv = 1.f / red[0];
    for (int i = tid; i < 4096; i += 256) dst[i] = expf(b2f(src[i]) - m) * inv;
}

// ======================================================================
extern "C" void kernel_launch(void* const* d_in, const int* in_sizes, int n_in,
                              void* d_out, int out_size, void* d_ws, size_t ws_size,
                              hipStream_t stream)
{
    const float* G     = (const float*)d_in[0];
    const float* X     = (const float*)d_in[1];
    const int*   avail = (const int*)d_in[2];
    const float* lh    = (const float*)d_in[3];
    const float* pa    = (const float*)d_in[4];
    const int*   relf  = (const int*)d_in[5];
    const float* We  = (const float*)d_in[6];   const float* be  = (const float*)d_in[7];
    const float* W1  = (const float*)d_in[8];   const float* b1  = (const float*)d_in[9];
    const float* W2  = (const float*)d_in[10];  const float* b2  = (const float*)d_in[11];
    const float* W3  = (const float*)d_in[12];  const float* b3  = (const float*)d_in[13];
    const float* Wle = (const float*)d_in[14];  const float* ble = (const float*)d_in[15];
    const float* Wih = (const float*)d_in[16];  const float* Whh = (const float*)d_in[17];
    const float* bih = (const float*)d_in[18];  const float* bhh = (const float*)d_in[19];
    const float* Wa  = (const float*)d_in[20];  const float* ba  = (const float*)d_in[21];
    const float* Wv  = (const float*)d_in[22];  const float* bv  = (const float*)d_in[23];
    const float* Wt1 = (const float*)d_in[24];  const float* bt1 = (const float*)d_in[25];
    const float* Wc2 = (const float*)d_in[26];  const float* bc2 = (const float*)d_in[27];
    const float* Wc3 = (const float*)d_in[28];  const float* bc3 = (const float*)d_in[29];
    const float* Wc4 = (const float*)d_in[30];  const float* bc4 = (const float*)d_in[31];
    const float* Wc5 = (const float*)d_in[32];  const float* bc5 = (const float*)d_in[33];
    const float* Wc6 = (const float*)d_in[34];  const float* bc6 = (const float*)d_in[35];

    char* ws = (char*)d_ws;
    float* goaAll = (float*)(ws + WS_GOA);
    float* hbuf   = (float*)(ws + WS_HBUF);
    float* cbuf   = (float*)(ws + WS_CBUF);
    float* hout   = (float*)(ws + WS_HOUT);
    float* glo    = (float*)(ws + WS_GLO);
    float* wihT   = (float*)(ws + WS_WIHT);
    float* whhT   = (float*)(ws + WS_WHHT);
    float* bsum   = (float*)(ws + WS_BSUM);
    u16*   c2     = (u16*)(ws + WS_C2);
    u16*   c3     = (u16*)(ws + WS_C3);
    u16*   c4     = (u16*)(ws + WS_C4);
    u16*   c5     = (u16*)(ws + WS_C5);
    u16*   sl     = (u16*)(ws + WS_SL);
    u16*   WeT    = (u16*)(ws + WS_WET);
    u16*   W1T    = (u16*)(ws + WS_W1T);
    u16*   W2T    = (u16*)(ws + WS_W2T);
    u16*   W3T    = (u16*)(ws + WS_W3T);
    float* gatesX = (float*)(ws + WS_GX);
    float* s1f    = (float*)(ws + WS_S1F);
    float* wp4    = (float*)(ws + WS_WP4);
    float* wp5    = (float*)(ws + WS_WP5);
    float* wp3    = (float*)(ws + WS_WP3);
    float* wp2    = (float*)(ws + WS_WP2);
    float* out    = (float*)d_out;     // OUTPUT IS FLOAT32

    wprep<<<256, 256, 0, stream>>>(We, W1, W2, W3, WeT, W1T, W2T, W3T);
    wtrans<<<1024, 256, 0, stream>>>(Wih, Whh, bih, bhh, wihT, whhT, bsum);
    gcn_mfma<<<2048, 1024, 0, stream>>>(G, X, pa, WeT, be, W1T, b1, W2T, b2, W3T, b3, goaAll);
    lstm_pre<<<256, 256, 0, stream>>>(goaAll, Wle, ble, wihT, bsum, gatesX);
    lstm_seq<<<64, 1024, 0, stream>>>(gatesX, whhT, relf, lh, hbuf, cbuf, hout);
    heads<<<64, 256, 0, stream>>>(goaAll, hout, hbuf, cbuf, Wa, ba, Wv, bv, avail, glo, out);
    // goaAll + gatesX dead from here; reuse for padded conv weights
    wpad_k<<<1728, 256, 0, stream>>>(Wc4, Wc5, Wc3, Wc2, wp4, wp5, wp3, wp2);
    deconv1_k<<<256, 256, 0, stream>>>(glo, Wt1, bt1, s1f);
    conv2_k<<<512, 256, 0, stream>>>(s1f, wp2, bc2, c2);
    // c2->c3: banded, 128ci, 4x4->8x8, BH=8 (whole), DW=4, COT=32 -> grid 64*1*2
    up_conv_b<128, 4, 4, 8, 4, 32, 64><<<128, 256, 0, stream>>>(c2, wp3, bc3, c3);
    // c3->c4: banded, 64ci, 8x8->16x16, BH=4, DW=4, COT=32 -> grid 64*4*2
    up_conv_b<64, 8, 8, 4, 4, 32, 64><<<512, 256, 0, stream>>>(c3, wp4, bc4, c4);
    // c4->c5: banded, 64ci, 16x16->32x32, BH=4, DW=8, COT=32 -> grid 64*8*2
    up_conv_b<64, 16, 16, 4, 8, 32, 64><<<1024, 256, 0, stream>>>(c4, wp5, bc5, c5);
    up_conv6<<<512, 256, 0, stream>>>(c5, Wc6, bc6, sl);
    softmax_spatial<<<128, 256, 0, stream>>>(sl, out + OUT_SPATIAL);
}

// Round 8
// 1313.043 us; speedup vs baseline: 1.3165x; 1.0672x over previous
//
#include <hip/hip_runtime.h>
#include <math.h>

typedef unsigned short u16;
typedef unsigned int u32;

typedef __attribute__((ext_vector_type(8))) short bf16x8;
typedef __attribute__((ext_vector_type(4))) float f32x4;

// ---------- bf16 helpers (intermediates only; I/O is f32) ----------
__device__ __forceinline__ float b2f(u16 u) {
    union { u32 ui; float f; } v; v.ui = ((u32)u) << 16; return v.f;
}
__device__ __forceinline__ float b2f_lo(u32 u) {
    union { u32 ui; float f; } v; v.ui = u << 16; return v.f;
}
__device__ __forceinline__ float b2f_hi(u32 u) {
    union { u32 ui; float f; } v; v.ui = u & 0xffff0000u; return v.f;
}
__device__ __forceinline__ u16 f2b(float f) {
    union { float f; u32 ui; } v; v.f = f;
    u32 x = v.ui;
    u32 r = (x + 0x7fffu + ((x >> 16) & 1u)) >> 16;
    return (u16)r;
}
__device__ __forceinline__ float sigf(float x) { return 1.0f / (1.0f + expf(-x)); }
// fast tanh: error ~1e-6, always followed by bf16 rounding (ulp ~4e-3 rel)
__device__ __forceinline__ float ftanh(float x) {
    float e = __expf(2.0f * x);
    return 1.0f - 2.0f / (e + 1.0f);
}

// ---------- problem constants ----------
#define GNODES 128
#define EMBD   256
#define NB     64
#define TS     32
#define GOA    268
#define GLO    524

// output layout (f32 elements)
#define OUT_SPATIAL 0
#define OUT_NS      524288
#define OUT_V       524800
#define OUT_H       524864

// workspace byte offsets
#define WS_GOA   ((size_t)0)
#define WS_HBUF  ((size_t)2195456)
#define WS_CBUF  ((size_t)2260992)
#define WS_HOUT  ((size_t)2326528)
#define WS_GLO   ((size_t)2392064)
#define WS_WIHT  ((size_t)2526208)
#define WS_WHHT  ((size_t)3574784)
#define WS_BSUM  ((size_t)4623360)
#define WS_C2    ((size_t)4627456)
#define WS_C3    ((size_t)4889600)
#define WS_C4    ((size_t)5413888)
#define WS_C5    ((size_t)7511040)
#define WS_SL    ((size_t)15899648)
#define WS_WET   ((size_t)16948224)   // 256*64 bf16
#define WS_W1T   ((size_t)16980992)   // 256*256 bf16
#define WS_W2T   ((size_t)17112064)
#define WS_W3T   ((size_t)17243136)
#define WS_GX    ((size_t)17374208)   // 2048*1024 f32 = 8,388,608
#define WS_S1F   ((size_t)25762816)   // 64*4096 f32 = 1,048,576 -> end 26,811,392

// padded conv weights: wp4/wp5/wp3 in the goaAll region (dead after
// `heads`); wp2 (128co x 256ci x 12 = 1.5MB) in the gatesX region
// (dead after lstm_seq). wpad_k runs after heads.
#define WS_WP4   WS_GOA
#define WS_WP5   (WS_GOA + (size_t)196608)
#define WS_WP3   (WS_GOA + (size_t)393216)   // end 786,432 < 2,195,456
#define WS_WP2   WS_GX                        // 1,572,864 < 8,388,608

// LDS strides (elements). NOTE (R8 analysis): SA_S/2=132, TT_S/2=68,
// XS_S/2=36 are all odd-multiples-of-4 mod 32 — with the 16B b128
// alignment constraint this is already the 8-slot/8-lane bank floor;
// the 4.4e7 conflict counter is inherent b128 serialization, not
// fixable by padding (268 would misalign b128; 272 is worse).
#define SA_S 264
#define TT_S 136
#define XS_S 72

// ======================================================================
// weight prep: transpose + bf16-cast GCN weights
// ======================================================================
__global__ void wprep(const float* __restrict__ We, const float* __restrict__ W1,
                      const float* __restrict__ W2, const float* __restrict__ W3,
                      u16* __restrict__ WeT, u16* __restrict__ W1T,
                      u16* __restrict__ W2T, u16* __restrict__ W3T)
{
    int idx = blockIdx.x * 256 + threadIdx.x;
    if (idx < 16384) {
        int k = idx >> 8, nn = idx & 255;
        WeT[nn * 64 + k] = f2b(We[idx]);
    }
    {
        int k = idx >> 8, nn = idx & 255;
        W1T[nn * 256 + k] = f2b(W1[idx]);
        W2T[nn * 256 + k] = f2b(W2[idx]);
        W3T[nn * 256 + k] = f2b(W3[idx]);
    }
}

// ======================================================================
// GCN via MFMA — 1024 threads (16 waves), 1 item per block. FROZEN at
// the R5/R7 known-good form (440us, absmax 9.77e-4). R6's
// v_cvt_pk_bf16_f32 broke correctness — do NOT reintroduce without a
// single-site isolated test. Design rule: <=64 VGPRs at 1024 threads.
// ======================================================================
__global__ __launch_bounds__(1024, 4) void gcn_mfma(
    const float* __restrict__ G, const float* __restrict__ X, const float* __restrict__ pa,
    const u16* __restrict__ WeT, const float* __restrict__ be,
    const u16* __restrict__ W1T, const float* __restrict__ b1,
    const u16* __restrict__ W2T, const float* __restrict__ b2,
    const u16* __restrict__ W3T, const float* __restrict__ b3,
    float* __restrict__ goaAll)
{
    __shared__ u16 Sa[128 * SA_S];
    __shared__ u16 Tt[256 * TT_S];
    __shared__ float dis[GNODES];
    __shared__ float dred[1024];
    __shared__ float pm[256];

    const int item = blockIdx.x;
    const int tid  = threadIdx.x;
    const int wv   = tid >> 6;        // 0..15
    const int nt   = wv & 7;          // node tile (A-mult / emb)
    const int ch   = wv >> 3;         // half index (A-mult / emb)
    const int lane = tid & 63;
    const int l16  = lane & 15;
    const int quad = lane >> 4;
    const float* Gp = G + (size_t)item * GNODES * GNODES;
    const float* Xp = X + (size_t)item * GNODES * 64;

    // stage X -> Tt (bf16), and degree partial sums (8 threads/row)
    for (int idx = tid; idx < 128 * 64; idx += 1024) {
        int m = idx >> 6, k = idx & 63;
        Tt[m * XS_S + k] = f2b(Xp[idx]);
    }
    {
        int row = tid >> 3, part = tid & 7;
        const float4* gr = (const float4*)(Gp + (size_t)row * GNODES) + part * 4;
        float s = 0.f;
#pragma unroll
        for (int k = 0; k < 4; ++k) { float4 g = gr[k]; s += g.x + g.y + g.z + g.w; }
        dred[tid] = s;
    }
    __syncthreads();
    if (tid < GNODES) {
        float s = 0.f;
#pragma unroll
        for (int p = 0; p < 8; ++p) s += dred[tid * 8 + p];
        dis[tid] = 1.0f / sqrtf(s + 1.0f);
    }
    __syncthreads();

    // bAgg: normalized adjacency fragments for node-tile nt (dup across ch)
    bf16x8 bAgg[4];
    {
        const int i = nt * 16 + l16;
        const float di = dis[i];
        const float* gr = Gp + (size_t)i * GNODES;
#pragma unroll
        for (int t = 0; t < 4; ++t) {
            const int k0 = t * 32 + quad * 8;
            float4 ga = *(const float4*)(gr + k0);
            float4 gb = *(const float4*)(gr + k0 + 4);
            float vv[8] = {ga.x, ga.y, ga.z, ga.w, gb.x, gb.y, gb.z, gb.w};
            bf16x8 f;
#pragma unroll
            for (int j = 0; j < 8; ++j) {
                int k = k0 + j;
                float a = (vv[j] + (k == i ? 1.0f : 0.0f)) * di * dis[k];
                f[j] = (short)f2b(a);
            }
            bAgg[t] = f;
        }
    }

    // emb = tanh(X @ We + be): wave = (node-tile nt, feature-half ch)
    {
        bf16x8 a0 = *(const bf16x8*)(Tt + (16 * nt + l16) * XS_S + quad * 8);
        bf16x8 a1 = *(const bf16x8*)(Tt + (16 * nt + l16) * XS_S + 32 + quad * 8);
        for (int cj = 0; cj < 8; ++cj) {
            const int ct = ch * 8 + cj;
            const int nf = ct * 16 + l16;
            bf16x8 wb0 = *(const bf16x8*)(WeT + nf * 64 + quad * 8);
            bf16x8 wb1 = *(const bf16x8*)(WeT + nf * 64 + 32 + quad * 8);
            float bb = be[nf];
            f32x4 acc = {bb, bb, bb, bb};
            acc = __builtin_amdgcn_mfma_f32_16x16x32_bf16(a0, wb0, acc, 0, 0, 0);
            acc = __builtin_amdgcn_mfma_f32_16x16x32_bf16(a1, wb1, acc, 0, 0, 0);
#pragma unroll
            for (int r = 0; r < 4; ++r) {
                int node = 16 * nt + quad * 4 + r;
                Sa[node * SA_S + nf] = f2b(ftanh(acc[r]));
            }
        }
    }
    __syncthreads();

    const u16* WTs[3]  = {W1T, W2T, W3T};
    const float* bss[3] = {b1, b2, b3};

    for (int l = 0; l < 3; ++l) {
        const u16* WT = WTs[l];
        const float* bias = bss[l];

        // ---- W-multiply: wave = ftile (wv). bfr persistent, afr streamed.
        const int nf = wv * 16 + l16;
        const float bb = bias[nf];
        bf16x8 bfr[8];
#pragma unroll
        for (int t = 0; t < 8; ++t)
            bfr[t] = *(const bf16x8*)(WT + (size_t)nf * 256 + t * 32 + quad * 8);

        for (int rt = 0; rt < 8; ++rt) {
            bf16x8 afr[8];
#pragma unroll
            for (int t = 0; t < 8; ++t)
                afr[t] = *(const bf16x8*)(Sa + (16 * rt + l16) * SA_S + t * 32 + quad * 8);
            f32x4 acc = {bb, bb, bb, bb};
#pragma unroll
            for (int t = 0; t < 8; ++t)
                acc = __builtin_amdgcn_mfma_f32_16x16x32_bf16(afr[t], bfr[t], acc, 0, 0, 0);
            u16 p0 = f2b(acc[0]), p1 = f2b(acc[1]), p2 = f2b(acc[2]), p3 = f2b(acc[3]);
            uint2 pk; pk.x = (u32)p0 | ((u32)p1 << 16); pk.y = (u32)p2 | ((u32)p3 << 16);
            *(uint2*)(Tt + (size_t)nf * TT_S + 16 * rt + quad * 4) = pk;
        }
        __syncthreads();

        // ---- A-multiply: wave = (node-tile nt, feature-half ch) ----
        for (int fj = 0; fj < 8; ++fj) {
            const int ft = ch * 8 + fj;
            bf16x8 afr[4];
#pragma unroll
            for (int t = 0; t < 4; ++t)
                afr[t] = *(const bf16x8*)(Tt + (16 * ft + l16) * TT_S + t * 32 + quad * 8);
            f32x4 acc = {0.f, 0.f, 0.f, 0.f};
#pragma unroll
            for (int t = 0; t < 4; ++t)
                acc = __builtin_amdgcn_mfma_f32_16x16x32_bf16(afr[t], bAgg[t], acc, 0, 0, 0);
            int i = nt * 16 + l16;
            u16 p0 = f2b(ftanh(acc[0])), p1 = f2b(ftanh(acc[1]));
            u16 p2 = f2b(ftanh(acc[2])), p3 = f2b(ftanh(acc[3]));
            uint2 pk; pk.x = (u32)p0 | ((u32)p1 << 16); pk.y = (u32)p2 | ((u32)p3 << 16);
            *(uint2*)(Sa + (size_t)i * SA_S + 16 * ft + quad * 4) = pk;
        }
        __syncthreads();
    }

    // ---- column max over nodes (split rows across two thread groups) ----
    const int nb = item >> 5, tt = item & 31;
    float* gdst = goaAll + ((size_t)tt * NB + nb) * GOA;
    float mymax = -2.0f;
    if (tid < 512) {
        int f = tid & 255, h = tid >> 8;
        for (int i = h * 64; i < h * 64 + 64; ++i)
            mymax = fmaxf(mymax, b2f(Sa[i * SA_S + f]));
        if (h == 1) pm[f] = mymax;
    }
    __syncthreads();
    if (tid < 256) {
        gdst[tid] = fmaxf(mymax, pm[tid]);
    } else if (tid >= 512 && tid < 524) {
        gdst[256 + (tid - 512)] = pa[(size_t)item * 12 + (tid - 512)];
    }
}

// ======================================================================
// wtrans: wihT (k-major) for lstm_pre; whh4 ([k/4][u][4] float4-packed)
// for lstm_seq; bsum.
// ======================================================================
__global__ void wtrans(const float* __restrict__ Wih, const float* __restrict__ Whh,
                       const float* __restrict__ bih, const float* __restrict__ bhh,
                       float* __restrict__ wihT, float* __restrict__ whh4, float* __restrict__ bsum)
{
    int idx = blockIdx.x * 256 + threadIdx.x;
    int r = idx >> 8;          // output unit u (0..1023)
    int k = idx & 255;         // input k
    wihT[k * 1024 + r] = Wih[idx];
    whh4[(size_t)(k >> 2) * 4096 + r * 4 + (k & 3)] = Whh[idx];
    if (idx < 1024) bsum[idx] = bih[idx] + bhh[idx];
}

// ======================================================================
// lstm_pre: LP_IT=4 items/block, 512 blocks (2 blocks/CU). Transposed
// LDS (glT[k][i], xvT[k][i]) -> per-k activations via ONE broadcast
// ds_read_b128; fused 16-accumulator (4g x 4i) gate loop. Per-thread
// LDS insts ~16x fewer vs R7. Bit-exact: per-accumulator FMA order
// over ascending k is unchanged.
// ======================================================================
#define LP_IT 4
__global__ __launch_bounds__(256) void lstm_pre(
    const float* __restrict__ goaAll, const float* __restrict__ Wle, const float* __restrict__ ble,
    const float* __restrict__ wihT, const float* __restrict__ bsum,
    float* __restrict__ gatesX)
{
    __shared__ float glT[GOA * LP_IT];     // glT[k*4 + it]
    __shared__ float xvT[256 * LP_IT];     // xvT[k*4 + it]
    const int b0 = blockIdx.x * LP_IT;
    const int u = threadIdx.x;

    for (int idx = u; idx < LP_IT * GOA; idx += 256) {
        int k = idx >> 2, it = idx & 3;
        glT[idx] = goaAll[(size_t)(b0 + it) * GOA + k];
    }
    __syncthreads();

    {
        float acc[LP_IT];
        float bl = ble[u];
#pragma unroll
        for (int i = 0; i < LP_IT; ++i) acc[i] = bl;
        for (int k = 0; k < GOA; ++k) {
            float w = Wle[k * 256 + u];
            float4 g4 = *(const float4*)&glT[k * 4];
            acc[0] = fmaf(g4.x, w, acc[0]);
            acc[1] = fmaf(g4.y, w, acc[1]);
            acc[2] = fmaf(g4.z, w, acc[2]);
            acc[3] = fmaf(g4.w, w, acc[3]);
        }
        float4 xv4;
        xv4.x = tanhf(acc[0]); xv4.y = tanhf(acc[1]);
        xv4.z = tanhf(acc[2]); xv4.w = tanhf(acc[3]);
        *(float4*)&xvT[u * 4] = xv4;
    }
    __syncthreads();

    {
        float a[4][LP_IT];
#pragma unroll
        for (int g = 0; g < 4; ++g) {
            float bs = bsum[g * 256 + u];
#pragma unroll
            for (int i = 0; i < LP_IT; ++i) a[g][i] = bs;
        }
        for (int k = 0; k < 256; ++k) {
            float4 x4 = *(const float4*)&xvT[k * 4];
            float w0 = wihT[k * 1024 + u];
            float w1 = wihT[k * 1024 + 256 + u];
            float w2 = wihT[k * 1024 + 512 + u];
            float w3 = wihT[k * 1024 + 768 + u];
            a[0][0] = fmaf(x4.x, w0, a[0][0]); a[0][1] = fmaf(x4.y, w0, a[0][1]);
            a[0][2] = fmaf(x4.z, w0, a[0][2]); a[0][3] = fmaf(x4.w, w0, a[0][3]);
            a[1][0] = fmaf(x4.x, w1, a[1][0]); a[1][1] = fmaf(x4.y, w1, a[1][1]);
            a[1][2] = fmaf(x4.z, w1, a[1][2]); a[1][3] = fmaf(x4.w, w1, a[1][3]);
            a[2][0] = fmaf(x4.x, w2, a[2][0]); a[2][1] = fmaf(x4.y, w2, a[2][1]);
            a[2][2] = fmaf(x4.z, w2, a[2][2]); a[2][3] = fmaf(x4.w, w2, a[2][3]);
            a[3][0] = fmaf(x4.x, w3, a[3][0]); a[3][1] = fmaf(x4.y, w3, a[3][1]);
            a[3][2] = fmaf(x4.z, w3, a[3][2]); a[3][3] = fmaf(x4.w, w3, a[3][3]);
        }
#pragma unroll
        for (int g = 0; g < 4; ++g)
#pragma unroll
            for (int i = 0; i < LP_IT; ++i)
                gatesX[(size_t)(b0 + i) * 1024 + g * 256 + u] = a[g][i];
    }
}

// ======================================================================
// lstm_seq: h-recurrence, zero-skip, 4-way acc ILP, float4 weights
// (whh4 layout) -> 64 dwordx4 loads/thread/step instead of 256 dwords.
// Bit-exact: a0..a3 chains identical to R7.
// ======================================================================
__global__ __launch_bounds__(1024) void lstm_seq(
    const float* __restrict__ gatesX, const float* __restrict__ whh4,
    const int* __restrict__ relf, const float* __restrict__ lh,
    float* __restrict__ hbuf, float* __restrict__ cbuf, float* __restrict__ hout)
{
    __shared__ float hv[256];
    __shared__ float ga[1024];
    __shared__ int hzf;
    const int n = blockIdx.x, u = threadIdx.x;
    float cpriv = 0.f;
    if (u < 256) { hv[u] = lh[n * 256 + u]; cpriv = lh[16384 + n * 256 + u]; }
    if (u == 0) hzf = 0;
    __syncthreads();

    const float4* w4base = (const float4*)whh4 + u;   // [k4*1024 + u]

    for (int t = 0; t < TS; ++t) {
        float a = gatesX[((size_t)t * NB + n) * 1024 + u];
        if (!hzf) {
            float a0 = 0.f, a1 = 0.f, a2 = 0.f, a3 = 0.f;
#pragma unroll 4
            for (int k4 = 0; k4 < 64; ++k4) {
                float4 w = w4base[k4 * 1024];
                int k = k4 * 4;
                a0 = fmaf(hv[k],     w.x, a0);
                a1 = fmaf(hv[k + 1], w.y, a1);
                a2 = fmaf(hv[k + 2], w.z, a2);
                a3 = fmaf(hv[k + 3], w.w, a3);
            }
            a += (a0 + a1) + (a2 + a3);
        }
        ga[u] = a;
        __syncthreads();
        if (u < 256) {
            float ai = ga[u], af = ga[256 + u], ag = ga[512 + u], ao = ga[768 + u];
            float cn = sigf(af) * cpriv + sigf(ai) * tanhf(ag);
            float hn = sigf(ao) * tanhf(cn);
            float kp = (relf[n * TS + t] != 0) ? 1.f : 0.f;
            if (t == TS - 1) {
                hout[n * 256 + u] = hn;
                hbuf[n * 256 + u] = hn * kp;
                cbuf[n * 256 + u] = cn * kp;
            }
            cpriv = cn * kp;
            hv[u] = hn * kp;
        }
        if (u == 0) hzf = (relf[n * TS + t] != 0) ? 0 : 1;
        __syncthreads();
    }
}

// ======================================================================
__global__ __launch_bounds__(256) void heads(
    const float* __restrict__ goaAll, const float* __restrict__ hout,
    const float* __restrict__ hbuf, const float* __restrict__ cbuf,
    const float* __restrict__ Wa, const float* __restrict__ ba,
    const float* __restrict__ Wv, const float* __restrict__ bv,
    const int* __restrict__ avail, float* __restrict__ glo, float* __restrict__ out)
{
    __shared__ float gl[GLO];
    __shared__ float lg[8];
    const int n = blockIdx.x, tid = threadIdx.x;
    const float* gsrc = goaAll + ((size_t)31 * NB + n) * GOA;
    gl[tid] = hout[n * 256 + tid];
    gl[256 + tid] = gsrc[tid];
    if (tid < 12) gl[512 + tid] = gsrc[256 + tid];
    __syncthreads();

    glo[n * GLO + tid]       = gl[tid];
    glo[n * GLO + 256 + tid] = gl[256 + tid];
    if (tid < 12) glo[n * GLO + 512 + tid] = gl[512 + tid];

    out[OUT_H + n * 256 + tid]         = hbuf[n * 256 + tid];
    out[OUT_H + 16384 + n * 256 + tid] = cbuf[n * 256 + tid];

    if (tid < 8) {
        float a = ba[tid];
        for (int k = 0; k < GLO; ++k) a = fmaf(gl[k], Wa[k * 8 + tid], a);
        lg[tid] = (avail[n * 8 + tid] == 0) ? -INFINITY : a;
    } else if (tid == 8) {
        float a = bv[0];
        for (int k = 0; k < GLO; ++k) a = fmaf(gl[k], Wv[k], a);
        out[OUT_V + n] = a;
    }
    __syncthreads();
    if (tid == 0) {
        float m = -INFINITY;
        for (int a = 0; a < 8; ++a) m = fmaxf(m, lg[a]);
        float e[8], s = 0.f;
        for (int a = 0; a < 8; ++a) { e[a] = expf(lg[a] - m); s += e[a]; }
        float inv = 1.f / s;
        for (int a = 0; a < 8; ++a) out[OUT_NS + n * 8 + a] = e[a] * inv;
    }
}

// ======================================================================
// wpad_k: pad conv weights 9 -> 12 floats per (co,ci) for float4 loads.
// Wc4 (36864), Wc5 (36864), Wc3 (73728), Wc2 (294912). grid 1728x256.
// ======================================================================
__global__ void wpad_k(const float* __restrict__ Wc4, const float* __restrict__ Wc5,
                       const float* __restrict__ Wc3, const float* __restrict__ Wc2,
                       float* __restrict__ wp4, float* __restrict__ wp5,
                       float* __restrict__ wp3, float* __restrict__ wp2)
{
    int idx = blockIdx.x * 256 + threadIdx.x;
    const float* src; float* dst; int r;
    if (idx < 36864)        { src = Wc4; dst = wp4; r = idx; }
    else if (idx < 73728)   { src = Wc5; dst = wp5; r = idx - 36864; }
    else if (idx < 147456)  { src = Wc3; dst = wp3; r = idx - 73728; }
    else                    { src = Wc2; dst = wp2; r = idx - 147456; }
    int pair = r / 9, q = r - pair * 9;
    dst[pair * 12 + q] = src[r];
}

// ======================================================================
// deconv1_k: 512 threads (2 waves/SIMD for latency hiding), 2 outputs
// per thread via float2 weights. Bit-exact per-output FMA chains.
// ======================================================================
__global__ __launch_bounds__(512) void deconv1_k(
    const float* __restrict__ glo, const float* __restrict__ Wt1, const float* __restrict__ bt1,
    float* __restrict__ s1f)
{
    const int f = blockIdx.x;
    const int tid = threadIdx.x;
    const int n = tid >> 3, pp = tid & 7;
    float bb = bt1[f];
    float a0 = bb, a1 = bb;
    const float* gp = glo + n * GLO;
    for (int c = 0; c < GLO; ++c) {
        float g = gp[c];
        float2 w2 = *(const float2*)&Wt1[(((size_t)c * 256 + f) << 4) + pp * 2];
        a0 = fmaf(g, w2.x, a0);
        a1 = fmaf(g, w2.y, a1);
    }
    float* dst = s1f + (((size_t)n * 256 + f) << 4) + pp * 2;
    dst[0] = a0 > 0.f ? a0 : 0.1f * a0;
    dst[1] = a1 > 0.f ? a1 : 0.1f * a1;
}

// ======================================================================
// conv2_k: padded weights -> 3x float4 loads per ci (was 9 scalar).
// ======================================================================
__global__ __launch_bounds__(256) void conv2_k(
    const float* __restrict__ s1f, const float* __restrict__ wp2, const float* __restrict__ bc2,
    u16* __restrict__ c2)
{
    __shared__ float sp[256 * 36];   // 36,864 B
    const int n = blockIdx.x >> 3, cot = blockIdx.x & 7;
    const int tid = threadIdx.x;
    for (int i = tid; i < 256 * 36; i += 256) sp[i] = 0.f;
    __syncthreads();
    for (int i = tid; i < 4096; i += 256) {
        int ci = i >> 4, p = i & 15, y = p >> 2, x = p & 3;
        sp[ci * 36 + (y + 1) * 6 + (x + 1)] = s1f[((size_t)n * 256 + ci) * 16 + p];
    }
    __syncthreads();

    const int co = cot * 16 + (tid >> 4);
    const int p = tid & 15, y = p >> 2, x = p & 3;
    float acc = bc2[co];
    const float* wpb = wp2 + (size_t)co * 256 * 12;
    for (int ci = 0; ci < 256; ++ci) {
        const float4* wv4 = (const float4*)(wpb + ci * 12);
        float4 w0 = wv4[0], w1 = wv4[1], w2 = wv4[2];
        float wc[9] = {w0.x, w0.y, w0.z, w0.w, w1.x, w1.y, w1.z, w1.w, w2.x};
        const float* s = sp + ci * 36 + y * 6 + x;
#pragma unroll
        for (int ky = 0; ky < 3; ++ky) {
#pragma unroll
            for (int kx = 0; kx < 3; ++kx)
                acc = fmaf(s[ky * 6 + kx], wc[ky * 3 + kx], acc);
        }
    }
    c2[((size_t)n * 128 + co) * 16 + p] = f2b(acc);
}

// ======================================================================
// up_conv_b: banded upsample+conv with halo-in-LDS layout
// ======================================================================
template<int CIN, int HI, int WI, int BH, int DW, int COT, int CO>
__global__ __launch_bounds__(256) void up_conv_b(
    const u16* __restrict__ in, const float* __restrict__ wpad, const float* __restrict__ bias,
    u16* __restrict__ out)
{
    constexpr int H2 = 2 * HI, W2 = 2 * WI;
    constexpr int XG = W2 / DW;
    constexpr int ROWS = BH + 2;
    constexpr int STR = W2 + 2;            // even, odd bank count
    constexpr int NBAND = H2 / BH;
    constexpr int CT = CO / COT;
    constexpr int PAIRS = COT / 2;
    static_assert(XG * BH * PAIRS == 256, "thread map must cover block");
    static_assert((STR & 1) == 0, "u32 LDS reads need even u16 stride");

    __shared__ u16 S[CIN * ROWS * STR];

    const int tid = threadIdx.x;
    int b = blockIdx.x;
    const int ct = b % CT; b /= CT;
    const int band = b % NBAND;
    const int n = b / NBAND;
    const int r0 = band * BH;

    const u16* ip = in + (size_t)n * CIN * HI * WI;

    // stage: bilinear x2 upsample + relu, zero halo (y and x), bf16
    for (int i = tid; i < CIN * ROWS * STR; i += 256) {
        int x  = i % STR;
        int ry = (i / STR) % ROWS;
        int ci = i / (STR * ROWS);
        int yy = r0 - 1 + ry;
        int xx = x - 1;
        float v = 0.f;
        if (yy >= 0 && yy < H2 && xx >= 0 && xx < W2) {
            int y0 = (yy - 1) >> 1; float fy = (yy & 1) ? 0.25f : 0.75f;
            int x0 = (xx - 1) >> 1; float fx = (xx & 1) ? 0.25f : 0.75f;
            int y0c = y0 < 0 ? 0 : y0, y1c = y0 + 1 > HI - 1 ? HI - 1 : y0 + 1;
            int x0c = x0 < 0 ? 0 : x0, x1c = x0 + 1 > WI - 1 ? WI - 1 : x0 + 1;
            const u16* bp = ip + ci * HI * WI;
            float v00 = b2f(bp[y0c * WI + x0c]), v01 = b2f(bp[y0c * WI + x1c]);
            float v10 = b2f(bp[y1c * WI + x0c]), v11 = b2f(bp[y1c * WI + x1c]);
            v = (1.f - fy) * ((1.f - fx) * v00 + fx * v01)
              +        fy  * ((1.f - fx) * v10 + fx * v11);
            v = fmaxf(v, 0.f);
        }
        S[i] = f2b(v);
    }
    __syncthreads();

    const int xg = tid % XG;
    const int y  = (tid / XG) % BH;
    const int pr = tid / (XG * BH);
    const int co0 = ct * COT + pr * 2;
    const int x0 = xg * DW;
    const int yo = r0 + y;

    float acc0[DW], acc1[DW];
    const float bb0 = bias[co0], bb1 = bias[co0 + 1];
#pragma unroll
    for (int d = 0; d < DW; ++d) { acc0[d] = bb0; acc1[d] = bb1; }

    const float* wp0 = wpad + (size_t)(co0 * CIN) * 12;
    const float* wp1 = wpad + (size_t)((co0 + 1) * CIN) * 12;

    for (int ci = 0; ci < CIN; ++ci) {
        float wa[9], wb[9];
        {
            const float4* av = (const float4*)(wp0 + ci * 12);
            float4 a0 = av[0], a1 = av[1], a2 = av[2];
            wa[0] = a0.x; wa[1] = a0.y; wa[2] = a0.z; wa[3] = a0.w;
            wa[4] = a1.x; wa[5] = a1.y; wa[6] = a1.z; wa[7] = a1.w; wa[8] = a2.x;
            const float4* bv = (const float4*)(wp1 + ci * 12);
            float4 b0 = bv[0], b1 = bv[1], b2v = bv[2];
            wb[0] = b0.x; wb[1] = b0.y; wb[2] = b0.z; wb[3] = b0.w;
            wb[4] = b1.x; wb[5] = b1.y; wb[6] = b1.z; wb[7] = b1.w; wb[8] = b2v.x;
        }
#pragma unroll
        for (int ky = 0; ky < 3; ++ky) {
            const u32* Sr = (const u32*)(S + ci * ROWS * STR + (y + ky) * STR + x0);
            float seg[DW + 2];
#pragma unroll
            for (int k = 0; k < (DW + 2) / 2; ++k) {
                u32 u = Sr[k];
                seg[2 * k]     = b2f_lo(u);
                seg[2 * k + 1] = b2f_hi(u);
            }
#pragma unroll
            for (int d = 0; d < DW; ++d) {
                acc0[d] = fmaf(seg[d],     wa[ky * 3 + 0], acc0[d]);
                acc0[d] = fmaf(seg[d + 1], wa[ky * 3 + 1], acc0[d]);
                acc0[d] = fmaf(seg[d + 2], wa[ky * 3 + 2], acc0[d]);
                acc1[d] = fmaf(seg[d],     wb[ky * 3 + 0], acc1[d]);
                acc1[d] = fmaf(seg[d + 1], wb[ky * 3 + 1], acc1[d]);
                acc1[d] = fmaf(seg[d + 2], wb[ky * 3 + 2], acc1[d]);
            }
        }
    }

    u16* op0 = out + (((size_t)(n * CO + co0) * H2) + yo) * W2 + x0;
    u16* op1 = op0 + (size_t)H2 * W2;
#pragma unroll
    for (int d = 0; d < DW; d += 2) {
        u32 p0 = (u32)f2b(acc0[d]) | ((u32)f2b(acc0[d + 1]) << 16);
        u32 p1 = (u32)f2b(acc1[d]) | ((u32)f2b(acc1[d + 1]) << 16);
        *(u32*)(op0 + d) = p0;
        *(u32*)(op1 + d) = p1;
    }
}

// ======================================================================
// up_conv6: 4-wide units so all 256 threads compute (CO=2 final conv)
// ======================================================================
__global__ __launch_bounds__(256) void up_conv6(
    const u16* __restrict__ c5, const float* __restrict__ w, const float* __restrict__ bias,
    u16* __restrict__ sl)
{
    __shared__ u16 S[40960];
    const int tid = threadIdx.x;
    const int n = blockIdx.x >> 3;
    const int band = blockIdx.x & 7;
    const int r0 = band * 8;
    const u16* ip = c5 + (size_t)n * 64 * 1024;

    for (int i = tid; i < 40960; i += 256) {
        int x2 = i & 63; int ry = (i >> 6) % 10; int ci = i / 640;
        int yy = r0 - 1 + ry;
        float v = 0.f;
        if (yy >= 0 && yy < 64) {
            int y0 = (yy - 1) >> 1; float fy = (yy & 1) ? 0.25f : 0.75f;
            int x0 = (x2 - 1) >> 1; float fx = (x2 & 1) ? 0.25f : 0.75f;
            int y0c = y0 < 0 ? 0 : y0, y1c = y0 + 1 > 31 ? 31 : y0 + 1;
            int x0c = x0 < 0 ? 0 : x0, x1c = x0 + 1 > 31 ? 31 : x0 + 1;
            const u16* b = ip + ci * 1024;
            float v00 = b2f(b[y0c * 32 + x0c]), v01 = b2f(b[y0c * 32 + x1c]);
            float v10 = b2f(b[y1c * 32 + x0c]), v11 = b2f(b[y1c * 32 + x1c]);
            v = fmaxf((1.f - fy) * ((1.f - fx) * v00 + fx * v01)
                      +      fy  * ((1.f - fx) * v10 + fx * v11), 0.f);
        }
        S[i] = f2b(v);
    }
    __syncthreads();

    {
        const int u = tid;                  // 256 units: 2co x 8y x 16xg(4-wide)
        const int x0p = (u & 15) * 4;
        const int yr  = (u >> 4) & 7;
        const int co  = u >> 7;
        const int y = r0 + yr;
        float acc[4];
        float bb = bias[co];
#pragma unroll
        for (int d = 0; d < 4; ++d) acc[d] = bb;
        const float* wp = w + (size_t)co * 64 * 9;
        for (int ci = 0; ci < 64; ++ci) {
            const u16* Sr = S + ci * 640;
            float wk[9];
#pragma unroll
            for (int q = 0; q < 9; ++q) wk[q] = wp[ci * 9 + q];
#pragma unroll
            for (int ky = 0; ky < 3; ++ky) {
                int ry = yr + ky;
                float seg[6];
#pragma unroll
                for (int dx = 0; dx < 6; ++dx) {
                    int xx = x0p + dx - 1;
                    seg[dx] = (xx >= 0 && xx < 64) ? b2f(Sr[ry * 64 + xx]) : 0.f;
                }
#pragma unroll
                for (int d = 0; d < 4; ++d) {
                    acc[d] = fmaf(seg[d],     wk[ky * 3 + 0], acc[d]);
                    acc[d] = fmaf(seg[d + 1], wk[ky * 3 + 1], acc[d]);
                    acc[d] = fmaf(seg[d + 2], wk[ky * 3 + 2], acc[d]);
                }
            }
        }
        u16* op = sl + (size_t)(n * 2 + co) * 4096 + y * 64 + x0p;
        u32 p0 = (u32)f2b(acc[0]) | ((u32)f2b(acc[1]) << 16);
        u32 p1 = (u32)f2b(acc[2]) | ((u32)f2b(acc[3]) << 16);
        *(u32*)(op)     = p0;
        *(u32*)(op + 2) = p1;
    }
}

// ======================================================================
__global__ __launch_bounds__(256) void softmax_spatial(const u16* __restrict__ sl, float* __restrict__ out)
{
    __shared__ float red[256];
    const int b = blockIdx.x;
    const u16* src = sl + (size_t)b * 4096;
    float* dst = out + (size_t)b * 4096;
    const int tid = threadIdx.x;
    float m = -INFINITY;
    for (int i = tid; i < 4096; i += 256) m = fmaxf(m, b2f(src[i]));
    red[tid] = m; __syncthreads();
    for (int s = 128; s > 0; s >>= 1) { if (tid < s) red[tid] = fmaxf(red[tid], red[tid + s]); __syncthreads(); }
    m = red[0]; __syncthreads();
    float sum = 0.f;
    for (int i = tid; i < 4096; i += 256) sum += expf(b2f(src[i]) - m);
    red[tid] = sum; __syncthreads();
    for (int s = 128; s > 0; s >>= 1) { if (tid < s) red[tid] += red[tid + s]; __syncthreads(); }
    float inv = 1.f / red[0];
    for (int i = tid; i < 4096; i += 256) dst[i] = expf(b2f(src[i]) - m) * inv;
}

// ======================================================================
extern "C" void kernel_launch(void* const* d_in, const int* in_sizes, int n_in,
                              void* d_out, int out_size, void* d_ws, size_t ws_size,
                              hipStream_t stream)
{
    const float* G     = (const float*)d_in[0];
    const float* X     = (const float*)d_in[1];
    const int*   avail = (const int*)d_in[2];
    const float* lh    = (const float*)d_in[3];
    const float* pa    = (const float*)d_in[4];
    const int*   relf  = (const int*)d_in[5];
    const float* We  = (const float*)d_in[6];   const float* be  = (const float*)d_in[7];
    const float* W1  = (const float*)d_in[8];   const float* b1  = (const float*)d_in[9];
    const float* W2  = (const float*)d_in[10];  const float* b2  = (const float*)d_in[11];
    const float* W3  = (const float*)d_in[12];  const float* b3  = (const float*)d_in[13];
    const float* Wle = (const float*)d_in[14];  const float* ble = (const float*)d_in[15];
    const float* Wih = (const float*)d_in[16];  const float* Whh = (const float*)d_in[17];
    const float* bih = (const float*)d_in[18];  const float* bhh = (const float*)d_in[19];
    const float* Wa  = (const float*)d_in[20];  const float* ba  = (const float*)d_in[21];
    const float* Wv  = (const float*)d_in[22];  const float* bv  = (const float*)d_in[23];
    const float* Wt1 = (const float*)d_in[24];  const float* bt1 = (const float*)d_in[25];
    const float* Wc2 = (const float*)d_in[26];  const float* bc2 = (const float*)d_in[27];
    const float* Wc3 = (const float*)d_in[28];  const float* bc3 = (const float*)d_in[29];
    const float* Wc4 = (const float*)d_in[30];  const float* bc4 = (const float*)d_in[31];
    const float* Wc5 = (const float*)d_in[32];  const float* bc5 = (const float*)d_in[33];
    const float* Wc6 = (const float*)d_in[34];  const float* bc6 = (const float*)d_in[35];

    char* ws = (char*)d_ws;
    float* goaAll = (float*)(ws + WS_GOA);
    float* hbuf   = (float*)(ws + WS_HBUF);
    float* cbuf   = (float*)(ws + WS_CBUF);
    float* hout   = (float*)(ws + WS_HOUT);
    float* glo    = (float*)(ws + WS_GLO);
    float* wihT   = (float*)(ws + WS_WIHT);
    float* whh4   = (float*)(ws + WS_WHHT);
    float* bsum   = (float*)(ws + WS_BSUM);
    u16*   c2     = (u16*)(ws + WS_C2);
    u16*   c3     = (u16*)(ws + WS_C3);
    u16*   c4     = (u16*)(ws + WS_C4);
    u16*   c5     = (u16*)(ws + WS_C5);
    u16*   sl     = (u16*)(ws + WS_SL);
    u16*   WeT    = (u16*)(ws + WS_WET);
    u16*   W1T    = (u16*)(ws + WS_W1T);
    u16*   W2T    = (u16*)(ws + WS_W2T);
    u16*   W3T    = (u16*)(ws + WS_W3T);
    float* gatesX = (float*)(ws + WS_GX);
    float* s1f    = (float*)(ws + WS_S1F);
    float* wp4    = (float*)(ws + WS_WP4);
    float* wp5    = (float*)(ws + WS_WP5);
    float* wp3    = (float*)(ws + WS_WP3);
    float* wp2    = (float*)(ws + WS_WP2);
    float* out    = (float*)d_out;     // OUTPUT IS FLOAT32

    wprep<<<256, 256, 0, stream>>>(We, W1, W2, W3, WeT, W1T, W2T, W3T);
    wtrans<<<1024, 256, 0, stream>>>(Wih, Whh, bih, bhh, wihT, whh4, bsum);
    gcn_mfma<<<2048, 1024, 0, stream>>>(G, X, pa, WeT, be, W1T, b1, W2T, b2, W3T, b3, goaAll);
    lstm_pre<<<512, 256, 0, stream>>>(goaAll, Wle, ble, wihT, bsum, gatesX);
    lstm_seq<<<64, 1024, 0, stream>>>(gatesX, whh4, relf, lh, hbuf, cbuf, hout);
    heads<<<64, 256, 0, stream>>>(goaAll, hout, hbuf, cbuf, Wa, ba, Wv, bv, avail, glo, out);
    // goaAll + gatesX dead from here; reuse for padded conv weights
    wpad_k<<<1728, 256, 0, stream>>>(Wc4, Wc5, Wc3, Wc2, wp4, wp5, wp3, wp2);
    deconv1_k<<<256, 512, 0, stream>>>(glo, Wt1, bt1, s1f);
    conv2_k<<<512, 256, 0, stream>>>(s1f, wp2, bc2, c2);
    // c2->c3: banded, 128ci, 4x4->8x8, BH=8 (whole), DW=4, COT=32 -> grid 64*1*2
    up_conv_b<128, 4, 4, 8, 4, 32, 64><<<128, 256, 0, stream>>>(c2, wp3, bc3, c3);
    // c3->c4: banded, 64ci, 8x8->16x16, BH=4, DW=4, COT=32 -> grid 64*4*2
    up_conv_b<64, 8, 8, 4, 4, 32, 64><<<512, 256, 0, stream>>>(c3, wp4, bc4, c4);
    // c4->c5: banded, 64ci, 16x16->32x32, BH=4, DW=8, COT=32 -> grid 64*8*2
    up_conv_b<64, 16, 16, 4, 8, 32, 64><<<1024, 256, 0, stream>>>(c4, wp5, bc5, c5);
    up_conv6<<<512, 256, 0, stream>>>(c5, Wc6, bc6, sl);
    softmax_spatial<<<128, 256, 0, stream>>>(sl, out + OUT_SPATIAL);
}

// Round 9
// 1244.314 us; speedup vs baseline: 1.3892x; 1.0552x over previous
//
#include <hip/hip_runtime.h>
#include <math.h>

typedef unsigned short u16;
typedef unsigned int u32;

typedef __attribute__((ext_vector_type(8))) short bf16x8;
typedef __attribute__((ext_vector_type(4))) float f32x4;

// ---------- bf16 helpers (intermediates only; I/O is f32) ----------
__device__ __forceinline__ float b2f(u16 u) {
    union { u32 ui; float f; } v; v.ui = ((u32)u) << 16; return v.f;
}
__device__ __forceinline__ float b2f_lo(u32 u) {
    union { u32 ui; float f; } v; v.ui = u << 16; return v.f;
}
__device__ __forceinline__ float b2f_hi(u32 u) {
    union { u32 ui; float f; } v; v.ui = u & 0xffff0000u; return v.f;
}
__device__ __forceinline__ u16 f2b(float f) {
    union { float f; u32 ui; } v; v.f = f;
    u32 x = v.ui;
    u32 r = (x + 0x7fffu + ((x >> 16) & 1u)) >> 16;
    return (u16)r;
}
__device__ __forceinline__ float sigf(float x) { return 1.0f / (1.0f + expf(-x)); }
// fast tanh: error ~1e-6, always followed by bf16 rounding (ulp ~4e-3 rel)
__device__ __forceinline__ float ftanh(float x) {
    float e = __expf(2.0f * x);
    return 1.0f - 2.0f / (e + 1.0f);
}

// ---------- problem constants ----------
#define GNODES 128
#define EMBD   256
#define NB     64
#define TS     32
#define GOA    268
#define GLO    524

// output layout (f32 elements)
#define OUT_SPATIAL 0
#define OUT_NS      524288
#define OUT_V       524800
#define OUT_H       524864

// workspace byte offsets
#define WS_GOA   ((size_t)0)
#define WS_HBUF  ((size_t)2195456)
#define WS_CBUF  ((size_t)2260992)
#define WS_HOUT  ((size_t)2326528)
#define WS_GLO   ((size_t)2392064)
#define WS_WIHT  ((size_t)2526208)
#define WS_WHHT  ((size_t)3574784)
#define WS_BSUM  ((size_t)4623360)
#define WS_C2    ((size_t)4627456)
#define WS_C3    ((size_t)4889600)
#define WS_C4    ((size_t)5413888)
#define WS_C5    ((size_t)7511040)
#define WS_SL    ((size_t)15899648)
#define WS_WET   ((size_t)16948224)   // 256*64 bf16
#define WS_W1T   ((size_t)16980992)   // 256*256 bf16
#define WS_W2T   ((size_t)17112064)
#define WS_W3T   ((size_t)17243136)
#define WS_GX    ((size_t)17374208)   // 2048*1024 f32 = 8,388,608
#define WS_S1F   ((size_t)25762816)   // 64*4096 f32 = 1,048,576 -> end 26,811,392

// conv weight buffers in the goaAll region (dead after `heads`):
//   wb4/wb5: bf16 [q][co][ci] 9*64*64*2 = 73,728 B each (MFMA convs)
//   wp3: f32 padded 12/tap for c2->c3 scalar conv
// wp2 (f32 padded, 1.5MB) in gatesX region (dead after lstm_seq).
#define WS_WP4   WS_GOA
#define WS_WP5   (WS_GOA + (size_t)196608)
#define WS_WP3   (WS_GOA + (size_t)393216)   // end 786,432 < 2,195,456
#define WS_WP2   WS_GX                        // 1,572,864 < 8,388,608

// LDS strides (elements). gcn strides are at the b128 bank floor (R8).
#define SA_S 264
#define TT_S 136
#define XS_S 72

// ======================================================================
// weight prep: transpose + bf16-cast GCN weights
// ======================================================================
__global__ void wprep(const float* __restrict__ We, const float* __restrict__ W1,
                      const float* __restrict__ W2, const float* __restrict__ W3,
                      u16* __restrict__ WeT, u16* __restrict__ W1T,
                      u16* __restrict__ W2T, u16* __restrict__ W3T)
{
    int idx = blockIdx.x * 256 + threadIdx.x;
    if (idx < 16384) {
        int k = idx >> 8, nn = idx & 255;
        WeT[nn * 64 + k] = f2b(We[idx]);
    }
    {
        int k = idx >> 8, nn = idx & 255;
        W1T[nn * 256 + k] = f2b(W1[idx]);
        W2T[nn * 256 + k] = f2b(W2[idx]);
        W3T[nn * 256 + k] = f2b(W3[idx]);
    }
}

// ======================================================================
// GCN via MFMA — FROZEN at R5/R7 form (440us, absmax 9.77e-4).
// cvt_pk is permanently banned here (R6 failure, no safe probe site).
// Design rule: <=64 VGPRs at 1024 threads.
// ======================================================================
__global__ __launch_bounds__(1024, 4) void gcn_mfma(
    const float* __restrict__ G, const float* __restrict__ X, const float* __restrict__ pa,
    const u16* __restrict__ WeT, const float* __restrict__ be,
    const u16* __restrict__ W1T, const float* __restrict__ b1,
    const u16* __restrict__ W2T, const float* __restrict__ b2,
    const u16* __restrict__ W3T, const float* __restrict__ b3,
    float* __restrict__ goaAll)
{
    __shared__ u16 Sa[128 * SA_S];
    __shared__ u16 Tt[256 * TT_S];
    __shared__ float dis[GNODES];
    __shared__ float dred[1024];
    __shared__ float pm[256];

    const int item = blockIdx.x;
    const int tid  = threadIdx.x;
    const int wv   = tid >> 6;        // 0..15
    const int nt   = wv & 7;          // node tile (A-mult / emb)
    const int ch   = wv >> 3;         // half index (A-mult / emb)
    const int lane = tid & 63;
    const int l16  = lane & 15;
    const int quad = lane >> 4;
    const float* Gp = G + (size_t)item * GNODES * GNODES;
    const float* Xp = X + (size_t)item * GNODES * 64;

    // stage X -> Tt (bf16), and degree partial sums (8 threads/row)
    for (int idx = tid; idx < 128 * 64; idx += 1024) {
        int m = idx >> 6, k = idx & 63;
        Tt[m * XS_S + k] = f2b(Xp[idx]);
    }
    {
        int row = tid >> 3, part = tid & 7;
        const float4* gr = (const float4*)(Gp + (size_t)row * GNODES) + part * 4;
        float s = 0.f;
#pragma unroll
        for (int k = 0; k < 4; ++k) { float4 g = gr[k]; s += g.x + g.y + g.z + g.w; }
        dred[tid] = s;
    }
    __syncthreads();
    if (tid < GNODES) {
        float s = 0.f;
#pragma unroll
        for (int p = 0; p < 8; ++p) s += dred[tid * 8 + p];
        dis[tid] = 1.0f / sqrtf(s + 1.0f);
    }
    __syncthreads();

    // bAgg: normalized adjacency fragments for node-tile nt (dup across ch)
    bf16x8 bAgg[4];
    {
        const int i = nt * 16 + l16;
        const float di = dis[i];
        const float* gr = Gp + (size_t)i * GNODES;
#pragma unroll
        for (int t = 0; t < 4; ++t) {
            const int k0 = t * 32 + quad * 8;
            float4 ga = *(const float4*)(gr + k0);
            float4 gb = *(const float4*)(gr + k0 + 4);
            float vv[8] = {ga.x, ga.y, ga.z, ga.w, gb.x, gb.y, gb.z, gb.w};
            bf16x8 f;
#pragma unroll
            for (int j = 0; j < 8; ++j) {
                int k = k0 + j;
                float a = (vv[j] + (k == i ? 1.0f : 0.0f)) * di * dis[k];
                f[j] = (short)f2b(a);
            }
            bAgg[t] = f;
        }
    }

    // emb = tanh(X @ We + be): wave = (node-tile nt, feature-half ch)
    {
        bf16x8 a0 = *(const bf16x8*)(Tt + (16 * nt + l16) * XS_S + quad * 8);
        bf16x8 a1 = *(const bf16x8*)(Tt + (16 * nt + l16) * XS_S + 32 + quad * 8);
        for (int cj = 0; cj < 8; ++cj) {
            const int ct = ch * 8 + cj;
            const int nf = ct * 16 + l16;
            bf16x8 wb0 = *(const bf16x8*)(WeT + nf * 64 + quad * 8);
            bf16x8 wb1 = *(const bf16x8*)(WeT + nf * 64 + 32 + quad * 8);
            float bb = be[nf];
            f32x4 acc = {bb, bb, bb, bb};
            acc = __builtin_amdgcn_mfma_f32_16x16x32_bf16(a0, wb0, acc, 0, 0, 0);
            acc = __builtin_amdgcn_mfma_f32_16x16x32_bf16(a1, wb1, acc, 0, 0, 0);
#pragma unroll
            for (int r = 0; r < 4; ++r) {
                int node = 16 * nt + quad * 4 + r;
                Sa[node * SA_S + nf] = f2b(ftanh(acc[r]));
            }
        }
    }
    __syncthreads();

    const u16* WTs[3]  = {W1T, W2T, W3T};
    const float* bss[3] = {b1, b2, b3};

    for (int l = 0; l < 3; ++l) {
        const u16* WT = WTs[l];
        const float* bias = bss[l];

        // ---- W-multiply: wave = ftile (wv). bfr persistent, afr streamed.
        const int nf = wv * 16 + l16;
        const float bb = bias[nf];
        bf16x8 bfr[8];
#pragma unroll
        for (int t = 0; t < 8; ++t)
            bfr[t] = *(const bf16x8*)(WT + (size_t)nf * 256 + t * 32 + quad * 8);

        for (int rt = 0; rt < 8; ++rt) {
            bf16x8 afr[8];
#pragma unroll
            for (int t = 0; t < 8; ++t)
                afr[t] = *(const bf16x8*)(Sa + (16 * rt + l16) * SA_S + t * 32 + quad * 8);
            f32x4 acc = {bb, bb, bb, bb};
#pragma unroll
            for (int t = 0; t < 8; ++t)
                acc = __builtin_amdgcn_mfma_f32_16x16x32_bf16(afr[t], bfr[t], acc, 0, 0, 0);
            u16 p0 = f2b(acc[0]), p1 = f2b(acc[1]), p2 = f2b(acc[2]), p3 = f2b(acc[3]);
            uint2 pk; pk.x = (u32)p0 | ((u32)p1 << 16); pk.y = (u32)p2 | ((u32)p3 << 16);
            *(uint2*)(Tt + (size_t)nf * TT_S + 16 * rt + quad * 4) = pk;
        }
        __syncthreads();

        // ---- A-multiply: wave = (node-tile nt, feature-half ch) ----
        for (int fj = 0; fj < 8; ++fj) {
            const int ft = ch * 8 + fj;
            bf16x8 afr[4];
#pragma unroll
            for (int t = 0; t < 4; ++t)
                afr[t] = *(const bf16x8*)(Tt + (16 * ft + l16) * TT_S + t * 32 + quad * 8);
            f32x4 acc = {0.f, 0.f, 0.f, 0.f};
#pragma unroll
            for (int t = 0; t < 4; ++t)
                acc = __builtin_amdgcn_mfma_f32_16x16x32_bf16(afr[t], bAgg[t], acc, 0, 0, 0);
            int i = nt * 16 + l16;
            u16 p0 = f2b(ftanh(acc[0])), p1 = f2b(ftanh(acc[1]));
            u16 p2 = f2b(ftanh(acc[2])), p3 = f2b(ftanh(acc[3]));
            uint2 pk; pk.x = (u32)p0 | ((u32)p1 << 16); pk.y = (u32)p2 | ((u32)p3 << 16);
            *(uint2*)(Sa + (size_t)i * SA_S + 16 * ft + quad * 4) = pk;
        }
        __syncthreads();
    }

    // ---- column max over nodes (split rows across two thread groups) ----
    const int nb = item >> 5, tt = item & 31;
    float* gdst = goaAll + ((size_t)tt * NB + nb) * GOA;
    float mymax = -2.0f;
    if (tid < 512) {
        int f = tid & 255, h = tid >> 8;
        for (int i = h * 64; i < h * 64 + 64; ++i)
            mymax = fmaxf(mymax, b2f(Sa[i * SA_S + f]));
        if (h == 1) pm[f] = mymax;
    }
    __syncthreads();
    if (tid < 256) {
        gdst[tid] = fmaxf(mymax, pm[tid]);
    } else if (tid >= 512 && tid < 524) {
        gdst[256 + (tid - 512)] = pa[(size_t)item * 12 + (tid - 512)];
    }
}

// ======================================================================
// wtrans: wihT (k-major) for lstm_pre; whh4 ([k/4][u][4] float4-packed)
// for lstm_seq; bsum.
// ======================================================================
__global__ void wtrans(const float* __restrict__ Wih, const float* __restrict__ Whh,
                       const float* __restrict__ bih, const float* __restrict__ bhh,
                       float* __restrict__ wihT, float* __restrict__ whh4, float* __restrict__ bsum)
{
    int idx = blockIdx.x * 256 + threadIdx.x;
    int r = idx >> 8;          // output unit u (0..1023)
    int k = idx & 255;         // input k
    wihT[k * 1024 + r] = Wih[idx];
    whh4[(size_t)(k >> 2) * 4096 + r * 4 + (k & 3)] = Whh[idx];
    if (idx < 1024) bsum[idx] = bih[idx] + bhh[idx];
}

// ======================================================================
// lstm_pre: LP_IT=4 items/block, 512 blocks, transposed LDS (R8 form).
// ======================================================================
#define LP_IT 4
__global__ __launch_bounds__(256) void lstm_pre(
    const float* __restrict__ goaAll, const float* __restrict__ Wle, const float* __restrict__ ble,
    const float* __restrict__ wihT, const float* __restrict__ bsum,
    float* __restrict__ gatesX)
{
    __shared__ float glT[GOA * LP_IT];     // glT[k*4 + it]
    __shared__ float xvT[256 * LP_IT];     // xvT[k*4 + it]
    const int b0 = blockIdx.x * LP_IT;
    const int u = threadIdx.x;

    for (int idx = u; idx < LP_IT * GOA; idx += 256) {
        int k = idx >> 2, it = idx & 3;
        glT[idx] = goaAll[(size_t)(b0 + it) * GOA + k];
    }
    __syncthreads();

    {
        float acc[LP_IT];
        float bl = ble[u];
#pragma unroll
        for (int i = 0; i < LP_IT; ++i) acc[i] = bl;
        for (int k = 0; k < GOA; ++k) {
            float w = Wle[k * 256 + u];
            float4 g4 = *(const float4*)&glT[k * 4];
            acc[0] = fmaf(g4.x, w, acc[0]);
            acc[1] = fmaf(g4.y, w, acc[1]);
            acc[2] = fmaf(g4.z, w, acc[2]);
            acc[3] = fmaf(g4.w, w, acc[3]);
        }
        float4 xv4;
        xv4.x = tanhf(acc[0]); xv4.y = tanhf(acc[1]);
        xv4.z = tanhf(acc[2]); xv4.w = tanhf(acc[3]);
        *(float4*)&xvT[u * 4] = xv4;
    }
    __syncthreads();

    {
        float a[4][LP_IT];
#pragma unroll
        for (int g = 0; g < 4; ++g) {
            float bs = bsum[g * 256 + u];
#pragma unroll
            for (int i = 0; i < LP_IT; ++i) a[g][i] = bs;
        }
        for (int k = 0; k < 256; ++k) {
            float4 x4 = *(const float4*)&xvT[k * 4];
            float w0 = wihT[k * 1024 + u];
            float w1 = wihT[k * 1024 + 256 + u];
            float w2 = wihT[k * 1024 + 512 + u];
            float w3 = wihT[k * 1024 + 768 + u];
            a[0][0] = fmaf(x4.x, w0, a[0][0]); a[0][1] = fmaf(x4.y, w0, a[0][1]);
            a[0][2] = fmaf(x4.z, w0, a[0][2]); a[0][3] = fmaf(x4.w, w0, a[0][3]);
            a[1][0] = fmaf(x4.x, w1, a[1][0]); a[1][1] = fmaf(x4.y, w1, a[1][1]);
            a[1][2] = fmaf(x4.z, w1, a[1][2]); a[1][3] = fmaf(x4.w, w1, a[1][3]);
            a[2][0] = fmaf(x4.x, w2, a[2][0]); a[2][1] = fmaf(x4.y, w2, a[2][1]);
            a[2][2] = fmaf(x4.z, w2, a[2][2]); a[2][3] = fmaf(x4.w, w2, a[2][3]);
            a[3][0] = fmaf(x4.x, w3, a[3][0]); a[3][1] = fmaf(x4.y, w3, a[3][1]);
            a[3][2] = fmaf(x4.z, w3, a[3][2]); a[3][3] = fmaf(x4.w, w3, a[3][3]);
        }
#pragma unroll
        for (int g = 0; g < 4; ++g)
#pragma unroll
            for (int i = 0; i < LP_IT; ++i)
                gatesX[(size_t)(b0 + i) * 1024 + g * 256 + u] = a[g][i];
    }
}

// ======================================================================
// lstm_seq: h-recurrence, zero-skip, 4-way acc ILP, float4 weights.
// ======================================================================
__global__ __launch_bounds__(1024) void lstm_seq(
    const float* __restrict__ gatesX, const float* __restrict__ whh4,
    const int* __restrict__ relf, const float* __restrict__ lh,
    float* __restrict__ hbuf, float* __restrict__ cbuf, float* __restrict__ hout)
{
    __shared__ float hv[256];
    __shared__ float ga[1024];
    __shared__ int hzf;
    const int n = blockIdx.x, u = threadIdx.x;
    float cpriv = 0.f;
    if (u < 256) { hv[u] = lh[n * 256 + u]; cpriv = lh[16384 + n * 256 + u]; }
    if (u == 0) hzf = 0;
    __syncthreads();

    const float4* w4base = (const float4*)whh4 + u;   // [k4*1024 + u]

    for (int t = 0; t < TS; ++t) {
        float a = gatesX[((size_t)t * NB + n) * 1024 + u];
        if (!hzf) {
            float a0 = 0.f, a1 = 0.f, a2 = 0.f, a3 = 0.f;
#pragma unroll 4
            for (int k4 = 0; k4 < 64; ++k4) {
                float4 w = w4base[k4 * 1024];
                int k = k4 * 4;
                a0 = fmaf(hv[k],     w.x, a0);
                a1 = fmaf(hv[k + 1], w.y, a1);
                a2 = fmaf(hv[k + 2], w.z, a2);
                a3 = fmaf(hv[k + 3], w.w, a3);
            }
            a += (a0 + a1) + (a2 + a3);
        }
        ga[u] = a;
        __syncthreads();
        if (u < 256) {
            float ai = ga[u], af = ga[256 + u], ag = ga[512 + u], ao = ga[768 + u];
            float cn = sigf(af) * cpriv + sigf(ai) * tanhf(ag);
            float hn = sigf(ao) * tanhf(cn);
            float kp = (relf[n * TS + t] != 0) ? 1.f : 0.f;
            if (t == TS - 1) {
                hout[n * 256 + u] = hn;
                hbuf[n * 256 + u] = hn * kp;
                cbuf[n * 256 + u] = cn * kp;
            }
            cpriv = cn * kp;
            hv[u] = hn * kp;
        }
        if (u == 0) hzf = (relf[n * TS + t] != 0) ? 0 : 1;
        __syncthreads();
    }
}

// ======================================================================
__global__ __launch_bounds__(256) void heads(
    const float* __restrict__ goaAll, const float* __restrict__ hout,
    const float* __restrict__ hbuf, const float* __restrict__ cbuf,
    const float* __restrict__ Wa, const float* __restrict__ ba,
    const float* __restrict__ Wv, const float* __restrict__ bv,
    const int* __restrict__ avail, float* __restrict__ glo, float* __restrict__ out)
{
    __shared__ float gl[GLO];
    __shared__ float lg[8];
    const int n = blockIdx.x, tid = threadIdx.x;
    const float* gsrc = goaAll + ((size_t)31 * NB + n) * GOA;
    gl[tid] = hout[n * 256 + tid];
    gl[256 + tid] = gsrc[tid];
    if (tid < 12) gl[512 + tid] = gsrc[256 + tid];
    __syncthreads();

    glo[n * GLO + tid]       = gl[tid];
    glo[n * GLO + 256 + tid] = gl[256 + tid];
    if (tid < 12) glo[n * GLO + 512 + tid] = gl[512 + tid];

    out[OUT_H + n * 256 + tid]         = hbuf[n * 256 + tid];
    out[OUT_H + 16384 + n * 256 + tid] = cbuf[n * 256 + tid];

    if (tid < 8) {
        float a = ba[tid];
        for (int k = 0; k < GLO; ++k) a = fmaf(gl[k], Wa[k * 8 + tid], a);
        lg[tid] = (avail[n * 8 + tid] == 0) ? -INFINITY : a;
    } else if (tid == 8) {
        float a = bv[0];
        for (int k = 0; k < GLO; ++k) a = fmaf(gl[k], Wv[k], a);
        out[OUT_V + n] = a;
    }
    __syncthreads();
    if (tid == 0) {
        float m = -INFINITY;
        for (int a = 0; a < 8; ++a) m = fmaxf(m, lg[a]);
        float e[8], s = 0.f;
        for (int a = 0; a < 8; ++a) { e[a] = expf(lg[a] - m); s += e[a]; }
        float inv = 1.f / s;
        for (int a = 0; a < 8; ++a) out[OUT_NS + n * 8 + a] = e[a] * inv;
    }
}

// ======================================================================
// wpad_k: pad f32 conv weights 9 -> 12 per (co,ci): Wc3 (73728) + Wc2
// (294912). grid 1440x256 = 368640 exactly.
// ======================================================================
__global__ void wpad_k(const float* __restrict__ Wc3, const float* __restrict__ Wc2,
                       float* __restrict__ wp3, float* __restrict__ wp2)
{
    int idx = blockIdx.x * 256 + threadIdx.x;
    const float* src; float* dst; int r;
    if (idx < 73728) { src = Wc3; dst = wp3; r = idx; }
    else             { src = Wc2; dst = wp2; r = idx - 73728; }
    int pair = r / 9, q = r - pair * 9;
    dst[pair * 12 + q] = src[r];
}

// ======================================================================
// wconvb_k: Wc4/Wc5 [co][ci][ky][kx] f32 -> bf16 [q][co][ci] for the
// MFMA convs (q = ky*3+kx). grid 288x256 = 73728.
// ======================================================================
__global__ void wconvb_k(const float* __restrict__ Wc4, const float* __restrict__ Wc5,
                         u16* __restrict__ wb4, u16* __restrict__ wb5)
{
    int idx = blockIdx.x * 256 + threadIdx.x;   // 0..73727
    int which = idx / 36864;
    int r = idx - which * 36864;
    int co = r / 576, rem = r - co * 576;
    int ci = rem / 9, q = rem - ci * 9;
    const float* src = which ? Wc5 : Wc4;
    u16* dst = which ? wb5 : wb4;
    dst[(q * 64 + co) * 64 + ci] = f2b(src[r]);
}

// ======================================================================
__global__ __launch_bounds__(512) void deconv1_k(
    const float* __restrict__ glo, const float* __restrict__ Wt1, const float* __restrict__ bt1,
    float* __restrict__ s1f)
{
    const int f = blockIdx.x;
    const int tid = threadIdx.x;
    const int n = tid >> 3, pp = tid & 7;
    float bb = bt1[f];
    float a0 = bb, a1 = bb;
    const float* gp = glo + n * GLO;
    for (int c = 0; c < GLO; ++c) {
        float g = gp[c];
        float2 w2 = *(const float2*)&Wt1[(((size_t)c * 256 + f) << 4) + pp * 2];
        a0 = fmaf(g, w2.x, a0);
        a1 = fmaf(g, w2.y, a1);
    }
    float* dst = s1f + (((size_t)n * 256 + f) << 4) + pp * 2;
    dst[0] = a0 > 0.f ? a0 : 0.1f * a0;
    dst[1] = a1 > 0.f ? a1 : 0.1f * a1;
}

// ======================================================================
// conv2_k: padded weights -> 3x float4 loads per ci.
// ======================================================================
__global__ __launch_bounds__(256) void conv2_k(
    const float* __restrict__ s1f, const float* __restrict__ wp2, const float* __restrict__ bc2,
    u16* __restrict__ c2)
{
    __shared__ float sp[256 * 36];   // 36,864 B
    const int n = blockIdx.x >> 3, cot = blockIdx.x & 7;
    const int tid = threadIdx.x;
    for (int i = tid; i < 256 * 36; i += 256) sp[i] = 0.f;
    __syncthreads();
    for (int i = tid; i < 4096; i += 256) {
        int ci = i >> 4, p = i & 15, y = p >> 2, x = p & 3;
        sp[ci * 36 + (y + 1) * 6 + (x + 1)] = s1f[((size_t)n * 256 + ci) * 16 + p];
    }
    __syncthreads();

    const int co = cot * 16 + (tid >> 4);
    const int p = tid & 15, y = p >> 2, x = p & 3;
    float acc = bc2[co];
    const float* wpb = wp2 + (size_t)co * 256 * 12;
    for (int ci = 0; ci < 256; ++ci) {
        const float4* wv4 = (const float4*)(wpb + ci * 12);
        float4 w0 = wv4[0], w1 = wv4[1], w2 = wv4[2];
        float wc[9] = {w0.x, w0.y, w0.z, w0.w, w1.x, w1.y, w1.z, w1.w, w2.x};
        const float* s = sp + ci * 36 + y * 6 + x;
#pragma unroll
        for (int ky = 0; ky < 3; ++ky) {
#pragma unroll
            for (int kx = 0; kx < 3; ++kx)
                acc = fmaf(s[ky * 6 + kx], wc[ky * 3 + kx], acc);
        }
    }
    c2[((size_t)n * 128 + co) * 16 + p] = f2b(acc);
}

// ======================================================================
// up_conv_b: banded scalar upsample+conv (kept for c2->c3 only, CIN=128)
// ======================================================================
template<int CIN, int HI, int WI, int BH, int DW, int COT, int CO>
__global__ __launch_bounds__(256) void up_conv_b(
    const u16* __restrict__ in, const float* __restrict__ wpad, const float* __restrict__ bias,
    u16* __restrict__ out)
{
    constexpr int H2 = 2 * HI, W2 = 2 * WI;
    constexpr int XG = W2 / DW;
    constexpr int ROWS = BH + 2;
    constexpr int STR = W2 + 2;
    constexpr int NBAND = H2 / BH;
    constexpr int CT = CO / COT;
    constexpr int PAIRS = COT / 2;
    static_assert(XG * BH * PAIRS == 256, "thread map must cover block");
    static_assert((STR & 1) == 0, "u32 LDS reads need even u16 stride");

    __shared__ u16 S[CIN * ROWS * STR];

    const int tid = threadIdx.x;
    int b = blockIdx.x;
    const int ct = b % CT; b /= CT;
    const int band = b % NBAND;
    const int n = b / NBAND;
    const int r0 = band * BH;

    const u16* ip = in + (size_t)n * CIN * HI * WI;

    for (int i = tid; i < CIN * ROWS * STR; i += 256) {
        int x  = i % STR;
        int ry = (i / STR) % ROWS;
        int ci = i / (STR * ROWS);
        int yy = r0 - 1 + ry;
        int xx = x - 1;
        float v = 0.f;
        if (yy >= 0 && yy < H2 && xx >= 0 && xx < W2) {
            int y0 = (yy - 1) >> 1; float fy = (yy & 1) ? 0.25f : 0.75f;
            int x0 = (xx - 1) >> 1; float fx = (xx & 1) ? 0.25f : 0.75f;
            int y0c = y0 < 0 ? 0 : y0, y1c = y0 + 1 > HI - 1 ? HI - 1 : y0 + 1;
            int x0c = x0 < 0 ? 0 : x0, x1c = x0 + 1 > WI - 1 ? WI - 1 : x0 + 1;
            const u16* bp = ip + ci * HI * WI;
            float v00 = b2f(bp[y0c * WI + x0c]), v01 = b2f(bp[y0c * WI + x1c]);
            float v10 = b2f(bp[y1c * WI + x0c]), v11 = b2f(bp[y1c * WI + x1c]);
            v = (1.f - fy) * ((1.f - fx) * v00 + fx * v01)
              +        fy  * ((1.f - fx) * v10 + fx * v11);
            v = fmaxf(v, 0.f);
        }
        S[i] = f2b(v);
    }
    __syncthreads();

    const int xg = tid % XG;
    const int y  = (tid / XG) % BH;
    const int pr = tid / (XG * BH);
    const int co0 = ct * COT + pr * 2;
    const int x0 = xg * DW;
    const int yo = r0 + y;

    float acc0[DW], acc1[DW];
    const float bb0 = bias[co0], bb1 = bias[co0 + 1];
#pragma unroll
    for (int d = 0; d < DW; ++d) { acc0[d] = bb0; acc1[d] = bb1; }

    const float* wp0 = wpad + (size_t)(co0 * CIN) * 12;
    const float* wp1 = wpad + (size_t)((co0 + 1) * CIN) * 12;

    for (int ci = 0; ci < CIN; ++ci) {
        float wa[9], wb[9];
        {
            const float4* av = (const float4*)(wp0 + ci * 12);
            float4 a0 = av[0], a1 = av[1], a2 = av[2];
            wa[0] = a0.x; wa[1] = a0.y; wa[2] = a0.z; wa[3] = a0.w;
            wa[4] = a1.x; wa[5] = a1.y; wa[6] = a1.z; wa[7] = a1.w; wa[8] = a2.x;
            const float4* bv = (const float4*)(wp1 + ci * 12);
            float4 b0 = bv[0], b1 = bv[1], b2v = bv[2];
            wb[0] = b0.x; wb[1] = b0.y; wb[2] = b0.z; wb[3] = b0.w;
            wb[4] = b1.x; wb[5] = b1.y; wb[6] = b1.z; wb[7] = b1.w; wb[8] = b2v.x;
        }
#pragma unroll
        for (int ky = 0; ky < 3; ++ky) {
            const u32* Sr = (const u32*)(S + ci * ROWS * STR + (y + ky) * STR + x0);
            float seg[DW + 2];
#pragma unroll
            for (int k = 0; k < (DW + 2) / 2; ++k) {
                u32 u = Sr[k];
                seg[2 * k]     = b2f_lo(u);
                seg[2 * k + 1] = b2f_hi(u);
            }
#pragma unroll
            for (int d = 0; d < DW; ++d) {
                acc0[d] = fmaf(seg[d],     wa[ky * 3 + 0], acc0[d]);
                acc0[d] = fmaf(seg[d + 1], wa[ky * 3 + 1], acc0[d]);
                acc0[d] = fmaf(seg[d + 2], wa[ky * 3 + 2], acc0[d]);
                acc1[d] = fmaf(seg[d],     wb[ky * 3 + 0], acc1[d]);
                acc1[d] = fmaf(seg[d + 1], wb[ky * 3 + 1], acc1[d]);
                acc1[d] = fmaf(seg[d + 2], wb[ky * 3 + 2], acc1[d]);
            }
        }
    }

    u16* op0 = out + (((size_t)(n * CO + co0) * H2) + yo) * W2 + x0;
    u16* op1 = op0 + (size_t)H2 * W2;
#pragma unroll
    for (int d = 0; d < DW; d += 2) {
        u32 p0 = (u32)f2b(acc0[d]) | ((u32)f2b(acc0[d + 1]) << 16);
        u32 p1 = (u32)f2b(acc1[d]) | ((u32)f2b(acc1[d + 1]) << 16);
        *(u32*)(op0 + d) = p0;
        *(u32*)(op1 + d) = p1;
    }
}

// ======================================================================
// up_conv_mfma: upsample(x2 bilinear+relu) + 3x3 conv via 9-shift GEMM
// decomposition on MFMA. CIN=CO=64 only (c3->c4 HI=8, c4->c5 HI=16).
//   LDS: px-major S[pxl][ci] bf16, XOR-swizzled (byte ^= (pxl&7)<<4)
//        so B-fragments (8 consecutive ci per lane's px) are conflict-
//        free ds_read_b128 (16 lanes' 4-bank spans tile all 32 banks).
//   A-fragments: bf16 weights [q][co][ci] hoisted per wave (72 VGPR;
//        256-thr blocks -> 2 waves/EU -> 256 VGPR cap, no spill).
//   mfma(a=W(l16=co), b=X(l16=px)) -> D[co @ quad*4+r][px @ l16],
//        exactly mirroring the verified gcn fragment pattern.
// ======================================================================
template<int HI>
__global__ __launch_bounds__(256) void up_conv_mfma(
    const u16* __restrict__ in, const u16* __restrict__ wq,
    const float* __restrict__ bias, u16* __restrict__ out)
{
    constexpr int H2 = 2 * HI, W2 = 2 * HI;
    constexpr int BH = 4;
    constexpr int ROWS = BH + 2;
    constexpr int STRP = W2 + 2;
    constexpr int NBAND = H2 / BH;
    constexpr int XH = W2 / 16;
    constexpr int NPX = ROWS * STRP;

    __shared__ alignas(16) u16 S[NPX * 64];

    const int tid  = threadIdx.x;
    const int lane = tid & 63;
    const int wv   = tid >> 6;        // 0..3 = co-tile
    const int l16  = lane & 15;
    const int quad = lane >> 4;
    const int band = blockIdx.x % NBAND;
    const int n    = blockIdx.x / NBAND;
    const int r0   = band * BH;
    const u16* ip  = in + (size_t)n * 64 * HI * HI;

    // ---- stage: bilinear x2 + relu -> swizzled [pxl][ci] ----
    // i-order: ci slow, pxl fast => coalesced global reads per plane.
    for (int i = tid; i < NPX * 64; i += 256) {
        int ci = i / NPX;
        int pxl = i - ci * NPX;
        int ry = pxl / STRP, sx = pxl - ry * STRP;
        int yy = r0 - 1 + ry, xx = sx - 1;
        float v = 0.f;
        if (yy >= 0 && yy < H2 && xx >= 0 && xx < W2) {
            int y0 = (yy - 1) >> 1; float fy = (yy & 1) ? 0.25f : 0.75f;
            int x0 = (xx - 1) >> 1; float fx = (xx & 1) ? 0.25f : 0.75f;
            int y0c = y0 < 0 ? 0 : y0, y1c = y0 + 1 > HI - 1 ? HI - 1 : y0 + 1;
            int x0c = x0 < 0 ? 0 : x0, x1c = x0 + 1 > HI - 1 ? HI - 1 : x0 + 1;
            const u16* bp = ip + ci * HI * HI;
            float v00 = b2f(bp[y0c * HI + x0c]), v01 = b2f(bp[y0c * HI + x1c]);
            float v10 = b2f(bp[y1c * HI + x0c]), v11 = b2f(bp[y1c * HI + x1c]);
            v = (1.f - fy) * ((1.f - fx) * v00 + fx * v01)
              +        fy  * ((1.f - fx) * v10 + fx * v11);
            v = fmaxf(v, 0.f);
        }
        u32 byt = (((u32)pxl << 7) + ((u32)ci << 1)) ^ (((u32)(pxl & 7)) << 4);
        *(u16*)((char*)S + byt) = f2b(v);
    }
    __syncthreads();

    // ---- A-fragments: weights for co-tile wv, 9 q x 2 k-halves ----
    bf16x8 af[9][2];
#pragma unroll
    for (int q = 0; q < 9; ++q)
#pragma unroll
        for (int kh = 0; kh < 2; ++kh)
            af[q][kh] = *(const bf16x8*)(wq + ((q * 64 + wv * 16 + l16) * 64 + kh * 32 + quad * 8));

    float b4[4];
#pragma unroll
    for (int r = 0; r < 4; ++r) b4[r] = bias[wv * 16 + quad * 4 + r];

    // ---- output tiles: (y, xh), 16 px each ----
    for (int y = 0; y < BH; ++y) {
        for (int xh = 0; xh < XH; ++xh) {
            f32x4 acc = {0.f, 0.f, 0.f, 0.f};
#pragma unroll
            for (int qy = 0; qy < 3; ++qy) {
#pragma unroll
                for (int qx = 0; qx < 3; ++qx) {
                    const int q = qy * 3 + qx;
                    const int P = (y + qy) * STRP + xh * 16 + qx + l16;
                    const u32 base = ((u32)P << 7) + ((u32)quad << 4);
                    const u32 swz  = ((u32)(P & 7)) << 4;
                    const bf16x8 bf0 = *(const bf16x8*)((char*)S + (base ^ swz));
                    const bf16x8 bf1 = *(const bf16x8*)((char*)S + ((base + 64) ^ swz));
                    acc = __builtin_amdgcn_mfma_f32_16x16x32_bf16(af[q][0], bf0, acc, 0, 0, 0);
                    acc = __builtin_amdgcn_mfma_f32_16x16x32_bf16(af[q][1], bf1, acc, 0, 0, 0);
                }
            }
            const int xo = xh * 16 + l16;
            const int yo = r0 + y;
#pragma unroll
            for (int r = 0; r < 4; ++r) {
                const int co = wv * 16 + quad * 4 + r;
                out[((size_t)(n * 64 + co) * H2 + yo) * W2 + xo] = f2b(acc[r] + b4[r]);
            }
        }
    }
}

// ======================================================================
// up_conv6: 4-wide units so all 256 threads compute (CO=2 final conv)
// ======================================================================
__global__ __launch_bounds__(256) void up_conv6(
    const u16* __restrict__ c5, const float* __restrict__ w, const float* __restrict__ bias,
    u16* __restrict__ sl)
{
    __shared__ u16 S[40960];
    const int tid = threadIdx.x;
    const int n = blockIdx.x >> 3;
    const int band = blockIdx.x & 7;
    const int r0 = band * 8;
    const u16* ip = c5 + (size_t)n * 64 * 1024;

    for (int i = tid; i < 40960; i += 256) {
        int x2 = i & 63; int ry = (i >> 6) % 10; int ci = i / 640;
        int yy = r0 - 1 + ry;
        float v = 0.f;
        if (yy >= 0 && yy < 64) {
            int y0 = (yy - 1) >> 1; float fy = (yy & 1) ? 0.25f : 0.75f;
            int x0 = (x2 - 1) >> 1; float fx = (x2 & 1) ? 0.25f : 0.75f;
            int y0c = y0 < 0 ? 0 : y0, y1c = y0 + 1 > 31 ? 31 : y0 + 1;
            int x0c = x0 < 0 ? 0 : x0, x1c = x0 + 1 > 31 ? 31 : x0 + 1;
            const u16* b = ip + ci * 1024;
            float v00 = b2f(b[y0c * 32 + x0c]), v01 = b2f(b[y0c * 32 + x1c]);
            float v10 = b2f(b[y1c * 32 + x0c]), v11 = b2f(b[y1c * 32 + x1c]);
            v = fmaxf((1.f - fy) * ((1.f - fx) * v00 + fx * v01)
                      +      fy  * ((1.f - fx) * v10 + fx * v11), 0.f);
        }
        S[i] = f2b(v);
    }
    __syncthreads();

    {
        const int u = tid;                  // 256 units: 2co x 8y x 16xg(4-wide)
        const int x0p = (u & 15) * 4;
        const int yr  = (u >> 4) & 7;
        const int co  = u >> 7;
        const int y = r0 + yr;
        float acc[4];
        float bb = bias[co];
#pragma unroll
        for (int d = 0; d < 4; ++d) acc[d] = bb;
        const float* wp = w + (size_t)co * 64 * 9;
        for (int ci = 0; ci < 64; ++ci) {
            const u16* Sr = S + ci * 640;
            float wk[9];
#pragma unroll
            for (int q = 0; q < 9; ++q) wk[q] = wp[ci * 9 + q];
#pragma unroll
            for (int ky = 0; ky < 3; ++ky) {
                int ry = yr + ky;
                float seg[6];
#pragma unroll
                for (int dx = 0; dx < 6; ++dx) {
                    int xx = x0p + dx - 1;
                    seg[dx] = (xx >= 0 && xx < 64) ? b2f(Sr[ry * 64 + xx]) : 0.f;
                }
#pragma unroll
                for (int d = 0; d < 4; ++d) {
                    acc[d] = fmaf(seg[d],     wk[ky * 3 + 0], acc[d]);
                    acc[d] = fmaf(seg[d + 1], wk[ky * 3 + 1], acc[d]);
                    acc[d] = fmaf(seg[d + 2], wk[ky * 3 + 2], acc[d]);
                }
            }
        }
        u16* op = sl + (size_t)(n * 2 + co) * 4096 + y * 64 + x0p;
        u32 p0 = (u32)f2b(acc[0]) | ((u32)f2b(acc[1]) << 16);
        u32 p1 = (u32)f2b(acc[2]) | ((u32)f2b(acc[3]) << 16);
        *(u32*)(op)     = p0;
        *(u32*)(op + 2) = p1;
    }
}

// ======================================================================
__global__ __launch_bounds__(256) void softmax_spatial(const u16* __restrict__ sl, float* __restrict__ out)
{
    __shared__ float red[256];
    const int b = blockIdx.x;
    const u16* src = sl + (size_t)b * 4096;
    float* dst = out + (size_t)b * 4096;
    const int tid = threadIdx.x;
    float m = -INFINITY;
    for (int i = tid; i < 4096; i += 256) m = fmaxf(m, b2f(src[i]));
    red[tid] = m; __syncthreads();
    for (int s = 128; s > 0; s >>= 1) { if (tid < s) red[tid] = fmaxf(red[tid], red[tid + s]); __syncthreads(); }
    m = red[0]; __syncthreads();
    float sum = 0.f;
    for (int i = tid; i < 4096; i += 256) sum += expf(b2f(src[i]) - m);
    red[tid] = sum; __syncthreads();
    for (int s = 128; s > 0; s >>= 1) { if (tid < s) red[tid] += red[tid + s]; __syncthreads(); }
    float inv = 1.f / red[0];
    for (int i = tid; i < 4096; i += 256) dst[i] = expf(b2f(src[i]) - m) * inv;
}

// ======================================================================
extern "C" void kernel_launch(void* const* d_in, const int* in_sizes, int n_in,
                              void* d_out, int out_size, void* d_ws, size_t ws_size,
                              hipStream_t stream)
{
    const float* G     = (const float*)d_in[0];
    const float* X     = (const float*)d_in[1];
    const int*   avail = (const int*)d_in[2];
    const float* lh    = (const float*)d_in[3];
    const float* pa    = (const float*)d_in[4];
    const int*   relf  = (const int*)d_in[5];
    const float* We  = (const float*)d_in[6];   const float* be  = (const float*)d_in[7];
    const float* W1  = (const float*)d_in[8];   const float* b1  = (const float*)d_in[9];
    const float* W2  = (const float*)d_in[10];  const float* b2  = (const float*)d_in[11];
    const float* W3  = (const float*)d_in[12];  const float* b3  = (const float*)d_in[13];
    const float* Wle = (const float*)d_in[14];  const float* ble = (const float*)d_in[15];
    const float* Wih = (const float*)d_in[16];  const float* Whh = (const float*)d_in[17];
    const float* bih = (const float*)d_in[18];  const float* bhh = (const float*)d_in[19];
    const float* Wa  = (const float*)d_in[20];  const float* ba  = (const float*)d_in[21];
    const float* Wv  = (const float*)d_in[22];  const float* bv  = (const float*)d_in[23];
    const float* Wt1 = (const float*)d_in[24];  const float* bt1 = (const float*)d_in[25];
    const float* Wc2 = (const float*)d_in[26];  const float* bc2 = (const float*)d_in[27];
    const float* Wc3 = (const float*)d_in[28];  const float* bc3 = (const float*)d_in[29];
    const float* Wc4 = (const float*)d_in[30];  const float* bc4 = (const float*)d_in[31];
    const float* Wc5 = (const float*)d_in[32];  const float* bc5 = (const float*)d_in[33];
    const float* Wc6 = (const float*)d_in[34];  const float* bc6 = (const float*)d_in[35];

    char* ws = (char*)d_ws;
    float* goaAll = (float*)(ws + WS_GOA);
    float* hbuf   = (float*)(ws + WS_HBUF);
    float* cbuf   = (float*)(ws + WS_CBUF);
    float* hout   = (float*)(ws + WS_HOUT);
    float* glo    = (float*)(ws + WS_GLO);
    float* wihT   = (float*)(ws + WS_WIHT);
    float* whh4   = (float*)(ws + WS_WHHT);
    float* bsum   = (float*)(ws + WS_BSUM);
    u16*   c2     = (u16*)(ws + WS_C2);
    u16*   c3     = (u16*)(ws + WS_C3);
    u16*   c4     = (u16*)(ws + WS_C4);
    u16*   c5     = (u16*)(ws + WS_C5);
    u16*   sl     = (u16*)(ws + WS_SL);
    u16*   WeT    = (u16*)(ws + WS_WET);
    u16*   W1T    = (u16*)(ws + WS_W1T);
    u16*   W2T    = (u16*)(ws + WS_W2T);
    u16*   W3T    = (u16*)(ws + WS_W3T);
    float* gatesX = (float*)(ws + WS_GX);
    float* s1f    = (float*)(ws + WS_S1F);
    u16*   wb4    = (u16*)(ws + WS_WP4);
    u16*   wb5    = (u16*)(ws + WS_WP5);
    float* wp3    = (float*)(ws + WS_WP3);
    float* wp2    = (float*)(ws + WS_WP2);
    float* out    = (float*)d_out;     // OUTPUT IS FLOAT32

    wprep<<<256, 256, 0, stream>>>(We, W1, W2, W3, WeT, W1T, W2T, W3T);
    wtrans<<<1024, 256, 0, stream>>>(Wih, Whh, bih, bhh, wihT, whh4, bsum);
    gcn_mfma<<<2048, 1024, 0, stream>>>(G, X, pa, WeT, be, W1T, b1, W2T, b2, W3T, b3, goaAll);
    lstm_pre<<<512, 256, 0, stream>>>(goaAll, Wle, ble, wihT, bsum, gatesX);
    lstm_seq<<<64, 1024, 0, stream>>>(gatesX, whh4, relf, lh, hbuf, cbuf, hout);
    heads<<<64, 256, 0, stream>>>(goaAll, hout, hbuf, cbuf, Wa, ba, Wv, bv, avail, glo, out);
    // goaAll + gatesX dead from here; reuse for conv weight buffers
    wpad_k<<<1440, 256, 0, stream>>>(Wc3, Wc2, wp3, wp2);
    wconvb_k<<<288, 256, 0, stream>>>(Wc4, Wc5, wb4, wb5);
    deconv1_k<<<256, 512, 0, stream>>>(glo, Wt1, bt1, s1f);
    conv2_k<<<512, 256, 0, stream>>>(s1f, wp2, bc2, c2);
    // c2->c3: scalar banded, 128ci, 4x4->8x8 -> grid 64*1*2
    up_conv_b<128, 4, 4, 8, 4, 32, 64><<<128, 256, 0, stream>>>(c2, wp3, bc3, c3);
    // c3->c4: MFMA 9-shift GEMM, 8x8->16x16, grid 64n * 4 bands
    up_conv_mfma<8><<<256, 256, 0, stream>>>(c3, wb4, bc4, c4);
    // c4->c5: MFMA 9-shift GEMM, 16x16->32x32, grid 64n * 8 bands
    up_conv_mfma<16><<<512, 256, 0, stream>>>(c4, wb5, bc5, c5);
    up_conv6<<<512, 256, 0, stream>>>(c5, Wc6, bc6, sl);
    softmax_spatial<<<128, 256, 0, stream>>>(sl, out + OUT_SPATIAL);
}